// Round 19
// baseline (1183.834 us; speedup 1.0000x reference)
//
#include <hip/hip_runtime.h>
#include <cstdint>
#include <cstddef>

#define SS 512
#define BB 64
#define DD 128
#define HH 8
#define HDIM 16
#define FFD 1024
#define NL 6

typedef short bf16x8 __attribute__((ext_vector_type(8)));
typedef float f32x4 __attribute__((ext_vector_type(4)));

// hardware packed f32->bf16 (RNE), low16 = a, high16 = b
__device__ inline uint32_t pack2(float a, float b) {
  uint32_t r;
  asm("v_cvt_pk_bf16_f32 %0, %1, %2" : "=v"(r) : "v"(a), "v"(b));
  return r;
}

#define QSCALE 0.36067376022224085f  /* 0.25 * log2(e) */

// ---------------- fp32 -> bf16 convert (weights) ----------------
__global__ __launch_bounds__(256) void cvt_kernel(const float* __restrict__ s,
                                                  short* __restrict__ d, int n2) {
  int i = blockIdx.x * 256 + threadIdx.x;
  if (i < n2) {
    float2 v = ((const float2*)s)[i];
    ((uint32_t*)d)[i] = pack2(v.x, v.y);
  }
}

// qkv weights: scale Q rows (n<128) by 0.25*log2e (score scale folded, log2 domain)
__global__ __launch_bounds__(256) void cvt_qkv_kernel(const float* __restrict__ s,
                                                      short* __restrict__ d) {
  int i = blockIdx.x * 256 + threadIdx.x;
  if (i < NL * 384 * 64) {
    const int within = i % (384 * 64);
    const float sc = (within < 128 * 64) ? QSCALE : 1.0f;
    float2 v = ((const float2*)s)[i];
    ((uint32_t*)d)[i] = pack2(v.x * sc, v.y * sc);
  }
}

__global__ __launch_bounds__(256) void scale_bq_kernel(const float* __restrict__ s,
                                                       float* __restrict__ d) {
  int i = blockIdx.x * 256 + threadIdx.x;
  if (i < NL * 384) {
    const float sc = ((i % 384) < 128) ? QSCALE : 1.0f;
    d[i] = s[i] * sc;
  }
}

// ---------------- transpose+rownorm: (S,B,D)->(B,S,D) x0/h fp32, hb bf16, xn bf16 ----------------
__global__ __launch_bounds__(256) void transpose_rn_kernel(const float* __restrict__ src,
                                                           float* __restrict__ x0,
                                                           float* __restrict__ h,
                                                           short* __restrict__ hb,
                                                           short* __restrict__ xn) {
  const int wave = threadIdx.x >> 6;
  const int lane = threadIdx.x & 63;
  const int row = blockIdx.x * 4 + wave;   // row = b*512 + s
  const int b = row >> 9;
  const int s = row & 511;
  const float2 v = ((const float2*)(src + ((size_t)s * BB + b) * DD))[lane];
  ((float2*)(x0 + (size_t)row * DD))[lane] = v;
  ((float2*)(h + (size_t)row * DD))[lane] = v;
  ((uint32_t*)hb)[(size_t)row * 64 + lane] = pack2(v.x, v.y);
  float ss = v.x * v.x + v.y * v.y;
  #pragma unroll
  for (int off = 1; off < 64; off <<= 1) ss += __shfl_xor(ss, off);
  const float r = rsqrtf(ss);
  ((uint32_t*)xn)[(size_t)row * 64 + lane] = pack2(v.x * r, v.y * r);
}

// ---------------- MFMA GEMM (QKV only): C = A@B^T + bias, head-major permuted out ----------------
__global__ __launch_bounds__(256) void mgemm_qkv(const short* __restrict__ Ab,
                                                 const short* __restrict__ Bw,
                                                 const float* __restrict__ bias,
                                                 short* __restrict__ Cb) {
  __shared__ uint32_t Xs[128 * 32];
  __shared__ uint32_t Wls[128 * 32];
  const int t = threadIdx.x;
  const int wave = t >> 6, lane = t & 63;
  const int g = lane >> 4, p = lane & 15;
  const int wr = wave >> 1, wc = wave & 1;
  const int m0 = blockIdx.y * 128, n0 = blockIdx.x * 128;
  const int K = DD;

  f32x4 acc[4][4];
  #pragma unroll
  for (int i = 0; i < 4; ++i)
    #pragma unroll
    for (int j = 0; j < 4; ++j) acc[i][j] = (f32x4){0.f, 0.f, 0.f, 0.f};

  for (int kt = 0; kt < K; kt += 64) {
    __syncthreads();
    #pragma unroll
    for (int i = 0; i < 4; ++i) {
      const int idx = t + i * 256;
      const int row = idx >> 3, kc = idx & 7;
      const uint4 w = *(const uint4*)(Ab + (size_t)(m0 + row) * K + kt + kc * 8);
      *(uint4*)(Xs + row * 32 + ((kc ^ (row & 7)) << 2)) = w;
      const uint4 u = *(const uint4*)(Bw + (size_t)(n0 + row) * K + kt + kc * 8);
      *(uint4*)(Wls + row * 32 + ((kc ^ (row & 7)) << 2)) = u;
    }
    __syncthreads();
    #pragma unroll
    for (int kc32 = 0; kc32 < 2; ++kc32) {
      bf16x8 xf[4], wf[4];
      #pragma unroll
      for (int mi = 0; mi < 4; ++mi) {
        const int row = wr * 64 + mi * 16 + p;
        union { bf16x8 v; uint4 w; } u;
        u.w = *(const uint4*)(Xs + row * 32 + (((kc32 * 4 + g) ^ (row & 7)) << 2));
        xf[mi] = u.v;
      }
      #pragma unroll
      for (int ni = 0; ni < 4; ++ni) {
        const int row = wc * 64 + ni * 16 + p;
        union { bf16x8 v; uint4 w; } u;
        u.w = *(const uint4*)(Wls + row * 32 + (((kc32 * 4 + g) ^ (row & 7)) << 2));
        wf[ni] = u.v;
      }
      #pragma unroll
      for (int mi = 0; mi < 4; ++mi)
        #pragma unroll
        for (int ni = 0; ni < 4; ++ni)
          acc[mi][ni] = __builtin_amdgcn_mfma_f32_16x16x32_bf16(wf[ni], xf[mi], acc[mi][ni], 0, 0, 0);
    }
  }

  #pragma unroll
  for (int mi = 0; mi < 4; ++mi) {
    const int m = m0 + wr * 64 + mi * 16 + p;
    #pragma unroll
    for (int ni = 0; ni < 4; ++ni) {
      const int nb = n0 + wc * 64 + ni * 16 + g * 4;
      const float4 bv = *(const float4*)(bias + nb);
      float c[4];
      c[0] = acc[mi][ni][0] + bv.x;
      c[1] = acc[mi][ni][1] + bv.y;
      c[2] = acc[mi][ni][2] + bv.z;
      c[3] = acc[mi][ni][3] + bv.w;
      const int bb2 = m >> 9, s = m & 511;
      const int which = nb >> 7, hh = (nb >> 4) & 7, d = nb & 15;
      uint2 w;
      w.x = pack2(c[0], c[1]);
      w.y = pack2(c[2], c[3]);
      *(uint2*)(Cb + ((((size_t)(bb2 * 3 + which) * 8 + hh) * 512 + s) * 16 + d)) = w;
    }
  }
}

// ---------------- Fused cosine-sim pair ----------------
__global__ __launch_bounds__(256) void cos2_kernel(const short* __restrict__ xn,
                                                   const short* __restrict__ yn,
                                                   float* __restrict__ out) {
  __shared__ uint32_t Js[128 * 64];  // 32 KB
  const int t = threadIdx.x;
  const int w = t >> 6, lane = t & 63;
  const int g = lane >> 4, p = lane & 15;
  const int j0 = blockIdx.x * 128;
  const int i0 = blockIdx.y * 64;
  const int b = blockIdx.z;
  const short* xb = xn + (size_t)b * SS * DD;
  const short* yb = yn + (size_t)b * SS * DD;
  const int i = i0 + w * 16 + p;

  // ---- pass 1: xn ----
  bf16x8 af[4];
  #pragma unroll
  for (int kc = 0; kc < 4; ++kc) {
    union { bf16x8 v; uint4 u; } uu;
    uu.u = *(const uint4*)(xb + (size_t)i * DD + kc * 32 + g * 8);
    af[kc] = uu.v;
  }
  #pragma unroll
  for (int q = 0; q < 8; ++q) {
    const int idx = q * 256 + t;
    const int row = idx >> 4, slot = idx & 15;
    const int key = (row & 3) | ((row >> 1) & 12);
    const uint4 u = *(const uint4*)(xb + (size_t)(j0 + row) * DD + slot * 8);
    *(uint4*)(&Js[row * 64 + ((slot ^ key) << 2)]) = u;
  }
  __syncthreads();

  f32x4 acc[8];
  #pragma unroll
  for (int q = 0; q < 8; ++q) acc[q] = (f32x4){0.f, 0.f, 0.f, 0.f};
  #pragma unroll
  for (int kc = 0; kc < 4; ++kc) {
    #pragma unroll
    for (int ni = 0; ni < 8; ++ni) {
      const int row = ni * 16 + p;
      const int key = (row & 3) | ((row >> 1) & 12);
      union { bf16x8 v; uint4 u; } jf;
      jf.u = *(const uint4*)(&Js[row * 64 + (((kc * 4 + g) ^ key) << 2)]);
      acc[ni] = __builtin_amdgcn_mfma_f32_16x16x32_bf16(jf.v, af[kc], acc[ni], 0, 0, 0);
    }
  }
  float prev[8][4];
  #pragma unroll
  for (int ni = 0; ni < 8; ++ni)
    #pragma unroll
    for (int r = 0; r < 4; ++r) prev[ni][r] = fmaxf(acc[ni][r], 1e-6f);
  __syncthreads();

  // ---- pass 2: yn ----
  #pragma unroll
  for (int kc = 0; kc < 4; ++kc) {
    union { bf16x8 v; uint4 u; } uu;
    uu.u = *(const uint4*)(yb + (size_t)i * DD + kc * 32 + g * 8);
    af[kc] = uu.v;
  }
  #pragma unroll
  for (int q = 0; q < 8; ++q) {
    const int idx = q * 256 + t;
    const int row = idx >> 4, slot = idx & 15;
    const int key = (row & 3) | ((row >> 1) & 12);
    const uint4 u = *(const uint4*)(yb + (size_t)(j0 + row) * DD + slot * 8);
    *(uint4*)(&Js[row * 64 + ((slot ^ key) << 2)]) = u;
  }
  __syncthreads();

  #pragma unroll
  for (int q = 0; q < 8; ++q) acc[q] = (f32x4){0.f, 0.f, 0.f, 0.f};
  #pragma unroll
  for (int kc = 0; kc < 4; ++kc) {
    #pragma unroll
    for (int ni = 0; ni < 8; ++ni) {
      const int row = ni * 16 + p;
      const int key = (row & 3) | ((row >> 1) & 12);
      union { bf16x8 v; uint4 u; } jf;
      jf.u = *(const uint4*)(&Js[row * 64 + (((kc * 4 + g) ^ key) << 2)]);
      acc[ni] = __builtin_amdgcn_mfma_f32_16x16x32_bf16(jf.v, af[kc], acc[ni], 0, 0, 0);
    }
  }

  float* ob = out + (size_t)b * SS * SS;
  #pragma unroll
  for (int ni = 0; ni < 8; ++ni) {
    const int j = j0 + ni * 16 + g * 4;
    float4 wv;
    float* pw = &wv.x;
    #pragma unroll
    for (int r = 0; r < 4; ++r) {
      const float v = fmaxf(acc[ni][r], 1e-6f);
      pw[r] = fminf(fmaxf(0.5f * (v + prev[ni][r]), 0.1f), 0.9f);
    }
    *(float4*)(ob + (size_t)i * SS + j) = wv;
  }
}

// ---------------- Fused Wo+LN1+FFN+LN2 v3: 128 threads / 32 rows -> 4 blocks/CU ----------------
// r18 diagnosis: grid 512 = 2 lockstep blocks/CU, latency-bound. Halve block to
// 2 waves / 32 rows -> grid 1024 = 4 independent blocks/CU; barriers sync only
// 2 waves; stalls interleave across blocks. Same math/swizzles; staging indices
// rescaled for 128 threads (4 uint4 per weight buffer per thread).
__global__ __launch_bounds__(128) void wo_ffn_ln_kernel(const short* __restrict__ att,
                                                        const short* __restrict__ Wob,
                                                        const float* __restrict__ bov,
                                                        const float* __restrict__ lng1,
                                                        const float* __restrict__ lnb1,
                                                        const short* __restrict__ W1b,
                                                        const float* __restrict__ b1v,
                                                        const short* __restrict__ W2b,
                                                        const float* __restrict__ b2v,
                                                        const float* __restrict__ lng2,
                                                        const float* __restrict__ lnb2,
                                                        float* __restrict__ hx,
                                                        short* __restrict__ hb) {
  __shared__ uint32_t S[10240];      // 40 KB union
  uint32_t* WoLS = S;                // phase A: 8192 words (32 KB)
  uint32_t* Tb   = S;                // transient: 2048 words (8 KB, 32 rows)
  uint32_t* W1base = S;              // 2 bufs x 2048 words (after Tb dead)
  uint32_t* W2base = S + 4096;       // 3 bufs x 2048 words
  const int t = threadIdx.x;
  const int w = t >> 6, lane = t & 63;
  const int g = lane >> 4, p = lane & 15;
  const int m0 = blockIdx.x * 32;
  const int m = m0 + w * 16 + p;
  const int lr = w * 16 + p;                    // [0,32)
  const int lkey = (lr & 3) | ((lr >> 1) & 12);

  // ---- Phase A: att rows in regs, Wo in LDS ----
  bf16x8 af[4];
  #pragma unroll
  for (int kc = 0; kc < 4; ++kc) {
    union { bf16x8 v; uint4 u; } uu;
    uu.u = *(const uint4*)(att + (size_t)m * DD + kc * 32 + g * 8);
    af[kc] = uu.v;
  }
  #pragma unroll
  for (int i = 0; i < 16; ++i) {
    const int idx = i * 128 + t;
    const int row = idx >> 4, slot = idx & 15;
    const int key = (row & 3) | ((row >> 1) & 12);
    const uint4 u = *(const uint4*)(Wob + (size_t)row * DD + slot * 8);
    *(uint4*)(&WoLS[row * 64 + ((slot ^ key) << 2)]) = u;
  }
  __syncthreads();

  f32x4 acc[8];
  #pragma unroll
  for (int i = 0; i < 8; ++i) acc[i] = (f32x4){0.f, 0.f, 0.f, 0.f};
  #pragma unroll
  for (int kc = 0; kc < 4; ++kc) {
    #pragma unroll
    for (int ni = 0; ni < 8; ++ni) {
      const int row = ni * 16 + p;
      const int key = (row & 3) | ((row >> 1) & 12);
      union { bf16x8 v; uint4 u; } wf;
      wf.u = *(const uint4*)(&WoLS[row * 64 + (((kc * 4 + g) ^ key) << 2)]);
      acc[ni] = __builtin_amdgcn_mfma_f32_16x16x32_bf16(wf.v, af[kc], acc[ni], 0, 0, 0);
    }
  }

  // LN1 (lane-local rows)
  float h1r[8][4];
  float s1r = 0.0f, s2r = 0.0f;
  #pragma unroll
  for (int ni = 0; ni < 8; ++ni) {
    const int nb = ni * 16 + g * 4;
    const float4 rv = *(const float4*)(hx + (size_t)m * DD + nb);
    const float4 bv = *(const float4*)(bov + nb);
    h1r[ni][0] = acc[ni][0] + bv.x + rv.x;
    h1r[ni][1] = acc[ni][1] + bv.y + rv.y;
    h1r[ni][2] = acc[ni][2] + bv.z + rv.z;
    h1r[ni][3] = acc[ni][3] + bv.w + rv.w;
    #pragma unroll
    for (int r = 0; r < 4; ++r) {
      s1r += h1r[ni][r];
      s2r += h1r[ni][r] * h1r[ni][r];
    }
  }
  s1r += __shfl_xor(s1r, 16); s1r += __shfl_xor(s1r, 32);
  s2r += __shfl_xor(s2r, 16); s2r += __shfl_xor(s2r, 32);
  {
    const float mu = s1r * (1.0f / 128.0f);
    const float rs = rsqrtf(fmaxf(s2r * (1.0f / 128.0f) - mu * mu, 0.0f) + 1e-5f);
    #pragma unroll
    for (int ni = 0; ni < 8; ++ni) {
      const int nb = ni * 16 + g * 4;
      const float4 gv = *(const float4*)(lng1 + nb);
      const float4 bv = *(const float4*)(lnb1 + nb);
      h1r[ni][0] = (h1r[ni][0] - mu) * rs * gv.x + bv.x;
      h1r[ni][1] = (h1r[ni][1] - mu) * rs * gv.y + bv.y;
      h1r[ni][2] = (h1r[ni][2] - mu) * rs * gv.z + bv.z;
      h1r[ni][3] = (h1r[ni][3] - mu) * rs * gv.w + bv.w;
    }
  }
  __syncthreads();  // all Wo reads done before Tb overwrites WoLS

  // write h1 (bf16) into Tb (rows 0..31)
  #pragma unroll
  for (int ni = 0; ni < 8; ++ni) {
    const int w16 = ni * 8 + 2 * g;
    const int slot = w16 >> 2, offs = w16 & 3;
    uint2 pk;
    pk.x = pack2(h1r[ni][0], h1r[ni][1]);
    pk.y = pack2(h1r[ni][2], h1r[ni][3]);
    *(uint2*)(&Tb[lr * 64 + ((slot ^ lkey) << 2) + offs]) = pk;
  }
  __syncthreads();

  // h1 B-frags from Tb (read ONCE)
  bf16x8 hsf[4];
  #pragma unroll
  for (int kc = 0; kc < 4; ++kc) {
    union { bf16x8 v; uint4 u; } uu;
    uu.u = *(const uint4*)(&Tb[lr * 64 + (((kc * 4 + g) ^ lkey) << 2)]);
    hsf[kc] = uu.v;
  }
  __syncthreads();

  // ---- Phase B: ffn v3 (128-thread staging: 4 uint4 per buffer) ----
  uint4 rA[4], rB[4];

#define FFN_LOAD(c)                                                               \
  {                                                                               \
    const int nf0_ = (c) * 32;                                                    \
    _Pragma("unroll")                                                             \
    for (int i_ = 0; i_ < 4; ++i_) {                                              \
      const int u_ = i_ * 128 + t;                                                \
      rA[i_] = *(const uint4*)(W1b + (size_t)(nf0_ + (u_ >> 4)) * DD + (u_ & 15) * 8); \
      rB[i_] = *(const uint4*)(W2b + (size_t)(u_ >> 2) * FFD + nf0_ + (u_ & 3) * 8);   \
    }                                                                             \
  }

#define FFN_WRITE(bufA, bufB)                                                     \
  {                                                                               \
    uint32_t* W1p = W1base + (bufA) * 2048;                                       \
    uint32_t* W2p = W2base + (bufB) * 2048;                                       \
    _Pragma("unroll")                                                             \
    for (int i_ = 0; i_ < 4; ++i_) {                                              \
      const int u_ = i_ * 128 + t;                                                \
      const int rw1 = u_ >> 4, sl1 = u_ & 15;                                     \
      const int k1 = (rw1 & 3) | ((rw1 >> 1) & 12);                               \
      *(uint4*)(&W1p[rw1 * 64 + ((sl1 ^ k1) << 2)]) = rA[i_];                     \
      const int rw2 = u_ >> 2, sl2 = u_ & 3;                                      \
      *(uint4*)(&W2p[rw2 * 16 + ((sl2 ^ ((rw2 >> 1) & 3)) << 2)]) = rB[i_];       \
    }                                                                             \
  }

  FFN_LOAD(0);
  FFN_WRITE(0, 0);
  __syncthreads();

  const int pr0 = 8 * (p >> 2) + (p & 3);
  const int pr1 = pr0 + 4;
  const int key0 = (pr0 & 3) | ((pr0 >> 1) & 12);
  const int key1 = (pr1 & 3) | ((pr1 >> 1) & 12);

  f32x4 acc2[8];
  #pragma unroll
  for (int i = 0; i < 8; ++i) acc2[i] = (f32x4){0.f, 0.f, 0.f, 0.f};
  const f32x4 zacc = {0.f, 0.f, 0.f, 0.f};

  bf16x8 pbv;
  int bPrev = 2, bCur = 0, bNext = 1;

  for (int c = 0; c < 32; ++c) {
    const int bA = c & 1;
    if (c + 1 < 32) FFN_LOAD(c + 1);

    const uint32_t* W1p = W1base + bA * 2048;
    f32x4 s0 = zacc, s1 = zacc;
    #pragma unroll
    for (int kc = 0; kc < 4; ++kc) {
      union { bf16x8 v; uint4 u; } a0, a1;
      a0.u = *(const uint4*)(&W1p[pr0 * 64 + (((kc * 4 + g) ^ key0) << 2)]);
      a1.u = *(const uint4*)(&W1p[pr1 * 64 + (((kc * 4 + g) ^ key1) << 2)]);
      s0 = __builtin_amdgcn_mfma_f32_16x16x32_bf16(a0.v, hsf[kc], s0, 0, 0, 0);
      s1 = __builtin_amdgcn_mfma_f32_16x16x32_bf16(a1.v, hsf[kc], s1, 0, 0, 0);
    }

    if (c > 0) {
      const uint32_t* W2p = W2base + bPrev * 2048;
      #pragma unroll
      for (int ni = 0; ni < 8; ++ni) {
        const int row = ni * 16 + p;
        union { bf16x8 v; uint4 u; } wf;
        wf.u = *(const uint4*)(&W2p[row * 16 + ((g ^ ((row >> 1) & 3)) << 2)]);
        acc2[ni] = __builtin_amdgcn_mfma_f32_16x16x32_bf16(wf.v, pbv, acc2[ni], 0, 0, 0);
      }
    }

    const int nf0 = c * 32;
    const float4 bb0 = *(const float4*)(b1v + nf0 + 8 * g);
    const float4 bb1 = *(const float4*)(b1v + nf0 + 8 * g + 4);
    union { bf16x8 v; uint4 u; } pb;
    pb.u.x = pack2(fmaxf(s0[0] + bb0.x, 0.0f), fmaxf(s0[1] + bb0.y, 0.0f));
    pb.u.y = pack2(fmaxf(s0[2] + bb0.z, 0.0f), fmaxf(s0[3] + bb0.w, 0.0f));
    pb.u.z = pack2(fmaxf(s1[0] + bb1.x, 0.0f), fmaxf(s1[1] + bb1.y, 0.0f));
    pb.u.w = pack2(fmaxf(s1[2] + bb1.z, 0.0f), fmaxf(s1[3] + bb1.w, 0.0f));
    pbv = pb.v;

    if (c + 1 < 32) FFN_WRITE(bA ^ 1, bNext);
    __syncthreads();

    bPrev = bCur; bCur = bNext; bNext = (bNext == 2) ? 0 : bNext + 1;
  }

  { // final GEMM2(31): chunk 31 staged into buf (1+30)%3 = 1
    const uint32_t* W2p = W2base + 1 * 2048;
    #pragma unroll
    for (int ni = 0; ni < 8; ++ni) {
      const int row = ni * 16 + p;
      union { bf16x8 v; uint4 u; } wf;
      wf.u = *(const uint4*)(&W2p[row * 16 + ((g ^ ((row >> 1) & 3)) << 2)]);
      acc2[ni] = __builtin_amdgcn_mfma_f32_16x16x32_bf16(wf.v, pbv, acc2[ni], 0, 0, 0);
    }
  }

  // LN2: residual = h1r (regs)
  float t1 = 0.0f, t2 = 0.0f;
  #pragma unroll
  for (int ni = 0; ni < 8; ++ni) {
    const int nb = ni * 16 + g * 4;
    const float4 bv = *(const float4*)(b2v + nb);
    acc2[ni][0] += bv.x + h1r[ni][0];
    acc2[ni][1] += bv.y + h1r[ni][1];
    acc2[ni][2] += bv.z + h1r[ni][2];
    acc2[ni][3] += bv.w + h1r[ni][3];
    #pragma unroll
    for (int r = 0; r < 4; ++r) {
      t1 += acc2[ni][r];
      t2 += acc2[ni][r] * acc2[ni][r];
    }
  }
  t1 += __shfl_xor(t1, 16); t1 += __shfl_xor(t1, 32);
  t2 += __shfl_xor(t2, 16); t2 += __shfl_xor(t2, 32);
  const float mu2 = t1 * (1.0f / 128.0f);
  const float rs2 = rsqrtf(fmaxf(t2 * (1.0f / 128.0f) - mu2 * mu2, 0.0f) + 1e-5f);
  #pragma unroll
  for (int ni = 0; ni < 8; ++ni) {
    const int nb = ni * 16 + g * 4;
    const float4 gv = *(const float4*)(lng2 + nb);
    const float4 bv = *(const float4*)(lnb2 + nb);
    float c[4];
    c[0] = (acc2[ni][0] - mu2) * rs2 * gv.x + bv.x;
    c[1] = (acc2[ni][1] - mu2) * rs2 * gv.y + bv.y;
    c[2] = (acc2[ni][2] - mu2) * rs2 * gv.z + bv.z;
    c[3] = (acc2[ni][3] - mu2) * rs2 * gv.w + bv.w;
    float4 wv;
    wv.x = c[0]; wv.y = c[1]; wv.z = c[2]; wv.w = c[3];
    *(float4*)(hx + (size_t)m * DD + nb) = wv;
    uint2 wb;
    wb.x = pack2(c[0], c[1]);
    wb.y = pack2(c[2], c[3]);
    *(uint2*)(hb + (size_t)m * DD + nb) = wb;
  }
}

// ---------------- MFMA flash attention v6 (z=2) ----------------
__global__ __launch_bounds__(512) void attn_mfma_kernel(const short* __restrict__ qkvp,
                                                        short* __restrict__ o_out) {
  const int h = blockIdx.x;
  const int b = blockIdx.y;
  const int z = blockIdx.z;
  const int t = threadIdx.x;
  const int wave = t >> 6;
  const int lane = t & 63;
  const int g = lane >> 4;
  const int p = lane & 15;

  __shared__ uint32_t Ks[512 * 8];
  __shared__ uint32_t Vs[16 * 256];

  const short* baseQ = qkvp + ((size_t)(b * 3 + 0) * 8 + h) * 8192;
  const short* baseK = qkvp + ((size_t)(b * 3 + 1) * 8 + h) * 8192;
  const short* baseV = qkvp + ((size_t)(b * 3 + 2) * 8 + h) * 8192;

  { // stage K
    const int row = t;
    const uint4 lo = *(const uint4*)(baseK + row * 16);
    const uint4 hi = *(const uint4*)(baseK + row * 16 + 8);
    const int f = ((row >> 3) & 1) << 2;
    *(uint4*)(Ks + row * 8 + f) = lo;
    *(uint4*)(Ks + row * 8 + (f ^ 4)) = hi;
  }
  { // stage V^T (swizzled scatter)
    const int k = t;
    union { uint4 u[2]; short s[16]; } vv;
    vv.u[0] = *(const uint4*)(baseV + k * 16);
    vv.u[1] = *(const uint4*)(baseV + k * 16 + 8);
    const int wk = k >> 1;
    #pragma unroll
    for (int d = 0; d < 16; ++d) {
      const int word = d * 256 + (wk ^ ((d & 7) << 2));
      ((short*)(Vs + word))[k & 1] = vv.s[d];
    }
  }
  __syncthreads();

  const bf16x8 zfrag = {0, 0, 0, 0, 0, 0, 0, 0};
  const f32x4 zacc = {0.f, 0.f, 0.f, 0.f};

  #pragma unroll
  for (int qi = 0; qi < 2; ++qi) {
    const int qt = z * 16 + wave + qi * 8;
    bf16x8 qf = zfrag;
    if (g < 2) {
      union { bf16x8 v; uint4 w; } qu;
      qu.w = *(const uint4*)(baseQ + (qt * 16 + p) * 16 + g * 8);
      qf = qu.v;
    }

    f32x4 o = zacc;
    float lsum = 0.0f;

    for (int kv = 0; kv < 16; ++kv) {
      bf16x8 ka = zfrag, kb = zfrag;
      if (g < 2) {
        const int r0 = kv * 32 + 8 * (p >> 2) + (p & 3);
        const int r1 = r0 + 4;
        union { bf16x8 v; uint4 w; } u;
        u.w = *(const uint4*)(Ks + r0 * 8 + ((4 * g) ^ (((r0 >> 3) & 1) << 2)));
        ka = u.v;
        u.w = *(const uint4*)(Ks + r1 * 8 + ((4 * g) ^ (((r1 >> 3) & 1) << 2)));
        kb = u.v;
      }
      union { bf16x8 v; uint4 w; } vu;
      vu.w = *(const uint4*)(Vs + p * 256 + ((kv * 16 + g * 4) ^ ((p & 7) << 2)));

      const f32x4 s0 = __builtin_amdgcn_mfma_f32_16x16x32_bf16(ka, qf, zacc, 0, 0, 0);
      const f32x4 s1 = __builtin_amdgcn_mfma_f32_16x16x32_bf16(kb, qf, zacc, 0, 0, 0);

      float sv0[4], sv1[4];
      #pragma unroll
      for (int r = 0; r < 4; ++r) {
        sv0[r] = __builtin_amdgcn_exp2f(s0[r]);
        sv1[r] = __builtin_amdgcn_exp2f(s1[r]);
      }
      #pragma unroll
      for (int r = 0; r < 4; ++r) lsum += sv0[r] + sv1[r];

      union { bf16x8 v; uint4 w; } pu;
      pu.w.x = pack2(sv0[0], sv0[1]);
      pu.w.y = pack2(sv0[2], sv0[3]);
      pu.w.z = pack2(sv1[0], sv1[1]);
      pu.w.w = pack2(sv1[2], sv1[3]);

      o = __builtin_amdgcn_mfma_f32_16x16x32_bf16(pu.v, vu.v, o, 0, 0, 0);
    }

    lsum += __shfl_xor(lsum, 16);
    lsum += __shfl_xor(lsum, 32);
    const float li = 1.0f / lsum;
    #pragma unroll
    for (int r = 0; r < 4; ++r) {
      const float inv = __shfl(li, 4 * g + r);
      o_out[((size_t)(b * SS + qt * 16 + 4 * g + r)) * DD + h * HDIM + p] =
          (short)(pack2(o[r] * inv, 0.0f) & 0xffff);
    }
  }
}

// ---------------- yn = normalize(sigmoid(h) * x0) rowwise -> bf16 ----------------
__global__ __launch_bounds__(256) void mask_norm_kernel(const float* __restrict__ h,
                                                        const float* __restrict__ x0,
                                                        short* __restrict__ yn) {
  const int wave = threadIdx.x >> 6;
  const int lane = threadIdx.x & 63;
  const size_t row = (size_t)blockIdx.x * 4 + wave;
  const float2 hv = ((const float2*)(h + row * DD))[lane];
  const float2 xv = ((const float2*)(x0 + row * DD))[lane];
  const float a = xv.x / (1.0f + __expf(-hv.x));
  const float c = xv.y / (1.0f + __expf(-hv.y));
  float ss = a * a + c * c;
  #pragma unroll
  for (int off = 1; off < 64; off <<= 1) ss += __shfl_xor(ss, off);
  const float inv = 1.0f / fmaxf(sqrtf(ss), 1e-12f);
  ((uint32_t*)yn)[row * 64 + lane] = pack2(a * inv, c * inv);
}

extern "C" void kernel_launch(void* const* d_in, const int* in_sizes, int n_in,
                              void* d_out, int out_size, void* d_ws, size_t ws_size,
                              hipStream_t stream) {
  const float* src  = (const float*)d_in[0];
  const float* Wqkv = (const float*)d_in[1];
  const float* bqkv = (const float*)d_in[2];
  const float* Wo   = (const float*)d_in[3];
  const float* bo   = (const float*)d_in[4];
  const float* ln1g = (const float*)d_in[5];
  const float* ln1b = (const float*)d_in[6];
  const float* W1   = (const float*)d_in[7];
  const float* b1   = (const float*)d_in[8];
  const float* W2   = (const float*)d_in[9];
  const float* b2   = (const float*)d_in[10];
  const float* ln2g = (const float*)d_in[11];
  const float* ln2b = (const float*)d_in[12];
  float* out = (float*)d_out;

  char* W = (char*)d_ws;
  const size_t MB = 1048576;
  float* x0  = (float*)(W);
  float* h   = (float*)(W + 16 * MB);
  short* hb  = (short*)(W + 32 * MB);
  short* qkvp = (short*)(W + 40 * MB);   // 24 MB head-major [b][3][h][s][16]
  short* att = (short*)(W + 128 * MB);
  short* xn  = (short*)(W + 136 * MB);
  short* yn  = (short*)(W + 144 * MB);
  short* wqB = (short*)(W + 152 * MB);
  short* woB = wqB + (size_t)NL * 384 * DD;
  short* w1B = woB + (size_t)NL * DD * DD;
  short* w2B = w1B + (size_t)NL * FFD * DD;
  float* bq2 = (float*)(w2B + (size_t)NL * DD * FFD);

  const dim3 blk(256);
  const int ROWS = BB * SS;

  cvt_qkv_kernel<<<(NL * 384 * 64 + 255) / 256, blk, 0, stream>>>(Wqkv, wqB);
  cvt_kernel<<<(NL * DD * DD / 2 + 255) / 256, blk, 0, stream>>>(Wo, woB, NL * DD * DD / 2);
  cvt_kernel<<<(NL * FFD * DD / 2 + 255) / 256, blk, 0, stream>>>(W1, w1B, NL * FFD * DD / 2);
  cvt_kernel<<<(NL * DD * FFD / 2 + 255) / 256, blk, 0, stream>>>(W2, w2B, NL * DD * FFD / 2);
  scale_bq_kernel<<<(NL * 384 + 255) / 256, blk, 0, stream>>>(bqkv, bq2);

  transpose_rn_kernel<<<ROWS / 4, blk, 0, stream>>>(src, x0, h, hb, xn);

  for (int l = 0; l < NL; ++l) {
    mgemm_qkv<<<dim3(3, ROWS / 128), blk, 0, stream>>>(
        hb, wqB + (size_t)l * 384 * DD, bq2 + l * 384, qkvp);
    attn_mfma_kernel<<<dim3(HH, BB, 2), dim3(512), 0, stream>>>(qkvp, att);
    wo_ffn_ln_kernel<<<dim3(ROWS / 32), dim3(128), 0, stream>>>(
        att, woB + (size_t)l * DD * DD, bo + l * DD, ln1g + l * DD, ln1b + l * DD,
        w1B + (size_t)l * FFD * DD, b1 + l * FFD,
        w2B + (size_t)l * DD * FFD, b2 + l * DD,
        ln2g + l * DD, ln2b + l * DD, h, hb);
  }

  mask_norm_kernel<<<ROWS / 4, blk, 0, stream>>>(h, x0, yn);
  cos2_kernel<<<dim3(4, 8, BB), blk, 0, stream>>>(xn, yn, out);
}

// Round 20
// 533.686 us; speedup vs baseline: 2.2182x; 2.2182x over previous
//
#include <hip/hip_runtime.h>
#include <cstdint>
#include <cstddef>

#define SS 512
#define BB 64
#define DD 128
#define HH 8
#define HDIM 16
#define FFD 1024
#define NL 6

typedef short bf16x8 __attribute__((ext_vector_type(8)));
typedef float f32x4 __attribute__((ext_vector_type(4)));

// hardware packed f32->bf16 (RNE), low16 = a, high16 = b
__device__ inline uint32_t pack2(float a, float b) {
  uint32_t r;
  asm("v_cvt_pk_bf16_f32 %0, %1, %2" : "=v"(r) : "v"(a), "v"(b));
  return r;
}

#define QSCALE 0.36067376022224085f  /* 0.25 * log2(e) */

// ---------------- fp32 -> bf16 convert (weights) ----------------
__global__ __launch_bounds__(256) void cvt_kernel(const float* __restrict__ s,
                                                  short* __restrict__ d, int n2) {
  int i = blockIdx.x * 256 + threadIdx.x;
  if (i < n2) {
    float2 v = ((const float2*)s)[i];
    ((uint32_t*)d)[i] = pack2(v.x, v.y);
  }
}

// qkv weights: scale Q rows (n<128) by 0.25*log2e (score scale folded, log2 domain)
__global__ __launch_bounds__(256) void cvt_qkv_kernel(const float* __restrict__ s,
                                                      short* __restrict__ d) {
  int i = blockIdx.x * 256 + threadIdx.x;
  if (i < NL * 384 * 64) {
    const int within = i % (384 * 64);
    const float sc = (within < 128 * 64) ? QSCALE : 1.0f;
    float2 v = ((const float2*)s)[i];
    ((uint32_t*)d)[i] = pack2(v.x * sc, v.y * sc);
  }
}

__global__ __launch_bounds__(256) void scale_bq_kernel(const float* __restrict__ s,
                                                       float* __restrict__ d) {
  int i = blockIdx.x * 256 + threadIdx.x;
  if (i < NL * 384) {
    const float sc = ((i % 384) < 128) ? QSCALE : 1.0f;
    d[i] = s[i] * sc;
  }
}

// ---------------- transpose+rownorm: (S,B,D)->(B,S,D) x0/h fp32, hb bf16, xn bf16 ----------------
__global__ __launch_bounds__(256) void transpose_rn_kernel(const float* __restrict__ src,
                                                           float* __restrict__ x0,
                                                           float* __restrict__ h,
                                                           short* __restrict__ hb,
                                                           short* __restrict__ xn) {
  const int wave = threadIdx.x >> 6;
  const int lane = threadIdx.x & 63;
  const int row = blockIdx.x * 4 + wave;   // row = b*512 + s
  const int b = row >> 9;
  const int s = row & 511;
  const float2 v = ((const float2*)(src + ((size_t)s * BB + b) * DD))[lane];
  ((float2*)(x0 + (size_t)row * DD))[lane] = v;
  ((float2*)(h + (size_t)row * DD))[lane] = v;
  ((uint32_t*)hb)[(size_t)row * 64 + lane] = pack2(v.x, v.y);
  float ss = v.x * v.x + v.y * v.y;
  #pragma unroll
  for (int off = 1; off < 64; off <<= 1) ss += __shfl_xor(ss, off);
  const float r = rsqrtf(ss);
  ((uint32_t*)xn)[(size_t)row * 64 + lane] = pack2(v.x * r, v.y * r);
}

// ---------------- MFMA GEMM (QKV only): C = A@B^T + bias, head-major permuted out ----------------
__global__ __launch_bounds__(256) void mgemm_qkv(const short* __restrict__ Ab,
                                                 const short* __restrict__ Bw,
                                                 const float* __restrict__ bias,
                                                 short* __restrict__ Cb) {
  __shared__ uint32_t Xs[128 * 32];
  __shared__ uint32_t Wls[128 * 32];
  const int t = threadIdx.x;
  const int wave = t >> 6, lane = t & 63;
  const int g = lane >> 4, p = lane & 15;
  const int wr = wave >> 1, wc = wave & 1;
  const int m0 = blockIdx.y * 128, n0 = blockIdx.x * 128;
  const int K = DD;

  f32x4 acc[4][4];
  #pragma unroll
  for (int i = 0; i < 4; ++i)
    #pragma unroll
    for (int j = 0; j < 4; ++j) acc[i][j] = (f32x4){0.f, 0.f, 0.f, 0.f};

  for (int kt = 0; kt < K; kt += 64) {
    __syncthreads();
    #pragma unroll
    for (int i = 0; i < 4; ++i) {
      const int idx = t + i * 256;
      const int row = idx >> 3, kc = idx & 7;
      const uint4 w = *(const uint4*)(Ab + (size_t)(m0 + row) * K + kt + kc * 8);
      *(uint4*)(Xs + row * 32 + ((kc ^ (row & 7)) << 2)) = w;
      const uint4 u = *(const uint4*)(Bw + (size_t)(n0 + row) * K + kt + kc * 8);
      *(uint4*)(Wls + row * 32 + ((kc ^ (row & 7)) << 2)) = u;
    }
    __syncthreads();
    #pragma unroll
    for (int kc32 = 0; kc32 < 2; ++kc32) {
      bf16x8 xf[4], wf[4];
      #pragma unroll
      for (int mi = 0; mi < 4; ++mi) {
        const int row = wr * 64 + mi * 16 + p;
        union { bf16x8 v; uint4 w; } u;
        u.w = *(const uint4*)(Xs + row * 32 + (((kc32 * 4 + g) ^ (row & 7)) << 2));
        xf[mi] = u.v;
      }
      #pragma unroll
      for (int ni = 0; ni < 4; ++ni) {
        const int row = wc * 64 + ni * 16 + p;
        union { bf16x8 v; uint4 w; } u;
        u.w = *(const uint4*)(Wls + row * 32 + (((kc32 * 4 + g) ^ (row & 7)) << 2));
        wf[ni] = u.v;
      }
      #pragma unroll
      for (int mi = 0; mi < 4; ++mi)
        #pragma unroll
        for (int ni = 0; ni < 4; ++ni)
          acc[mi][ni] = __builtin_amdgcn_mfma_f32_16x16x32_bf16(wf[ni], xf[mi], acc[mi][ni], 0, 0, 0);
    }
  }

  #pragma unroll
  for (int mi = 0; mi < 4; ++mi) {
    const int m = m0 + wr * 64 + mi * 16 + p;
    #pragma unroll
    for (int ni = 0; ni < 4; ++ni) {
      const int nb = n0 + wc * 64 + ni * 16 + g * 4;
      const float4 bv = *(const float4*)(bias + nb);
      float c[4];
      c[0] = acc[mi][ni][0] + bv.x;
      c[1] = acc[mi][ni][1] + bv.y;
      c[2] = acc[mi][ni][2] + bv.z;
      c[3] = acc[mi][ni][3] + bv.w;
      const int bb2 = m >> 9, s = m & 511;
      const int which = nb >> 7, hh = (nb >> 4) & 7, d = nb & 15;
      uint2 w;
      w.x = pack2(c[0], c[1]);
      w.y = pack2(c[2], c[3]);
      *(uint2*)(Cb + ((((size_t)(bb2 * 3 + which) * 8 + hh) * 512 + s) * 16 + d)) = w;
    }
  }
}

// ---------------- Fused cosine-sim pair ----------------
__global__ __launch_bounds__(256) void cos2_kernel(const short* __restrict__ xn,
                                                   const short* __restrict__ yn,
                                                   float* __restrict__ out) {
  __shared__ uint32_t Js[128 * 64];  // 32 KB
  const int t = threadIdx.x;
  const int w = t >> 6, lane = t & 63;
  const int g = lane >> 4, p = lane & 15;
  const int j0 = blockIdx.x * 128;
  const int i0 = blockIdx.y * 64;
  const int b = blockIdx.z;
  const short* xb = xn + (size_t)b * SS * DD;
  const short* yb = yn + (size_t)b * SS * DD;
  const int i = i0 + w * 16 + p;

  // ---- pass 1: xn ----
  bf16x8 af[4];
  #pragma unroll
  for (int kc = 0; kc < 4; ++kc) {
    union { bf16x8 v; uint4 u; } uu;
    uu.u = *(const uint4*)(xb + (size_t)i * DD + kc * 32 + g * 8);
    af[kc] = uu.v;
  }
  #pragma unroll
  for (int q = 0; q < 8; ++q) {
    const int idx = q * 256 + t;
    const int row = idx >> 4, slot = idx & 15;
    const int key = (row & 3) | ((row >> 1) & 12);
    const uint4 u = *(const uint4*)(xb + (size_t)(j0 + row) * DD + slot * 8);
    *(uint4*)(&Js[row * 64 + ((slot ^ key) << 2)]) = u;
  }
  __syncthreads();

  f32x4 acc[8];
  #pragma unroll
  for (int q = 0; q < 8; ++q) acc[q] = (f32x4){0.f, 0.f, 0.f, 0.f};
  #pragma unroll
  for (int kc = 0; kc < 4; ++kc) {
    #pragma unroll
    for (int ni = 0; ni < 8; ++ni) {
      const int row = ni * 16 + p;
      const int key = (row & 3) | ((row >> 1) & 12);
      union { bf16x8 v; uint4 u; } jf;
      jf.u = *(const uint4*)(&Js[row * 64 + (((kc * 4 + g) ^ key) << 2)]);
      acc[ni] = __builtin_amdgcn_mfma_f32_16x16x32_bf16(jf.v, af[kc], acc[ni], 0, 0, 0);
    }
  }
  float prev[8][4];
  #pragma unroll
  for (int ni = 0; ni < 8; ++ni)
    #pragma unroll
    for (int r = 0; r < 4; ++r) prev[ni][r] = fmaxf(acc[ni][r], 1e-6f);
  __syncthreads();

  // ---- pass 2: yn ----
  #pragma unroll
  for (int kc = 0; kc < 4; ++kc) {
    union { bf16x8 v; uint4 u; } uu;
    uu.u = *(const uint4*)(yb + (size_t)i * DD + kc * 32 + g * 8);
    af[kc] = uu.v;
  }
  #pragma unroll
  for (int q = 0; q < 8; ++q) {
    const int idx = q * 256 + t;
    const int row = idx >> 4, slot = idx & 15;
    const int key = (row & 3) | ((row >> 1) & 12);
    const uint4 u = *(const uint4*)(yb + (size_t)(j0 + row) * DD + slot * 8);
    *(uint4*)(&Js[row * 64 + ((slot ^ key) << 2)]) = u;
  }
  __syncthreads();

  #pragma unroll
  for (int q = 0; q < 8; ++q) acc[q] = (f32x4){0.f, 0.f, 0.f, 0.f};
  #pragma unroll
  for (int kc = 0; kc < 4; ++kc) {
    #pragma unroll
    for (int ni = 0; ni < 8; ++ni) {
      const int row = ni * 16 + p;
      const int key = (row & 3) | ((row >> 1) & 12);
      union { bf16x8 v; uint4 u; } jf;
      jf.u = *(const uint4*)(&Js[row * 64 + (((kc * 4 + g) ^ key) << 2)]);
      acc[ni] = __builtin_amdgcn_mfma_f32_16x16x32_bf16(jf.v, af[kc], acc[ni], 0, 0, 0);
    }
  }

  float* ob = out + (size_t)b * SS * SS;
  #pragma unroll
  for (int ni = 0; ni < 8; ++ni) {
    const int j = j0 + ni * 16 + g * 4;
    float4 wv;
    float* pw = &wv.x;
    #pragma unroll
    for (int r = 0; r < 4; ++r) {
      const float v = fmaxf(acc[ni][r], 1e-6f);
      pw[r] = fminf(fmaxf(0.5f * (v + prev[ni][r]), 0.1f), 0.9f);
    }
    *(float4*)(ob + (size_t)i * SS + j) = wv;
  }
}

// ---------------- Fused Wo+LN1+FFN+LN2 (r18 proven config: 256 thr, 40 KB LDS) ----------------
__global__ __launch_bounds__(256) void wo_ffn_ln_kernel(const short* __restrict__ att,
                                                        const short* __restrict__ Wob,
                                                        const float* __restrict__ bov,
                                                        const float* __restrict__ lng1,
                                                        const float* __restrict__ lnb1,
                                                        const short* __restrict__ W1b,
                                                        const float* __restrict__ b1v,
                                                        const short* __restrict__ W2b,
                                                        const float* __restrict__ b2v,
                                                        const float* __restrict__ lng2,
                                                        const float* __restrict__ lnb2,
                                                        float* __restrict__ hx,
                                                        short* __restrict__ hb) {
  __shared__ uint32_t S[10240];      // 40 KB union
  uint32_t* WoLS = S;                // phase A: 8192 words (32 KB)
  uint32_t* Tb   = S;                // transient: 4096 words (16 KB)
  uint32_t* W1base = S;              // 2 bufs x 2048 words (after Tb dead)
  uint32_t* W2base = S + 4096;       // 3 bufs x 2048 words
  const int t = threadIdx.x;
  const int w = t >> 6, lane = t & 63;
  const int g = lane >> 4, p = lane & 15;
  const int m0 = blockIdx.x * 64;
  const int m = m0 + w * 16 + p;
  const int lr = w * 16 + p;
  const int lkey = (lr & 3) | ((lr >> 1) & 12);

  // ---- Phase A: att rows in regs, Wo in LDS ----
  bf16x8 af[4];
  #pragma unroll
  for (int kc = 0; kc < 4; ++kc) {
    union { bf16x8 v; uint4 u; } uu;
    uu.u = *(const uint4*)(att + (size_t)m * DD + kc * 32 + g * 8);
    af[kc] = uu.v;
  }
  #pragma unroll
  for (int i = 0; i < 8; ++i) {
    const int idx = i * 256 + t;
    const int row = idx >> 4, slot = idx & 15;
    const int key = (row & 3) | ((row >> 1) & 12);
    const uint4 u = *(const uint4*)(Wob + (size_t)row * DD + slot * 8);
    *(uint4*)(&WoLS[row * 64 + ((slot ^ key) << 2)]) = u;
  }
  __syncthreads();

  f32x4 acc[8];
  #pragma unroll
  for (int i = 0; i < 8; ++i) acc[i] = (f32x4){0.f, 0.f, 0.f, 0.f};
  #pragma unroll
  for (int kc = 0; kc < 4; ++kc) {
    #pragma unroll
    for (int ni = 0; ni < 8; ++ni) {
      const int row = ni * 16 + p;
      const int key = (row & 3) | ((row >> 1) & 12);
      union { bf16x8 v; uint4 u; } wf;
      wf.u = *(const uint4*)(&WoLS[row * 64 + (((kc * 4 + g) ^ key) << 2)]);
      acc[ni] = __builtin_amdgcn_mfma_f32_16x16x32_bf16(wf.v, af[kc], acc[ni], 0, 0, 0);
    }
  }

  // LN1 (lane-local rows)
  float h1r[8][4];
  float s1r = 0.0f, s2r = 0.0f;
  #pragma unroll
  for (int ni = 0; ni < 8; ++ni) {
    const int nb = ni * 16 + g * 4;
    const float4 rv = *(const float4*)(hx + (size_t)m * DD + nb);
    const float4 bv = *(const float4*)(bov + nb);
    h1r[ni][0] = acc[ni][0] + bv.x + rv.x;
    h1r[ni][1] = acc[ni][1] + bv.y + rv.y;
    h1r[ni][2] = acc[ni][2] + bv.z + rv.z;
    h1r[ni][3] = acc[ni][3] + bv.w + rv.w;
    #pragma unroll
    for (int r = 0; r < 4; ++r) {
      s1r += h1r[ni][r];
      s2r += h1r[ni][r] * h1r[ni][r];
    }
  }
  s1r += __shfl_xor(s1r, 16); s1r += __shfl_xor(s1r, 32);
  s2r += __shfl_xor(s2r, 16); s2r += __shfl_xor(s2r, 32);
  {
    const float mu = s1r * (1.0f / 128.0f);
    const float rs = rsqrtf(fmaxf(s2r * (1.0f / 128.0f) - mu * mu, 0.0f) + 1e-5f);
    #pragma unroll
    for (int ni = 0; ni < 8; ++ni) {
      const int nb = ni * 16 + g * 4;
      const float4 gv = *(const float4*)(lng1 + nb);
      const float4 bv = *(const float4*)(lnb1 + nb);
      h1r[ni][0] = (h1r[ni][0] - mu) * rs * gv.x + bv.x;
      h1r[ni][1] = (h1r[ni][1] - mu) * rs * gv.y + bv.y;
      h1r[ni][2] = (h1r[ni][2] - mu) * rs * gv.z + bv.z;
      h1r[ni][3] = (h1r[ni][3] - mu) * rs * gv.w + bv.w;
    }
  }
  __syncthreads();  // all Wo reads done before Tb overwrites WoLS

  // write h1 (bf16) into Tb
  #pragma unroll
  for (int ni = 0; ni < 8; ++ni) {
    const int w16 = ni * 8 + 2 * g;
    const int slot = w16 >> 2, offs = w16 & 3;
    uint2 pk;
    pk.x = pack2(h1r[ni][0], h1r[ni][1]);
    pk.y = pack2(h1r[ni][2], h1r[ni][3]);
    *(uint2*)(&Tb[lr * 64 + ((slot ^ lkey) << 2) + offs]) = pk;
  }
  __syncthreads();

  // h1 B-frags from Tb (read ONCE; Tb dead after this barrier)
  bf16x8 hsf[4];
  #pragma unroll
  for (int kc = 0; kc < 4; ++kc) {
    union { bf16x8 v; uint4 u; } uu;
    uu.u = *(const uint4*)(&Tb[lr * 64 + (((kc * 4 + g) ^ lkey) << 2)]);
    hsf[kc] = uu.v;
  }
  __syncthreads();

  // ---- Phase B: ffn v3 ----
  uint4 rA0, rA1, rB0, rB1;

#define FFN_LOAD(c)                                                               \
  {                                                                               \
    const int nf0_ = (c) * 32;                                                    \
    rA0 = *(const uint4*)(W1b + (size_t)(nf0_ + (t >> 4)) * DD + (t & 15) * 8);   \
    rA1 = *(const uint4*)(W1b + (size_t)(nf0_ + 16 + (t >> 4)) * DD + (t & 15) * 8); \
    rB0 = *(const uint4*)(W2b + (size_t)(t >> 2) * FFD + nf0_ + (t & 3) * 8);     \
    rB1 = *(const uint4*)(W2b + (size_t)(64 + (t >> 2)) * FFD + nf0_ + (t & 3) * 8); \
  }

#define FFN_WRITE(bufA, bufB)                                                     \
  {                                                                               \
    uint32_t* W1p = W1base + (bufA) * 2048;                                       \
    uint32_t* W2p = W2base + (bufB) * 2048;                                       \
    const int rw0 = t >> 4, sl0 = t & 15;                                         \
    const int k0 = (rw0 & 3) | ((rw0 >> 1) & 12);                                 \
    *(uint4*)(&W1p[rw0 * 64 + ((sl0 ^ k0) << 2)]) = rA0;                          \
    const int rw1 = 16 + rw0;                                                     \
    const int k1 = (rw1 & 3) | ((rw1 >> 1) & 12);                                 \
    *(uint4*)(&W1p[rw1 * 64 + ((sl0 ^ k1) << 2)]) = rA1;                          \
    const int rw2 = t >> 2, sl2 = t & 3;                                          \
    *(uint4*)(&W2p[rw2 * 16 + ((sl2 ^ ((rw2 >> 1) & 3)) << 2)]) = rB0;            \
    const int rw3 = 64 + rw2;                                                     \
    *(uint4*)(&W2p[rw3 * 16 + ((sl2 ^ ((rw3 >> 1) & 3)) << 2)]) = rB1;            \
  }

  FFN_LOAD(0);
  FFN_WRITE(0, 0);
  __syncthreads();

  const int pr0 = 8 * (p >> 2) + (p & 3);
  const int pr1 = pr0 + 4;
  const int key0 = (pr0 & 3) | ((pr0 >> 1) & 12);
  const int key1 = (pr1 & 3) | ((pr1 >> 1) & 12);

  f32x4 acc2[8];
  #pragma unroll
  for (int i = 0; i < 8; ++i) acc2[i] = (f32x4){0.f, 0.f, 0.f, 0.f};
  const f32x4 zacc = {0.f, 0.f, 0.f, 0.f};

  bf16x8 pbv;
  int bPrev = 2, bCur = 0, bNext = 1;

  for (int c = 0; c < 32; ++c) {
    const int bA = c & 1;
    if (c + 1 < 32) FFN_LOAD(c + 1);

    const uint32_t* W1p = W1base + bA * 2048;
    f32x4 s0 = zacc, s1 = zacc;
    #pragma unroll
    for (int kc = 0; kc < 4; ++kc) {
      union { bf16x8 v; uint4 u; } a0, a1;
      a0.u = *(const uint4*)(&W1p[pr0 * 64 + (((kc * 4 + g) ^ key0) << 2)]);
      a1.u = *(const uint4*)(&W1p[pr1 * 64 + (((kc * 4 + g) ^ key1) << 2)]);
      s0 = __builtin_amdgcn_mfma_f32_16x16x32_bf16(a0.v, hsf[kc], s0, 0, 0, 0);
      s1 = __builtin_amdgcn_mfma_f32_16x16x32_bf16(a1.v, hsf[kc], s1, 0, 0, 0);
    }

    if (c > 0) {
      const uint32_t* W2p = W2base + bPrev * 2048;
      #pragma unroll
      for (int ni = 0; ni < 8; ++ni) {
        const int row = ni * 16 + p;
        union { bf16x8 v; uint4 u; } wf;
        wf.u = *(const uint4*)(&W2p[row * 16 + ((g ^ ((row >> 1) & 3)) << 2)]);
        acc2[ni] = __builtin_amdgcn_mfma_f32_16x16x32_bf16(wf.v, pbv, acc2[ni], 0, 0, 0);
      }
    }

    const int nf0 = c * 32;
    const float4 bb0 = *(const float4*)(b1v + nf0 + 8 * g);
    const float4 bb1 = *(const float4*)(b1v + nf0 + 8 * g + 4);
    union { bf16x8 v; uint4 u; } pb;
    pb.u.x = pack2(fmaxf(s0[0] + bb0.x, 0.0f), fmaxf(s0[1] + bb0.y, 0.0f));
    pb.u.y = pack2(fmaxf(s0[2] + bb0.z, 0.0f), fmaxf(s0[3] + bb0.w, 0.0f));
    pb.u.z = pack2(fmaxf(s1[0] + bb1.x, 0.0f), fmaxf(s1[1] + bb1.y, 0.0f));
    pb.u.w = pack2(fmaxf(s1[2] + bb1.z, 0.0f), fmaxf(s1[3] + bb1.w, 0.0f));
    pbv = pb.v;

    if (c + 1 < 32) FFN_WRITE(bA ^ 1, bNext);
    __syncthreads();

    bPrev = bCur; bCur = bNext; bNext = (bNext == 2) ? 0 : bNext + 1;
  }

  { // final GEMM2(31): chunk 31 staged into buf (1+30)%3 = 1
    const uint32_t* W2p = W2base + 1 * 2048;
    #pragma unroll
    for (int ni = 0; ni < 8; ++ni) {
      const int row = ni * 16 + p;
      union { bf16x8 v; uint4 u; } wf;
      wf.u = *(const uint4*)(&W2p[row * 16 + ((g ^ ((row >> 1) & 3)) << 2)]);
      acc2[ni] = __builtin_amdgcn_mfma_f32_16x16x32_bf16(wf.v, pbv, acc2[ni], 0, 0, 0);
    }
  }

  // LN2: residual = h1r (regs)
  float t1 = 0.0f, t2 = 0.0f;
  #pragma unroll
  for (int ni = 0; ni < 8; ++ni) {
    const int nb = ni * 16 + g * 4;
    const float4 bv = *(const float4*)(b2v + nb);
    acc2[ni][0] += bv.x + h1r[ni][0];
    acc2[ni][1] += bv.y + h1r[ni][1];
    acc2[ni][2] += bv.z + h1r[ni][2];
    acc2[ni][3] += bv.w + h1r[ni][3];
    #pragma unroll
    for (int r = 0; r < 4; ++r) {
      t1 += acc2[ni][r];
      t2 += acc2[ni][r] * acc2[ni][r];
    }
  }
  t1 += __shfl_xor(t1, 16); t1 += __shfl_xor(t1, 32);
  t2 += __shfl_xor(t2, 16); t2 += __shfl_xor(t2, 32);
  const float mu2 = t1 * (1.0f / 128.0f);
  const float rs2 = rsqrtf(fmaxf(t2 * (1.0f / 128.0f) - mu2 * mu2, 0.0f) + 1e-5f);
  #pragma unroll
  for (int ni = 0; ni < 8; ++ni) {
    const int nb = ni * 16 + g * 4;
    const float4 gv = *(const float4*)(lng2 + nb);
    const float4 bv = *(const float4*)(lnb2 + nb);
    float c[4];
    c[0] = (acc2[ni][0] - mu2) * rs2 * gv.x + bv.x;
    c[1] = (acc2[ni][1] - mu2) * rs2 * gv.y + bv.y;
    c[2] = (acc2[ni][2] - mu2) * rs2 * gv.z + bv.z;
    c[3] = (acc2[ni][3] - mu2) * rs2 * gv.w + bv.w;
    float4 wv;
    wv.x = c[0]; wv.y = c[1]; wv.z = c[2]; wv.w = c[3];
    *(float4*)(hx + (size_t)m * DD + nb) = wv;
    uint2 wb;
    wb.x = pack2(c[0], c[1]);
    wb.y = pack2(c[2], c[3]);
    *(uint2*)(hb + (size_t)m * DD + nb) = wb;
  }
}

// ---------------- MFMA flash attention v6 (z=2) ----------------
__global__ __launch_bounds__(512) void attn_mfma_kernel(const short* __restrict__ qkvp,
                                                        short* __restrict__ o_out) {
  const int h = blockIdx.x;
  const int b = blockIdx.y;
  const int z = blockIdx.z;
  const int t = threadIdx.x;
  const int wave = t >> 6;
  const int lane = t & 63;
  const int g = lane >> 4;
  const int p = lane & 15;

  __shared__ uint32_t Ks[512 * 8];
  __shared__ uint32_t Vs[16 * 256];

  const short* baseQ = qkvp + ((size_t)(b * 3 + 0) * 8 + h) * 8192;
  const short* baseK = qkvp + ((size_t)(b * 3 + 1) * 8 + h) * 8192;
  const short* baseV = qkvp + ((size_t)(b * 3 + 2) * 8 + h) * 8192;

  { // stage K
    const int row = t;
    const uint4 lo = *(const uint4*)(baseK + row * 16);
    const uint4 hi = *(const uint4*)(baseK + row * 16 + 8);
    const int f = ((row >> 3) & 1) << 2;
    *(uint4*)(Ks + row * 8 + f) = lo;
    *(uint4*)(Ks + row * 8 + (f ^ 4)) = hi;
  }
  { // stage V^T (swizzled scatter)
    const int k = t;
    union { uint4 u[2]; short s[16]; } vv;
    vv.u[0] = *(const uint4*)(baseV + k * 16);
    vv.u[1] = *(const uint4*)(baseV + k * 16 + 8);
    const int wk = k >> 1;
    #pragma unroll
    for (int d = 0; d < 16; ++d) {
      const int word = d * 256 + (wk ^ ((d & 7) << 2));
      ((short*)(Vs + word))[k & 1] = vv.s[d];
    }
  }
  __syncthreads();

  const bf16x8 zfrag = {0, 0, 0, 0, 0, 0, 0, 0};
  const f32x4 zacc = {0.f, 0.f, 0.f, 0.f};

  #pragma unroll
  for (int qi = 0; qi < 2; ++qi) {
    const int qt = z * 16 + wave + qi * 8;
    bf16x8 qf = zfrag;
    if (g < 2) {
      union { bf16x8 v; uint4 w; } qu;
      qu.w = *(const uint4*)(baseQ + (qt * 16 + p) * 16 + g * 8);
      qf = qu.v;
    }

    f32x4 o = zacc;
    float lsum = 0.0f;

    for (int kv = 0; kv < 16; ++kv) {
      bf16x8 ka = zfrag, kb = zfrag;
      if (g < 2) {
        const int r0 = kv * 32 + 8 * (p >> 2) + (p & 3);
        const int r1 = r0 + 4;
        union { bf16x8 v; uint4 w; } u;
        u.w = *(const uint4*)(Ks + r0 * 8 + ((4 * g) ^ (((r0 >> 3) & 1) << 2)));
        ka = u.v;
        u.w = *(const uint4*)(Ks + r1 * 8 + ((4 * g) ^ (((r1 >> 3) & 1) << 2)));
        kb = u.v;
      }
      union { bf16x8 v; uint4 w; } vu;
      vu.w = *(const uint4*)(Vs + p * 256 + ((kv * 16 + g * 4) ^ ((p & 7) << 2)));

      const f32x4 s0 = __builtin_amdgcn_mfma_f32_16x16x32_bf16(ka, qf, zacc, 0, 0, 0);
      const f32x4 s1 = __builtin_amdgcn_mfma_f32_16x16x32_bf16(kb, qf, zacc, 0, 0, 0);

      float sv0[4], sv1[4];
      #pragma unroll
      for (int r = 0; r < 4; ++r) {
        sv0[r] = __builtin_amdgcn_exp2f(s0[r]);
        sv1[r] = __builtin_amdgcn_exp2f(s1[r]);
      }
      #pragma unroll
      for (int r = 0; r < 4; ++r) lsum += sv0[r] + sv1[r];

      union { bf16x8 v; uint4 w; } pu;
      pu.w.x = pack2(sv0[0], sv0[1]);
      pu.w.y = pack2(sv0[2], sv0[3]);
      pu.w.z = pack2(sv1[0], sv1[1]);
      pu.w.w = pack2(sv1[2], sv1[3]);

      o = __builtin_amdgcn_mfma_f32_16x16x32_bf16(pu.v, vu.v, o, 0, 0, 0);
    }

    lsum += __shfl_xor(lsum, 16);
    lsum += __shfl_xor(lsum, 32);
    const float li = 1.0f / lsum;
    #pragma unroll
    for (int r = 0; r < 4; ++r) {
      const float inv = __shfl(li, 4 * g + r);
      o_out[((size_t)(b * SS + qt * 16 + 4 * g + r)) * DD + h * HDIM + p] =
          (short)(pack2(o[r] * inv, 0.0f) & 0xffff);
    }
  }
}

// ---------------- yn = normalize(sigmoid(h) * x0) rowwise -> bf16 ----------------
__global__ __launch_bounds__(256) void mask_norm_kernel(const float* __restrict__ h,
                                                        const float* __restrict__ x0,
                                                        short* __restrict__ yn) {
  const int wave = threadIdx.x >> 6;
  const int lane = threadIdx.x & 63;
  const size_t row = (size_t)blockIdx.x * 4 + wave;
  const float2 hv = ((const float2*)(h + row * DD))[lane];
  const float2 xv = ((const float2*)(x0 + row * DD))[lane];
  const float a = xv.x / (1.0f + __expf(-hv.x));
  const float c = xv.y / (1.0f + __expf(-hv.y));
  float ss = a * a + c * c;
  #pragma unroll
  for (int off = 1; off < 64; off <<= 1) ss += __shfl_xor(ss, off);
  const float inv = 1.0f / fmaxf(sqrtf(ss), 1e-12f);
  ((uint32_t*)yn)[row * 64 + lane] = pack2(a * inv, c * inv);
}

extern "C" void kernel_launch(void* const* d_in, const int* in_sizes, int n_in,
                              void* d_out, int out_size, void* d_ws, size_t ws_size,
                              hipStream_t stream) {
  const float* src  = (const float*)d_in[0];
  const float* Wqkv = (const float*)d_in[1];
  const float* bqkv = (const float*)d_in[2];
  const float* Wo   = (const float*)d_in[3];
  const float* bo   = (const float*)d_in[4];
  const float* ln1g = (const float*)d_in[5];
  const float* ln1b = (const float*)d_in[6];
  const float* W1   = (const float*)d_in[7];
  const float* b1   = (const float*)d_in[8];
  const float* W2   = (const float*)d_in[9];
  const float* b2   = (const float*)d_in[10];
  const float* ln2g = (const float*)d_in[11];
  const float* ln2b = (const float*)d_in[12];
  float* out = (float*)d_out;

  char* W = (char*)d_ws;
  const size_t MB = 1048576;
  float* x0  = (float*)(W);
  float* h   = (float*)(W + 16 * MB);
  short* hb  = (short*)(W + 32 * MB);
  short* qkvp = (short*)(W + 40 * MB);   // 24 MB head-major [b][3][h][s][16]
  short* att = (short*)(W + 128 * MB);
  short* xn  = (short*)(W + 136 * MB);
  short* yn  = (short*)(W + 144 * MB);
  short* wqB = (short*)(W + 152 * MB);
  short* woB = wqB + (size_t)NL * 384 * DD;
  short* w1B = woB + (size_t)NL * DD * DD;
  short* w2B = w1B + (size_t)NL * FFD * DD;
  float* bq2 = (float*)(w2B + (size_t)NL * DD * FFD);

  const dim3 blk(256);
  const int ROWS = BB * SS;

  cvt_qkv_kernel<<<(NL * 384 * 64 + 255) / 256, blk, 0, stream>>>(Wqkv, wqB);
  cvt_kernel<<<(NL * DD * DD / 2 + 255) / 256, blk, 0, stream>>>(Wo, woB, NL * DD * DD / 2);
  cvt_kernel<<<(NL * FFD * DD / 2 + 255) / 256, blk, 0, stream>>>(W1, w1B, NL * FFD * DD / 2);
  cvt_kernel<<<(NL * DD * FFD / 2 + 255) / 256, blk, 0, stream>>>(W2, w2B, NL * DD * FFD / 2);
  scale_bq_kernel<<<(NL * 384 + 255) / 256, blk, 0, stream>>>(bqkv, bq2);

  transpose_rn_kernel<<<ROWS / 4, blk, 0, stream>>>(src, x0, h, hb, xn);

  for (int l = 0; l < NL; ++l) {
    mgemm_qkv<<<dim3(3, ROWS / 128), blk, 0, stream>>>(
        hb, wqB + (size_t)l * 384 * DD, bq2 + l * 384, qkvp);
    attn_mfma_kernel<<<dim3(HH, BB, 2), dim3(512), 0, stream>>>(qkvp, att);
    wo_ffn_ln_kernel<<<dim3(ROWS / 64), blk, 0, stream>>>(
        att, woB + (size_t)l * DD * DD, bo + l * DD, ln1g + l * DD, ln1b + l * DD,
        w1B + (size_t)l * FFD * DD, b1 + l * FFD,
        w2B + (size_t)l * DD * FFD, b2 + l * DD,
        ln2g + l * DD, ln2b + l * DD, h, hb);
  }

  mask_norm_kernel<<<ROWS / 4, blk, 0, stream>>>(h, x0, yn);
  cos2_kernel<<<dim3(4, 8, BB), blk, 0, stream>>>(xn, yn, out);
}

// Round 21
// 522.133 us; speedup vs baseline: 2.2673x; 1.0221x over previous
//
#include <hip/hip_runtime.h>
#include <cstdint>
#include <cstddef>

#define SS 512
#define BB 64
#define DD 128
#define HH 8
#define HDIM 16
#define FFD 1024
#define NL 6

typedef short bf16x8 __attribute__((ext_vector_type(8)));
typedef float f32x4 __attribute__((ext_vector_type(4)));

// hardware packed f32->bf16 (RNE), low16 = a, high16 = b
__device__ inline uint32_t pack2(float a, float b) {
  uint32_t r;
  asm("v_cvt_pk_bf16_f32 %0, %1, %2" : "=v"(r) : "v"(a), "v"(b));
  return r;
}

#define QSCALE 0.36067376022224085f  /* 0.25 * log2(e) */

// ---------------- fp32 -> bf16 convert (weights) ----------------
__global__ __launch_bounds__(256) void cvt_kernel(const float* __restrict__ s,
                                                  short* __restrict__ d, int n2) {
  int i = blockIdx.x * 256 + threadIdx.x;
  if (i < n2) {
    float2 v = ((const float2*)s)[i];
    ((uint32_t*)d)[i] = pack2(v.x, v.y);
  }
}

// qkv weights: scale Q rows (n<128) by 0.25*log2e (score scale folded, log2 domain)
__global__ __launch_bounds__(256) void cvt_qkv_kernel(const float* __restrict__ s,
                                                      short* __restrict__ d) {
  int i = blockIdx.x * 256 + threadIdx.x;
  if (i < NL * 384 * 64) {
    const int within = i % (384 * 64);
    const float sc = (within < 128 * 64) ? QSCALE : 1.0f;
    float2 v = ((const float2*)s)[i];
    ((uint32_t*)d)[i] = pack2(v.x * sc, v.y * sc);
  }
}

__global__ __launch_bounds__(256) void scale_bq_kernel(const float* __restrict__ s,
                                                       float* __restrict__ d) {
  int i = blockIdx.x * 256 + threadIdx.x;
  if (i < NL * 384) {
    const float sc = ((i % 384) < 128) ? QSCALE : 1.0f;
    d[i] = s[i] * sc;
  }
}

// ---------------- transpose+rownorm: (S,B,D)->(B,S,D) x0/h fp32, hb bf16, xn bf16 ----------------
__global__ __launch_bounds__(256) void transpose_rn_kernel(const float* __restrict__ src,
                                                           float* __restrict__ x0,
                                                           float* __restrict__ h,
                                                           short* __restrict__ hb,
                                                           short* __restrict__ xn) {
  const int wave = threadIdx.x >> 6;
  const int lane = threadIdx.x & 63;
  const int row = blockIdx.x * 4 + wave;   // row = b*512 + s
  const int b = row >> 9;
  const int s = row & 511;
  const float2 v = ((const float2*)(src + ((size_t)s * BB + b) * DD))[lane];
  ((float2*)(x0 + (size_t)row * DD))[lane] = v;
  ((float2*)(h + (size_t)row * DD))[lane] = v;
  ((uint32_t*)hb)[(size_t)row * 64 + lane] = pack2(v.x, v.y);
  float ss = v.x * v.x + v.y * v.y;
  #pragma unroll
  for (int off = 1; off < 64; off <<= 1) ss += __shfl_xor(ss, off);
  const float r = rsqrtf(ss);
  ((uint32_t*)xn)[(size_t)row * 64 + lane] = pack2(v.x * r, v.y * r);
}

// ---------------- MFMA GEMM (QKV only): C = A@B^T + bias, head-major permuted out ----------------
__global__ __launch_bounds__(256) void mgemm_qkv(const short* __restrict__ Ab,
                                                 const short* __restrict__ Bw,
                                                 const float* __restrict__ bias,
                                                 short* __restrict__ Cb) {
  __shared__ uint32_t Xs[128 * 32];
  __shared__ uint32_t Wls[128 * 32];
  const int t = threadIdx.x;
  const int wave = t >> 6, lane = t & 63;
  const int g = lane >> 4, p = lane & 15;
  const int wr = wave >> 1, wc = wave & 1;
  const int m0 = blockIdx.y * 128, n0 = blockIdx.x * 128;
  const int K = DD;

  f32x4 acc[4][4];
  #pragma unroll
  for (int i = 0; i < 4; ++i)
    #pragma unroll
    for (int j = 0; j < 4; ++j) acc[i][j] = (f32x4){0.f, 0.f, 0.f, 0.f};

  for (int kt = 0; kt < K; kt += 64) {
    __syncthreads();
    #pragma unroll
    for (int i = 0; i < 4; ++i) {
      const int idx = t + i * 256;
      const int row = idx >> 3, kc = idx & 7;
      const uint4 w = *(const uint4*)(Ab + (size_t)(m0 + row) * K + kt + kc * 8);
      *(uint4*)(Xs + row * 32 + ((kc ^ (row & 7)) << 2)) = w;
      const uint4 u = *(const uint4*)(Bw + (size_t)(n0 + row) * K + kt + kc * 8);
      *(uint4*)(Wls + row * 32 + ((kc ^ (row & 7)) << 2)) = u;
    }
    __syncthreads();
    #pragma unroll
    for (int kc32 = 0; kc32 < 2; ++kc32) {
      bf16x8 xf[4], wf[4];
      #pragma unroll
      for (int mi = 0; mi < 4; ++mi) {
        const int row = wr * 64 + mi * 16 + p;
        union { bf16x8 v; uint4 w; } u;
        u.w = *(const uint4*)(Xs + row * 32 + (((kc32 * 4 + g) ^ (row & 7)) << 2));
        xf[mi] = u.v;
      }
      #pragma unroll
      for (int ni = 0; ni < 4; ++ni) {
        const int row = wc * 64 + ni * 16 + p;
        union { bf16x8 v; uint4 w; } u;
        u.w = *(const uint4*)(Wls + row * 32 + (((kc32 * 4 + g) ^ (row & 7)) << 2));
        wf[ni] = u.v;
      }
      #pragma unroll
      for (int mi = 0; mi < 4; ++mi)
        #pragma unroll
        for (int ni = 0; ni < 4; ++ni)
          acc[mi][ni] = __builtin_amdgcn_mfma_f32_16x16x32_bf16(wf[ni], xf[mi], acc[mi][ni], 0, 0, 0);
    }
  }

  #pragma unroll
  for (int mi = 0; mi < 4; ++mi) {
    const int m = m0 + wr * 64 + mi * 16 + p;
    #pragma unroll
    for (int ni = 0; ni < 4; ++ni) {
      const int nb = n0 + wc * 64 + ni * 16 + g * 4;
      const float4 bv = *(const float4*)(bias + nb);
      float c[4];
      c[0] = acc[mi][ni][0] + bv.x;
      c[1] = acc[mi][ni][1] + bv.y;
      c[2] = acc[mi][ni][2] + bv.z;
      c[3] = acc[mi][ni][3] + bv.w;
      const int bb2 = m >> 9, s = m & 511;
      const int which = nb >> 7, hh = (nb >> 4) & 7, d = nb & 15;
      uint2 w;
      w.x = pack2(c[0], c[1]);
      w.y = pack2(c[2], c[3]);
      *(uint2*)(Cb + ((((size_t)(bb2 * 3 + which) * 8 + hh) * 512 + s) * 16 + d)) = w;
    }
  }
}

// ---------------- Fused cosine-sim pair ----------------
__global__ __launch_bounds__(256) void cos2_kernel(const short* __restrict__ xn,
                                                   const short* __restrict__ yn,
                                                   float* __restrict__ out) {
  __shared__ uint32_t Js[128 * 64];  // 32 KB
  const int t = threadIdx.x;
  const int w = t >> 6, lane = t & 63;
  const int g = lane >> 4, p = lane & 15;
  const int j0 = blockIdx.x * 128;
  const int i0 = blockIdx.y * 64;
  const int b = blockIdx.z;
  const short* xb = xn + (size_t)b * SS * DD;
  const short* yb = yn + (size_t)b * SS * DD;
  const int i = i0 + w * 16 + p;

  // ---- pass 1: xn ----
  bf16x8 af[4];
  #pragma unroll
  for (int kc = 0; kc < 4; ++kc) {
    union { bf16x8 v; uint4 u; } uu;
    uu.u = *(const uint4*)(xb + (size_t)i * DD + kc * 32 + g * 8);
    af[kc] = uu.v;
  }
  #pragma unroll
  for (int q = 0; q < 8; ++q) {
    const int idx = q * 256 + t;
    const int row = idx >> 4, slot = idx & 15;
    const int key = (row & 3) | ((row >> 1) & 12);
    const uint4 u = *(const uint4*)(xb + (size_t)(j0 + row) * DD + slot * 8);
    *(uint4*)(&Js[row * 64 + ((slot ^ key) << 2)]) = u;
  }
  __syncthreads();

  f32x4 acc[8];
  #pragma unroll
  for (int q = 0; q < 8; ++q) acc[q] = (f32x4){0.f, 0.f, 0.f, 0.f};
  #pragma unroll
  for (int kc = 0; kc < 4; ++kc) {
    #pragma unroll
    for (int ni = 0; ni < 8; ++ni) {
      const int row = ni * 16 + p;
      const int key = (row & 3) | ((row >> 1) & 12);
      union { bf16x8 v; uint4 u; } jf;
      jf.u = *(const uint4*)(&Js[row * 64 + (((kc * 4 + g) ^ key) << 2)]);
      acc[ni] = __builtin_amdgcn_mfma_f32_16x16x32_bf16(jf.v, af[kc], acc[ni], 0, 0, 0);
    }
  }
  float prev[8][4];
  #pragma unroll
  for (int ni = 0; ni < 8; ++ni)
    #pragma unroll
    for (int r = 0; r < 4; ++r) prev[ni][r] = fmaxf(acc[ni][r], 1e-6f);
  __syncthreads();

  // ---- pass 2: yn ----
  #pragma unroll
  for (int kc = 0; kc < 4; ++kc) {
    union { bf16x8 v; uint4 u; } uu;
    uu.u = *(const uint4*)(yb + (size_t)i * DD + kc * 32 + g * 8);
    af[kc] = uu.v;
  }
  #pragma unroll
  for (int q = 0; q < 8; ++q) {
    const int idx = q * 256 + t;
    const int row = idx >> 4, slot = idx & 15;
    const int key = (row & 3) | ((row >> 1) & 12);
    const uint4 u = *(const uint4*)(yb + (size_t)(j0 + row) * DD + slot * 8);
    *(uint4*)(&Js[row * 64 + ((slot ^ key) << 2)]) = u;
  }
  __syncthreads();

  #pragma unroll
  for (int q = 0; q < 8; ++q) acc[q] = (f32x4){0.f, 0.f, 0.f, 0.f};
  #pragma unroll
  for (int kc = 0; kc < 4; ++kc) {
    #pragma unroll
    for (int ni = 0; ni < 8; ++ni) {
      const int row = ni * 16 + p;
      const int key = (row & 3) | ((row >> 1) & 12);
      union { bf16x8 v; uint4 u; } jf;
      jf.u = *(const uint4*)(&Js[row * 64 + (((kc * 4 + g) ^ key) << 2)]);
      acc[ni] = __builtin_amdgcn_mfma_f32_16x16x32_bf16(jf.v, af[kc], acc[ni], 0, 0, 0);
    }
  }

  float* ob = out + (size_t)b * SS * SS;
  #pragma unroll
  for (int ni = 0; ni < 8; ++ni) {
    const int j = j0 + ni * 16 + g * 4;
    float4 wv;
    float* pw = &wv.x;
    #pragma unroll
    for (int r = 0; r < 4; ++r) {
      const float v = fmaxf(acc[ni][r], 1e-6f);
      pw[r] = fminf(fmaxf(0.5f * (v + prev[ni][r]), 0.1f), 0.9f);
    }
    *(float4*)(ob + (size_t)i * SS + j) = wv;
  }
}

// ---------------- Fused Wo+LN1+FFN+LN2 (+ optional fused mask_norm on last layer) ----------------
// When ynp != nullptr (last layer): instead of writing hx/hb (dead afterward),
// compute yn = normalize(x0 * sigmoid(h)) directly from the in-register final h
// (same lane-local row + 2-shfl reduce pattern as the LN epilogues; numerics
// identical to the standalone mask_norm which read the same fp32 h values).
__global__ __launch_bounds__(256) void wo_ffn_ln_kernel(const short* __restrict__ att,
                                                        const short* __restrict__ Wob,
                                                        const float* __restrict__ bov,
                                                        const float* __restrict__ lng1,
                                                        const float* __restrict__ lnb1,
                                                        const short* __restrict__ W1b,
                                                        const float* __restrict__ b1v,
                                                        const short* __restrict__ W2b,
                                                        const float* __restrict__ b2v,
                                                        const float* __restrict__ lng2,
                                                        const float* __restrict__ lnb2,
                                                        float* __restrict__ hx,
                                                        short* __restrict__ hb,
                                                        const float* __restrict__ x0p,
                                                        short* __restrict__ ynp) {
  __shared__ uint32_t S[10240];      // 40 KB union
  uint32_t* WoLS = S;                // phase A: 8192 words (32 KB)
  uint32_t* Tb   = S;                // transient: 4096 words (16 KB)
  uint32_t* W1base = S;              // 2 bufs x 2048 words (after Tb dead)
  uint32_t* W2base = S + 4096;       // 3 bufs x 2048 words
  const int t = threadIdx.x;
  const int w = t >> 6, lane = t & 63;
  const int g = lane >> 4, p = lane & 15;
  const int m0 = blockIdx.x * 64;
  const int m = m0 + w * 16 + p;
  const int lr = w * 16 + p;
  const int lkey = (lr & 3) | ((lr >> 1) & 12);

  // ---- Phase A: att rows in regs, Wo in LDS ----
  bf16x8 af[4];
  #pragma unroll
  for (int kc = 0; kc < 4; ++kc) {
    union { bf16x8 v; uint4 u; } uu;
    uu.u = *(const uint4*)(att + (size_t)m * DD + kc * 32 + g * 8);
    af[kc] = uu.v;
  }
  #pragma unroll
  for (int i = 0; i < 8; ++i) {
    const int idx = i * 256 + t;
    const int row = idx >> 4, slot = idx & 15;
    const int key = (row & 3) | ((row >> 1) & 12);
    const uint4 u = *(const uint4*)(Wob + (size_t)row * DD + slot * 8);
    *(uint4*)(&WoLS[row * 64 + ((slot ^ key) << 2)]) = u;
  }
  __syncthreads();

  f32x4 acc[8];
  #pragma unroll
  for (int i = 0; i < 8; ++i) acc[i] = (f32x4){0.f, 0.f, 0.f, 0.f};
  #pragma unroll
  for (int kc = 0; kc < 4; ++kc) {
    #pragma unroll
    for (int ni = 0; ni < 8; ++ni) {
      const int row = ni * 16 + p;
      const int key = (row & 3) | ((row >> 1) & 12);
      union { bf16x8 v; uint4 u; } wf;
      wf.u = *(const uint4*)(&WoLS[row * 64 + (((kc * 4 + g) ^ key) << 2)]);
      acc[ni] = __builtin_amdgcn_mfma_f32_16x16x32_bf16(wf.v, af[kc], acc[ni], 0, 0, 0);
    }
  }

  // LN1 (lane-local rows)
  float h1r[8][4];
  float s1r = 0.0f, s2r = 0.0f;
  #pragma unroll
  for (int ni = 0; ni < 8; ++ni) {
    const int nb = ni * 16 + g * 4;
    const float4 rv = *(const float4*)(hx + (size_t)m * DD + nb);
    const float4 bv = *(const float4*)(bov + nb);
    h1r[ni][0] = acc[ni][0] + bv.x + rv.x;
    h1r[ni][1] = acc[ni][1] + bv.y + rv.y;
    h1r[ni][2] = acc[ni][2] + bv.z + rv.z;
    h1r[ni][3] = acc[ni][3] + bv.w + rv.w;
    #pragma unroll
    for (int r = 0; r < 4; ++r) {
      s1r += h1r[ni][r];
      s2r += h1r[ni][r] * h1r[ni][r];
    }
  }
  s1r += __shfl_xor(s1r, 16); s1r += __shfl_xor(s1r, 32);
  s2r += __shfl_xor(s2r, 16); s2r += __shfl_xor(s2r, 32);
  {
    const float mu = s1r * (1.0f / 128.0f);
    const float rs = rsqrtf(fmaxf(s2r * (1.0f / 128.0f) - mu * mu, 0.0f) + 1e-5f);
    #pragma unroll
    for (int ni = 0; ni < 8; ++ni) {
      const int nb = ni * 16 + g * 4;
      const float4 gv = *(const float4*)(lng1 + nb);
      const float4 bv = *(const float4*)(lnb1 + nb);
      h1r[ni][0] = (h1r[ni][0] - mu) * rs * gv.x + bv.x;
      h1r[ni][1] = (h1r[ni][1] - mu) * rs * gv.y + bv.y;
      h1r[ni][2] = (h1r[ni][2] - mu) * rs * gv.z + bv.z;
      h1r[ni][3] = (h1r[ni][3] - mu) * rs * gv.w + bv.w;
    }
  }
  __syncthreads();  // all Wo reads done before Tb overwrites WoLS

  // write h1 (bf16) into Tb
  #pragma unroll
  for (int ni = 0; ni < 8; ++ni) {
    const int w16 = ni * 8 + 2 * g;
    const int slot = w16 >> 2, offs = w16 & 3;
    uint2 pk;
    pk.x = pack2(h1r[ni][0], h1r[ni][1]);
    pk.y = pack2(h1r[ni][2], h1r[ni][3]);
    *(uint2*)(&Tb[lr * 64 + ((slot ^ lkey) << 2) + offs]) = pk;
  }
  __syncthreads();

  // h1 B-frags from Tb (read ONCE; Tb dead after this barrier)
  bf16x8 hsf[4];
  #pragma unroll
  for (int kc = 0; kc < 4; ++kc) {
    union { bf16x8 v; uint4 u; } uu;
    uu.u = *(const uint4*)(&Tb[lr * 64 + (((kc * 4 + g) ^ lkey) << 2)]);
    hsf[kc] = uu.v;
  }
  __syncthreads();

  // ---- Phase B: ffn v3 ----
  uint4 rA0, rA1, rB0, rB1;

#define FFN_LOAD(c)                                                               \
  {                                                                               \
    const int nf0_ = (c) * 32;                                                    \
    rA0 = *(const uint4*)(W1b + (size_t)(nf0_ + (t >> 4)) * DD + (t & 15) * 8);   \
    rA1 = *(const uint4*)(W1b + (size_t)(nf0_ + 16 + (t >> 4)) * DD + (t & 15) * 8); \
    rB0 = *(const uint4*)(W2b + (size_t)(t >> 2) * FFD + nf0_ + (t & 3) * 8);     \
    rB1 = *(const uint4*)(W2b + (size_t)(64 + (t >> 2)) * FFD + nf0_ + (t & 3) * 8); \
  }

#define FFN_WRITE(bufA, bufB)                                                     \
  {                                                                               \
    uint32_t* W1p = W1base + (bufA) * 2048;                                       \
    uint32_t* W2p = W2base + (bufB) * 2048;                                       \
    const int rw0 = t >> 4, sl0 = t & 15;                                         \
    const int k0 = (rw0 & 3) | ((rw0 >> 1) & 12);                                 \
    *(uint4*)(&W1p[rw0 * 64 + ((sl0 ^ k0) << 2)]) = rA0;                          \
    const int rw1 = 16 + rw0;                                                     \
    const int k1 = (rw1 & 3) | ((rw1 >> 1) & 12);                                 \
    *(uint4*)(&W1p[rw1 * 64 + ((sl0 ^ k1) << 2)]) = rA1;                          \
    const int rw2 = t >> 2, sl2 = t & 3;                                          \
    *(uint4*)(&W2p[rw2 * 16 + ((sl2 ^ ((rw2 >> 1) & 3)) << 2)]) = rB0;            \
    const int rw3 = 64 + rw2;                                                     \
    *(uint4*)(&W2p[rw3 * 16 + ((sl2 ^ ((rw3 >> 1) & 3)) << 2)]) = rB1;            \
  }

  FFN_LOAD(0);
  FFN_WRITE(0, 0);
  __syncthreads();

  const int pr0 = 8 * (p >> 2) + (p & 3);
  const int pr1 = pr0 + 4;
  const int key0 = (pr0 & 3) | ((pr0 >> 1) & 12);
  const int key1 = (pr1 & 3) | ((pr1 >> 1) & 12);

  f32x4 acc2[8];
  #pragma unroll
  for (int i = 0; i < 8; ++i) acc2[i] = (f32x4){0.f, 0.f, 0.f, 0.f};
  const f32x4 zacc = {0.f, 0.f, 0.f, 0.f};

  bf16x8 pbv;
  int bPrev = 2, bCur = 0, bNext = 1;

  for (int c = 0; c < 32; ++c) {
    const int bA = c & 1;
    if (c + 1 < 32) FFN_LOAD(c + 1);

    const uint32_t* W1p = W1base + bA * 2048;
    f32x4 s0 = zacc, s1 = zacc;
    #pragma unroll
    for (int kc = 0; kc < 4; ++kc) {
      union { bf16x8 v; uint4 u; } a0, a1;
      a0.u = *(const uint4*)(&W1p[pr0 * 64 + (((kc * 4 + g) ^ key0) << 2)]);
      a1.u = *(const uint4*)(&W1p[pr1 * 64 + (((kc * 4 + g) ^ key1) << 2)]);
      s0 = __builtin_amdgcn_mfma_f32_16x16x32_bf16(a0.v, hsf[kc], s0, 0, 0, 0);
      s1 = __builtin_amdgcn_mfma_f32_16x16x32_bf16(a1.v, hsf[kc], s1, 0, 0, 0);
    }

    if (c > 0) {
      const uint32_t* W2p = W2base + bPrev * 2048;
      #pragma unroll
      for (int ni = 0; ni < 8; ++ni) {
        const int row = ni * 16 + p;
        union { bf16x8 v; uint4 u; } wf;
        wf.u = *(const uint4*)(&W2p[row * 16 + ((g ^ ((row >> 1) & 3)) << 2)]);
        acc2[ni] = __builtin_amdgcn_mfma_f32_16x16x32_bf16(wf.v, pbv, acc2[ni], 0, 0, 0);
      }
    }

    const int nf0 = c * 32;
    const float4 bb0 = *(const float4*)(b1v + nf0 + 8 * g);
    const float4 bb1 = *(const float4*)(b1v + nf0 + 8 * g + 4);
    union { bf16x8 v; uint4 u; } pb;
    pb.u.x = pack2(fmaxf(s0[0] + bb0.x, 0.0f), fmaxf(s0[1] + bb0.y, 0.0f));
    pb.u.y = pack2(fmaxf(s0[2] + bb0.z, 0.0f), fmaxf(s0[3] + bb0.w, 0.0f));
    pb.u.z = pack2(fmaxf(s1[0] + bb1.x, 0.0f), fmaxf(s1[1] + bb1.y, 0.0f));
    pb.u.w = pack2(fmaxf(s1[2] + bb1.z, 0.0f), fmaxf(s1[3] + bb1.w, 0.0f));
    pbv = pb.v;

    if (c + 1 < 32) FFN_WRITE(bA ^ 1, bNext);
    __syncthreads();

    bPrev = bCur; bCur = bNext; bNext = (bNext == 2) ? 0 : bNext + 1;
  }

  { // final GEMM2(31): chunk 31 staged into buf (1+30)%3 = 1
    const uint32_t* W2p = W2base + 1 * 2048;
    #pragma unroll
    for (int ni = 0; ni < 8; ++ni) {
      const int row = ni * 16 + p;
      union { bf16x8 v; uint4 u; } wf;
      wf.u = *(const uint4*)(&W2p[row * 16 + ((g ^ ((row >> 1) & 3)) << 2)]);
      acc2[ni] = __builtin_amdgcn_mfma_f32_16x16x32_bf16(wf.v, pbv, acc2[ni], 0, 0, 0);
    }
  }

  // LN2: residual = h1r (regs)
  float t1 = 0.0f, t2 = 0.0f;
  #pragma unroll
  for (int ni = 0; ni < 8; ++ni) {
    const int nb = ni * 16 + g * 4;
    const float4 bv = *(const float4*)(b2v + nb);
    acc2[ni][0] += bv.x + h1r[ni][0];
    acc2[ni][1] += bv.y + h1r[ni][1];
    acc2[ni][2] += bv.z + h1r[ni][2];
    acc2[ni][3] += bv.w + h1r[ni][3];
    #pragma unroll
    for (int r = 0; r < 4; ++r) {
      t1 += acc2[ni][r];
      t2 += acc2[ni][r] * acc2[ni][r];
    }
  }
  t1 += __shfl_xor(t1, 16); t1 += __shfl_xor(t1, 32);
  t2 += __shfl_xor(t2, 16); t2 += __shfl_xor(t2, 32);
  const float mu2 = t1 * (1.0f / 128.0f);
  const float rs2 = rsqrtf(fmaxf(t2 * (1.0f / 128.0f) - mu2 * mu2, 0.0f) + 1e-5f);

  if (ynp == nullptr) {
    #pragma unroll
    for (int ni = 0; ni < 8; ++ni) {
      const int nb = ni * 16 + g * 4;
      const float4 gv = *(const float4*)(lng2 + nb);
      const float4 bv = *(const float4*)(lnb2 + nb);
      float c[4];
      c[0] = (acc2[ni][0] - mu2) * rs2 * gv.x + bv.x;
      c[1] = (acc2[ni][1] - mu2) * rs2 * gv.y + bv.y;
      c[2] = (acc2[ni][2] - mu2) * rs2 * gv.z + bv.z;
      c[3] = (acc2[ni][3] - mu2) * rs2 * gv.w + bv.w;
      float4 wv;
      wv.x = c[0]; wv.y = c[1]; wv.z = c[2]; wv.w = c[3];
      *(float4*)(hx + (size_t)m * DD + nb) = wv;
      uint2 wb;
      wb.x = pack2(c[0], c[1]);
      wb.y = pack2(c[2], c[3]);
      *(uint2*)(hb + (size_t)m * DD + nb) = wb;
    }
  } else {
    // last layer: fused mask_norm — yn = normalize(x0 * sigmoid(h_final))
    float av[8][4];
    float ssum = 0.0f;
    #pragma unroll
    for (int ni = 0; ni < 8; ++ni) {
      const int nb = ni * 16 + g * 4;
      const float4 gv = *(const float4*)(lng2 + nb);
      const float4 bv = *(const float4*)(lnb2 + nb);
      const float4 xv = *(const float4*)(x0p + (size_t)m * DD + nb);
      const float hc0 = (acc2[ni][0] - mu2) * rs2 * gv.x + bv.x;
      const float hc1 = (acc2[ni][1] - mu2) * rs2 * gv.y + bv.y;
      const float hc2 = (acc2[ni][2] - mu2) * rs2 * gv.z + bv.z;
      const float hc3 = (acc2[ni][3] - mu2) * rs2 * gv.w + bv.w;
      av[ni][0] = xv.x / (1.0f + __expf(-hc0));
      av[ni][1] = xv.y / (1.0f + __expf(-hc1));
      av[ni][2] = xv.z / (1.0f + __expf(-hc2));
      av[ni][3] = xv.w / (1.0f + __expf(-hc3));
      #pragma unroll
      for (int r = 0; r < 4; ++r) ssum += av[ni][r] * av[ni][r];
    }
    ssum += __shfl_xor(ssum, 16);
    ssum += __shfl_xor(ssum, 32);
    const float inv = 1.0f / fmaxf(sqrtf(ssum), 1e-12f);
    #pragma unroll
    for (int ni = 0; ni < 8; ++ni) {
      const int nb = ni * 16 + g * 4;
      uint2 wb;
      wb.x = pack2(av[ni][0] * inv, av[ni][1] * inv);
      wb.y = pack2(av[ni][2] * inv, av[ni][3] * inv);
      *(uint2*)(ynp + (size_t)m * DD + nb) = wb;
    }
  }
}

// ---------------- MFMA flash attention v6 (z=2) ----------------
__global__ __launch_bounds__(512) void attn_mfma_kernel(const short* __restrict__ qkvp,
                                                        short* __restrict__ o_out) {
  const int h = blockIdx.x;
  const int b = blockIdx.y;
  const int z = blockIdx.z;
  const int t = threadIdx.x;
  const int wave = t >> 6;
  const int lane = t & 63;
  const int g = lane >> 4;
  const int p = lane & 15;

  __shared__ uint32_t Ks[512 * 8];
  __shared__ uint32_t Vs[16 * 256];

  const short* baseQ = qkvp + ((size_t)(b * 3 + 0) * 8 + h) * 8192;
  const short* baseK = qkvp + ((size_t)(b * 3 + 1) * 8 + h) * 8192;
  const short* baseV = qkvp + ((size_t)(b * 3 + 2) * 8 + h) * 8192;

  { // stage K
    const int row = t;
    const uint4 lo = *(const uint4*)(baseK + row * 16);
    const uint4 hi = *(const uint4*)(baseK + row * 16 + 8);
    const int f = ((row >> 3) & 1) << 2;
    *(uint4*)(Ks + row * 8 + f) = lo;
    *(uint4*)(Ks + row * 8 + (f ^ 4)) = hi;
  }
  { // stage V^T (swizzled scatter)
    const int k = t;
    union { uint4 u[2]; short s[16]; } vv;
    vv.u[0] = *(const uint4*)(baseV + k * 16);
    vv.u[1] = *(const uint4*)(baseV + k * 16 + 8);
    const int wk = k >> 1;
    #pragma unroll
    for (int d = 0; d < 16; ++d) {
      const int word = d * 256 + (wk ^ ((d & 7) << 2));
      ((short*)(Vs + word))[k & 1] = vv.s[d];
    }
  }
  __syncthreads();

  const bf16x8 zfrag = {0, 0, 0, 0, 0, 0, 0, 0};
  const f32x4 zacc = {0.f, 0.f, 0.f, 0.f};

  #pragma unroll
  for (int qi = 0; qi < 2; ++qi) {
    const int qt = z * 16 + wave + qi * 8;
    bf16x8 qf = zfrag;
    if (g < 2) {
      union { bf16x8 v; uint4 w; } qu;
      qu.w = *(const uint4*)(baseQ + (qt * 16 + p) * 16 + g * 8);
      qf = qu.v;
    }

    f32x4 o = zacc;
    float lsum = 0.0f;

    for (int kv = 0; kv < 16; ++kv) {
      bf16x8 ka = zfrag, kb = zfrag;
      if (g < 2) {
        const int r0 = kv * 32 + 8 * (p >> 2) + (p & 3);
        const int r1 = r0 + 4;
        union { bf16x8 v; uint4 w; } u;
        u.w = *(const uint4*)(Ks + r0 * 8 + ((4 * g) ^ (((r0 >> 3) & 1) << 2)));
        ka = u.v;
        u.w = *(const uint4*)(Ks + r1 * 8 + ((4 * g) ^ (((r1 >> 3) & 1) << 2)));
        kb = u.v;
      }
      union { bf16x8 v; uint4 w; } vu;
      vu.w = *(const uint4*)(Vs + p * 256 + ((kv * 16 + g * 4) ^ ((p & 7) << 2)));

      const f32x4 s0 = __builtin_amdgcn_mfma_f32_16x16x32_bf16(ka, qf, zacc, 0, 0, 0);
      const f32x4 s1 = __builtin_amdgcn_mfma_f32_16x16x32_bf16(kb, qf, zacc, 0, 0, 0);

      float sv0[4], sv1[4];
      #pragma unroll
      for (int r = 0; r < 4; ++r) {
        sv0[r] = __builtin_amdgcn_exp2f(s0[r]);
        sv1[r] = __builtin_amdgcn_exp2f(s1[r]);
      }
      #pragma unroll
      for (int r = 0; r < 4; ++r) lsum += sv0[r] + sv1[r];

      union { bf16x8 v; uint4 w; } pu;
      pu.w.x = pack2(sv0[0], sv0[1]);
      pu.w.y = pack2(sv0[2], sv0[3]);
      pu.w.z = pack2(sv1[0], sv1[1]);
      pu.w.w = pack2(sv1[2], sv1[3]);

      o = __builtin_amdgcn_mfma_f32_16x16x32_bf16(pu.v, vu.v, o, 0, 0, 0);
    }

    lsum += __shfl_xor(lsum, 16);
    lsum += __shfl_xor(lsum, 32);
    const float li = 1.0f / lsum;
    #pragma unroll
    for (int r = 0; r < 4; ++r) {
      const float inv = __shfl(li, 4 * g + r);
      o_out[((size_t)(b * SS + qt * 16 + 4 * g + r)) * DD + h * HDIM + p] =
          (short)(pack2(o[r] * inv, 0.0f) & 0xffff);
    }
  }
}

extern "C" void kernel_launch(void* const* d_in, const int* in_sizes, int n_in,
                              void* d_out, int out_size, void* d_ws, size_t ws_size,
                              hipStream_t stream) {
  const float* src  = (const float*)d_in[0];
  const float* Wqkv = (const float*)d_in[1];
  const float* bqkv = (const float*)d_in[2];
  const float* Wo   = (const float*)d_in[3];
  const float* bo   = (const float*)d_in[4];
  const float* ln1g = (const float*)d_in[5];
  const float* ln1b = (const float*)d_in[6];
  const float* W1   = (const float*)d_in[7];
  const float* b1   = (const float*)d_in[8];
  const float* W2   = (const float*)d_in[9];
  const float* b2   = (const float*)d_in[10];
  const float* ln2g = (const float*)d_in[11];
  const float* ln2b = (const float*)d_in[12];
  float* out = (float*)d_out;

  char* W = (char*)d_ws;
  const size_t MB = 1048576;
  float* x0  = (float*)(W);
  float* h   = (float*)(W + 16 * MB);
  short* hb  = (short*)(W + 32 * MB);
  short* qkvp = (short*)(W + 40 * MB);   // 24 MB head-major [b][3][h][s][16]
  short* att = (short*)(W + 128 * MB);
  short* xn  = (short*)(W + 136 * MB);
  short* yn  = (short*)(W + 144 * MB);
  short* wqB = (short*)(W + 152 * MB);
  short* woB = wqB + (size_t)NL * 384 * DD;
  short* w1B = woB + (size_t)NL * DD * DD;
  short* w2B = w1B + (size_t)NL * FFD * DD;
  float* bq2 = (float*)(w2B + (size_t)NL * DD * FFD);

  const dim3 blk(256);
  const int ROWS = BB * SS;

  cvt_qkv_kernel<<<(NL * 384 * 64 + 255) / 256, blk, 0, stream>>>(Wqkv, wqB);
  cvt_kernel<<<(NL * DD * DD / 2 + 255) / 256, blk, 0, stream>>>(Wo, woB, NL * DD * DD / 2);
  cvt_kernel<<<(NL * FFD * DD / 2 + 255) / 256, blk, 0, stream>>>(W1, w1B, NL * FFD * DD / 2);
  cvt_kernel<<<(NL * DD * FFD / 2 + 255) / 256, blk, 0, stream>>>(W2, w2B, NL * DD * FFD / 2);
  scale_bq_kernel<<<(NL * 384 + 255) / 256, blk, 0, stream>>>(bqkv, bq2);

  transpose_rn_kernel<<<ROWS / 4, blk, 0, stream>>>(src, x0, h, hb, xn);

  for (int l = 0; l < NL; ++l) {
    mgemm_qkv<<<dim3(3, ROWS / 128), blk, 0, stream>>>(
        hb, wqB + (size_t)l * 384 * DD, bq2 + l * 384, qkvp);
    attn_mfma_kernel<<<dim3(HH, BB, 2), dim3(512), 0, stream>>>(qkvp, att);
    const bool last = (l == NL - 1);
    wo_ffn_ln_kernel<<<dim3(ROWS / 64), blk, 0, stream>>>(
        att, woB + (size_t)l * DD * DD, bo + l * DD, ln1g + l * DD, ln1b + l * DD,
        w1B + (size_t)l * FFD * DD, b1 + l * FFD,
        w2B + (size_t)l * DD * FFD, b2 + l * DD,
        ln2g + l * DD, ln2b + l * DD, h, hb,
        last ? x0 : nullptr, last ? yn : nullptr);
  }

  cos2_kernel<<<dim3(4, 8, BB), blk, 0, stream>>>(xn, yn, out);
}

// Round 22
// 500.281 us; speedup vs baseline: 2.3663x; 1.0437x over previous
//
#include <hip/hip_runtime.h>
#include <cstdint>
#include <cstddef>

#define SS 512
#define BB 64
#define DD 128
#define HH 8
#define HDIM 16
#define FFD 1024
#define NL 6

typedef short bf16x8 __attribute__((ext_vector_type(8)));
typedef float f32x4 __attribute__((ext_vector_type(4)));

// hardware packed f32->bf16 (RNE), low16 = a, high16 = b
__device__ inline uint32_t pack2(float a, float b) {
  uint32_t r;
  asm("v_cvt_pk_bf16_f32 %0, %1, %2" : "=v"(r) : "v"(a), "v"(b));
  return r;
}

#define QSCALE 0.36067376022224085f  /* 0.25 * log2(e) */

// ---------------- fp32 -> bf16 convert (weights) ----------------
__global__ __launch_bounds__(256) void cvt_kernel(const float* __restrict__ s,
                                                  short* __restrict__ d, int n2) {
  int i = blockIdx.x * 256 + threadIdx.x;
  if (i < n2) {
    float2 v = ((const float2*)s)[i];
    ((uint32_t*)d)[i] = pack2(v.x, v.y);
  }
}

// qkv weights: scale Q rows (n<128) by 0.25*log2e (score scale folded, log2 domain)
__global__ __launch_bounds__(256) void cvt_qkv_kernel(const float* __restrict__ s,
                                                      short* __restrict__ d) {
  int i = blockIdx.x * 256 + threadIdx.x;
  if (i < NL * 384 * 64) {
    const int within = i % (384 * 64);
    const float sc = (within < 128 * 64) ? QSCALE : 1.0f;
    float2 v = ((const float2*)s)[i];
    ((uint32_t*)d)[i] = pack2(v.x * sc, v.y * sc);
  }
}

__global__ __launch_bounds__(256) void scale_bq_kernel(const float* __restrict__ s,
                                                       float* __restrict__ d) {
  int i = blockIdx.x * 256 + threadIdx.x;
  if (i < NL * 384) {
    const float sc = ((i % 384) < 128) ? QSCALE : 1.0f;
    d[i] = s[i] * sc;
  }
}

// ---------------- transpose+rownorm: (S,B,D)->(B,S,D) x0/h fp32, hb bf16, xn bf16 ----------------
__global__ __launch_bounds__(256) void transpose_rn_kernel(const float* __restrict__ src,
                                                           float* __restrict__ x0,
                                                           float* __restrict__ h,
                                                           short* __restrict__ hb,
                                                           short* __restrict__ xn) {
  const int wave = threadIdx.x >> 6;
  const int lane = threadIdx.x & 63;
  const int row = blockIdx.x * 4 + wave;   // row = b*512 + s
  const int b = row >> 9;
  const int s = row & 511;
  const float2 v = ((const float2*)(src + ((size_t)s * BB + b) * DD))[lane];
  ((float2*)(x0 + (size_t)row * DD))[lane] = v;
  ((float2*)(h + (size_t)row * DD))[lane] = v;
  ((uint32_t*)hb)[(size_t)row * 64 + lane] = pack2(v.x, v.y);
  float ss = v.x * v.x + v.y * v.y;
  #pragma unroll
  for (int off = 1; off < 64; off <<= 1) ss += __shfl_xor(ss, off);
  const float r = rsqrtf(ss);
  ((uint32_t*)xn)[(size_t)row * 64 + lane] = pack2(v.x * r, v.y * r);
}

// ---------------- MFMA GEMM (QKV layer 0 only): C = A@B^T + bias, head-major out ----------------
__global__ __launch_bounds__(256) void mgemm_qkv(const short* __restrict__ Ab,
                                                 const short* __restrict__ Bw,
                                                 const float* __restrict__ bias,
                                                 short* __restrict__ Cb) {
  __shared__ uint32_t Xs[128 * 32];
  __shared__ uint32_t Wls[128 * 32];
  const int t = threadIdx.x;
  const int wave = t >> 6, lane = t & 63;
  const int g = lane >> 4, p = lane & 15;
  const int wr = wave >> 1, wc = wave & 1;
  const int m0 = blockIdx.y * 128, n0 = blockIdx.x * 128;
  const int K = DD;

  f32x4 acc[4][4];
  #pragma unroll
  for (int i = 0; i < 4; ++i)
    #pragma unroll
    for (int j = 0; j < 4; ++j) acc[i][j] = (f32x4){0.f, 0.f, 0.f, 0.f};

  for (int kt = 0; kt < K; kt += 64) {
    __syncthreads();
    #pragma unroll
    for (int i = 0; i < 4; ++i) {
      const int idx = t + i * 256;
      const int row = idx >> 3, kc = idx & 7;
      const uint4 w = *(const uint4*)(Ab + (size_t)(m0 + row) * K + kt + kc * 8);
      *(uint4*)(Xs + row * 32 + ((kc ^ (row & 7)) << 2)) = w;
      const uint4 u = *(const uint4*)(Bw + (size_t)(n0 + row) * K + kt + kc * 8);
      *(uint4*)(Wls + row * 32 + ((kc ^ (row & 7)) << 2)) = u;
    }
    __syncthreads();
    #pragma unroll
    for (int kc32 = 0; kc32 < 2; ++kc32) {
      bf16x8 xf[4], wf[4];
      #pragma unroll
      for (int mi = 0; mi < 4; ++mi) {
        const int row = wr * 64 + mi * 16 + p;
        union { bf16x8 v; uint4 w; } u;
        u.w = *(const uint4*)(Xs + row * 32 + (((kc32 * 4 + g) ^ (row & 7)) << 2));
        xf[mi] = u.v;
      }
      #pragma unroll
      for (int ni = 0; ni < 4; ++ni) {
        const int row = wc * 64 + ni * 16 + p;
        union { bf16x8 v; uint4 w; } u;
        u.w = *(const uint4*)(Wls + row * 32 + (((kc32 * 4 + g) ^ (row & 7)) << 2));
        wf[ni] = u.v;
      }
      #pragma unroll
      for (int mi = 0; mi < 4; ++mi)
        #pragma unroll
        for (int ni = 0; ni < 4; ++ni)
          acc[mi][ni] = __builtin_amdgcn_mfma_f32_16x16x32_bf16(wf[ni], xf[mi], acc[mi][ni], 0, 0, 0);
    }
  }

  #pragma unroll
  for (int mi = 0; mi < 4; ++mi) {
    const int m = m0 + wr * 64 + mi * 16 + p;
    #pragma unroll
    for (int ni = 0; ni < 4; ++ni) {
      const int nb = n0 + wc * 64 + ni * 16 + g * 4;
      const float4 bv = *(const float4*)(bias + nb);
      float c[4];
      c[0] = acc[mi][ni][0] + bv.x;
      c[1] = acc[mi][ni][1] + bv.y;
      c[2] = acc[mi][ni][2] + bv.z;
      c[3] = acc[mi][ni][3] + bv.w;
      const int bb2 = m >> 9, s = m & 511;
      const int which = nb >> 7, hh = (nb >> 4) & 7, d = nb & 15;
      uint2 w;
      w.x = pack2(c[0], c[1]);
      w.y = pack2(c[2], c[3]);
      *(uint2*)(Cb + ((((size_t)(bb2 * 3 + which) * 8 + hh) * 512 + s) * 16 + d)) = w;
    }
  }
}

// ---------------- Fused cosine-sim pair ----------------
__global__ __launch_bounds__(256) void cos2_kernel(const short* __restrict__ xn,
                                                   const short* __restrict__ yn,
                                                   float* __restrict__ out) {
  __shared__ uint32_t Js[128 * 64];  // 32 KB
  const int t = threadIdx.x;
  const int w = t >> 6, lane = t & 63;
  const int g = lane >> 4, p = lane & 15;
  const int j0 = blockIdx.x * 128;
  const int i0 = blockIdx.y * 64;
  const int b = blockIdx.z;
  const short* xb = xn + (size_t)b * SS * DD;
  const short* yb = yn + (size_t)b * SS * DD;
  const int i = i0 + w * 16 + p;

  // ---- pass 1: xn ----
  bf16x8 af[4];
  #pragma unroll
  for (int kc = 0; kc < 4; ++kc) {
    union { bf16x8 v; uint4 u; } uu;
    uu.u = *(const uint4*)(xb + (size_t)i * DD + kc * 32 + g * 8);
    af[kc] = uu.v;
  }
  #pragma unroll
  for (int q = 0; q < 8; ++q) {
    const int idx = q * 256 + t;
    const int row = idx >> 4, slot = idx & 15;
    const int key = (row & 3) | ((row >> 1) & 12);
    const uint4 u = *(const uint4*)(xb + (size_t)(j0 + row) * DD + slot * 8);
    *(uint4*)(&Js[row * 64 + ((slot ^ key) << 2)]) = u;
  }
  __syncthreads();

  f32x4 acc[8];
  #pragma unroll
  for (int q = 0; q < 8; ++q) acc[q] = (f32x4){0.f, 0.f, 0.f, 0.f};
  #pragma unroll
  for (int kc = 0; kc < 4; ++kc) {
    #pragma unroll
    for (int ni = 0; ni < 8; ++ni) {
      const int row = ni * 16 + p;
      const int key = (row & 3) | ((row >> 1) & 12);
      union { bf16x8 v; uint4 u; } jf;
      jf.u = *(const uint4*)(&Js[row * 64 + (((kc * 4 + g) ^ key) << 2)]);
      acc[ni] = __builtin_amdgcn_mfma_f32_16x16x32_bf16(jf.v, af[kc], acc[ni], 0, 0, 0);
    }
  }
  float prev[8][4];
  #pragma unroll
  for (int ni = 0; ni < 8; ++ni)
    #pragma unroll
    for (int r = 0; r < 4; ++r) prev[ni][r] = fmaxf(acc[ni][r], 1e-6f);
  __syncthreads();

  // ---- pass 2: yn ----
  #pragma unroll
  for (int kc = 0; kc < 4; ++kc) {
    union { bf16x8 v; uint4 u; } uu;
    uu.u = *(const uint4*)(yb + (size_t)i * DD + kc * 32 + g * 8);
    af[kc] = uu.v;
  }
  #pragma unroll
  for (int q = 0; q < 8; ++q) {
    const int idx = q * 256 + t;
    const int row = idx >> 4, slot = idx & 15;
    const int key = (row & 3) | ((row >> 1) & 12);
    const uint4 u = *(const uint4*)(yb + (size_t)(j0 + row) * DD + slot * 8);
    *(uint4*)(&Js[row * 64 + ((slot ^ key) << 2)]) = u;
  }
  __syncthreads();

  #pragma unroll
  for (int q = 0; q < 8; ++q) acc[q] = (f32x4){0.f, 0.f, 0.f, 0.f};
  #pragma unroll
  for (int kc = 0; kc < 4; ++kc) {
    #pragma unroll
    for (int ni = 0; ni < 8; ++ni) {
      const int row = ni * 16 + p;
      const int key = (row & 3) | ((row >> 1) & 12);
      union { bf16x8 v; uint4 u; } jf;
      jf.u = *(const uint4*)(&Js[row * 64 + (((kc * 4 + g) ^ key) << 2)]);
      acc[ni] = __builtin_amdgcn_mfma_f32_16x16x32_bf16(jf.v, af[kc], acc[ni], 0, 0, 0);
    }
  }

  float* ob = out + (size_t)b * SS * SS;
  #pragma unroll
  for (int ni = 0; ni < 8; ++ni) {
    const int j = j0 + ni * 16 + g * 4;
    float4 wv;
    float* pw = &wv.x;
    #pragma unroll
    for (int r = 0; r < 4; ++r) {
      const float v = fmaxf(acc[ni][r], 1e-6f);
      pw[r] = fminf(fmaxf(0.5f * (v + prev[ni][r]), 0.1f), 0.9f);
    }
    *(float4*)(ob + (size_t)i * SS + j) = wv;
  }
}

// ---------------- Fused Wo+LN1+FFN+LN2 + {phase C: next-layer QKV | mask_norm} ----------------
// qkvo != nullptr (layers 0..4): after LN2, write h fp32 (next residual), pass h
// bf16 through Tb (bit-identical to the old hb), and compute next layer's QKV
// via 12x32-row chunks of the verified FFN-GEMM1 machinery, writing head-major.
// ynp != nullptr (layer 5): fused mask_norm instead (r20, verified).
__global__ __launch_bounds__(256) void wo_ffn_ln_kernel(const short* __restrict__ att,
                                                        const short* __restrict__ Wob,
                                                        const float* __restrict__ bov,
                                                        const float* __restrict__ lng1,
                                                        const float* __restrict__ lnb1,
                                                        const short* __restrict__ W1b,
                                                        const float* __restrict__ b1v,
                                                        const short* __restrict__ W2b,
                                                        const float* __restrict__ b2v,
                                                        const float* __restrict__ lng2,
                                                        const float* __restrict__ lnb2,
                                                        float* __restrict__ hx,
                                                        const short* __restrict__ Wqn,
                                                        const float* __restrict__ bqn,
                                                        short* __restrict__ qkvo,
                                                        const float* __restrict__ x0p,
                                                        short* __restrict__ ynp) {
  __shared__ uint32_t S[10240];      // 40 KB union
  uint32_t* WoLS = S;                // phase A: 8192 words (32 KB)
  uint32_t* Tb   = S;                // transient: 4096 words (16 KB)
  uint32_t* W1base = S;              // 2 bufs x 2048 words
  uint32_t* W2base = S + 4096;       // 3 bufs x 2048 words
  const int t = threadIdx.x;
  const int w = t >> 6, lane = t & 63;
  const int g = lane >> 4, p = lane & 15;
  const int m0 = blockIdx.x * 64;
  const int m = m0 + w * 16 + p;
  const int lr = w * 16 + p;
  const int lkey = (lr & 3) | ((lr >> 1) & 12);

  // ---- Phase A: att rows in regs, Wo in LDS ----
  bf16x8 af[4];
  #pragma unroll
  for (int kc = 0; kc < 4; ++kc) {
    union { bf16x8 v; uint4 u; } uu;
    uu.u = *(const uint4*)(att + (size_t)m * DD + kc * 32 + g * 8);
    af[kc] = uu.v;
  }
  #pragma unroll
  for (int i = 0; i < 8; ++i) {
    const int idx = i * 256 + t;
    const int row = idx >> 4, slot = idx & 15;
    const int key = (row & 3) | ((row >> 1) & 12);
    const uint4 u = *(const uint4*)(Wob + (size_t)row * DD + slot * 8);
    *(uint4*)(&WoLS[row * 64 + ((slot ^ key) << 2)]) = u;
  }
  __syncthreads();

  f32x4 acc[8];
  #pragma unroll
  for (int i = 0; i < 8; ++i) acc[i] = (f32x4){0.f, 0.f, 0.f, 0.f};
  #pragma unroll
  for (int kc = 0; kc < 4; ++kc) {
    #pragma unroll
    for (int ni = 0; ni < 8; ++ni) {
      const int row = ni * 16 + p;
      const int key = (row & 3) | ((row >> 1) & 12);
      union { bf16x8 v; uint4 u; } wf;
      wf.u = *(const uint4*)(&WoLS[row * 64 + (((kc * 4 + g) ^ key) << 2)]);
      acc[ni] = __builtin_amdgcn_mfma_f32_16x16x32_bf16(wf.v, af[kc], acc[ni], 0, 0, 0);
    }
  }

  // LN1 (lane-local rows)
  float h1r[8][4];
  float s1r = 0.0f, s2r = 0.0f;
  #pragma unroll
  for (int ni = 0; ni < 8; ++ni) {
    const int nb = ni * 16 + g * 4;
    const float4 rv = *(const float4*)(hx + (size_t)m * DD + nb);
    const float4 bv = *(const float4*)(bov + nb);
    h1r[ni][0] = acc[ni][0] + bv.x + rv.x;
    h1r[ni][1] = acc[ni][1] + bv.y + rv.y;
    h1r[ni][2] = acc[ni][2] + bv.z + rv.z;
    h1r[ni][3] = acc[ni][3] + bv.w + rv.w;
    #pragma unroll
    for (int r = 0; r < 4; ++r) {
      s1r += h1r[ni][r];
      s2r += h1r[ni][r] * h1r[ni][r];
    }
  }
  s1r += __shfl_xor(s1r, 16); s1r += __shfl_xor(s1r, 32);
  s2r += __shfl_xor(s2r, 16); s2r += __shfl_xor(s2r, 32);
  {
    const float mu = s1r * (1.0f / 128.0f);
    const float rs = rsqrtf(fmaxf(s2r * (1.0f / 128.0f) - mu * mu, 0.0f) + 1e-5f);
    #pragma unroll
    for (int ni = 0; ni < 8; ++ni) {
      const int nb = ni * 16 + g * 4;
      const float4 gv = *(const float4*)(lng1 + nb);
      const float4 bv = *(const float4*)(lnb1 + nb);
      h1r[ni][0] = (h1r[ni][0] - mu) * rs * gv.x + bv.x;
      h1r[ni][1] = (h1r[ni][1] - mu) * rs * gv.y + bv.y;
      h1r[ni][2] = (h1r[ni][2] - mu) * rs * gv.z + bv.z;
      h1r[ni][3] = (h1r[ni][3] - mu) * rs * gv.w + bv.w;
    }
  }
  __syncthreads();  // all Wo reads done before Tb overwrites WoLS

  // write h1 (bf16) into Tb
  #pragma unroll
  for (int ni = 0; ni < 8; ++ni) {
    const int w16 = ni * 8 + 2 * g;
    const int slot = w16 >> 2, offs = w16 & 3;
    uint2 pk;
    pk.x = pack2(h1r[ni][0], h1r[ni][1]);
    pk.y = pack2(h1r[ni][2], h1r[ni][3]);
    *(uint2*)(&Tb[lr * 64 + ((slot ^ lkey) << 2) + offs]) = pk;
  }
  __syncthreads();

  // h1 B-frags from Tb (read ONCE; Tb dead after this barrier)
  bf16x8 hsf[4];
  #pragma unroll
  for (int kc = 0; kc < 4; ++kc) {
    union { bf16x8 v; uint4 u; } uu;
    uu.u = *(const uint4*)(&Tb[lr * 64 + (((kc * 4 + g) ^ lkey) << 2)]);
    hsf[kc] = uu.v;
  }
  __syncthreads();

  // ---- Phase B: ffn v3 ----
  uint4 rA0, rA1, rB0, rB1;

#define FFN_LOAD(c)                                                               \
  {                                                                               \
    const int nf0_ = (c) * 32;                                                    \
    rA0 = *(const uint4*)(W1b + (size_t)(nf0_ + (t >> 4)) * DD + (t & 15) * 8);   \
    rA1 = *(const uint4*)(W1b + (size_t)(nf0_ + 16 + (t >> 4)) * DD + (t & 15) * 8); \
    rB0 = *(const uint4*)(W2b + (size_t)(t >> 2) * FFD + nf0_ + (t & 3) * 8);     \
    rB1 = *(const uint4*)(W2b + (size_t)(64 + (t >> 2)) * FFD + nf0_ + (t & 3) * 8); \
  }

#define FFN_WRITE(bufA, bufB)                                                     \
  {                                                                               \
    uint32_t* W1p = W1base + (bufA) * 2048;                                       \
    uint32_t* W2p = W2base + (bufB) * 2048;                                       \
    const int rw0 = t >> 4, sl0 = t & 15;                                         \
    const int k0 = (rw0 & 3) | ((rw0 >> 1) & 12);                                 \
    *(uint4*)(&W1p[rw0 * 64 + ((sl0 ^ k0) << 2)]) = rA0;                          \
    const int rw1 = 16 + rw0;                                                     \
    const int k1 = (rw1 & 3) | ((rw1 >> 1) & 12);                                 \
    *(uint4*)(&W1p[rw1 * 64 + ((sl0 ^ k1) << 2)]) = rA1;                          \
    const int rw2 = t >> 2, sl2 = t & 3;                                          \
    *(uint4*)(&W2p[rw2 * 16 + ((sl2 ^ ((rw2 >> 1) & 3)) << 2)]) = rB0;            \
    const int rw3 = 64 + rw2;                                                     \
    *(uint4*)(&W2p[rw3 * 16 + ((sl2 ^ ((rw3 >> 1) & 3)) << 2)]) = rB1;            \
  }

  FFN_LOAD(0);
  FFN_WRITE(0, 0);
  __syncthreads();

  const int pr0 = 8 * (p >> 2) + (p & 3);
  const int pr1 = pr0 + 4;
  const int key0 = (pr0 & 3) | ((pr0 >> 1) & 12);
  const int key1 = (pr1 & 3) | ((pr1 >> 1) & 12);

  f32x4 acc2[8];
  #pragma unroll
  for (int i = 0; i < 8; ++i) acc2[i] = (f32x4){0.f, 0.f, 0.f, 0.f};
  const f32x4 zacc = {0.f, 0.f, 0.f, 0.f};

  bf16x8 pbv;
  int bPrev = 2, bCur = 0, bNext = 1;

  for (int c = 0; c < 32; ++c) {
    const int bA = c & 1;
    if (c + 1 < 32) FFN_LOAD(c + 1);

    const uint32_t* W1p = W1base + bA * 2048;
    f32x4 s0 = zacc, s1 = zacc;
    #pragma unroll
    for (int kc = 0; kc < 4; ++kc) {
      union { bf16x8 v; uint4 u; } a0, a1;
      a0.u = *(const uint4*)(&W1p[pr0 * 64 + (((kc * 4 + g) ^ key0) << 2)]);
      a1.u = *(const uint4*)(&W1p[pr1 * 64 + (((kc * 4 + g) ^ key1) << 2)]);
      s0 = __builtin_amdgcn_mfma_f32_16x16x32_bf16(a0.v, hsf[kc], s0, 0, 0, 0);
      s1 = __builtin_amdgcn_mfma_f32_16x16x32_bf16(a1.v, hsf[kc], s1, 0, 0, 0);
    }

    if (c > 0) {
      const uint32_t* W2p = W2base + bPrev * 2048;
      #pragma unroll
      for (int ni = 0; ni < 8; ++ni) {
        const int row = ni * 16 + p;
        union { bf16x8 v; uint4 u; } wf;
        wf.u = *(const uint4*)(&W2p[row * 16 + ((g ^ ((row >> 1) & 3)) << 2)]);
        acc2[ni] = __builtin_amdgcn_mfma_f32_16x16x32_bf16(wf.v, pbv, acc2[ni], 0, 0, 0);
      }
    }

    const int nf0 = c * 32;
    const float4 bb0 = *(const float4*)(b1v + nf0 + 8 * g);
    const float4 bb1 = *(const float4*)(b1v + nf0 + 8 * g + 4);
    union { bf16x8 v; uint4 u; } pb;
    pb.u.x = pack2(fmaxf(s0[0] + bb0.x, 0.0f), fmaxf(s0[1] + bb0.y, 0.0f));
    pb.u.y = pack2(fmaxf(s0[2] + bb0.z, 0.0f), fmaxf(s0[3] + bb0.w, 0.0f));
    pb.u.z = pack2(fmaxf(s1[0] + bb1.x, 0.0f), fmaxf(s1[1] + bb1.y, 0.0f));
    pb.u.w = pack2(fmaxf(s1[2] + bb1.z, 0.0f), fmaxf(s1[3] + bb1.w, 0.0f));
    pbv = pb.v;

    if (c + 1 < 32) FFN_WRITE(bA ^ 1, bNext);
    __syncthreads();

    bPrev = bCur; bCur = bNext; bNext = (bNext == 2) ? 0 : bNext + 1;
  }

  { // final GEMM2(31): chunk 31 staged into buf (1+30)%3 = 1
    const uint32_t* W2p = W2base + 1 * 2048;
    #pragma unroll
    for (int ni = 0; ni < 8; ++ni) {
      const int row = ni * 16 + p;
      union { bf16x8 v; uint4 u; } wf;
      wf.u = *(const uint4*)(&W2p[row * 16 + ((g ^ ((row >> 1) & 3)) << 2)]);
      acc2[ni] = __builtin_amdgcn_mfma_f32_16x16x32_bf16(wf.v, pbv, acc2[ni], 0, 0, 0);
    }
  }

  // LN2: residual = h1r (regs)
  float t1 = 0.0f, t2 = 0.0f;
  #pragma unroll
  for (int ni = 0; ni < 8; ++ni) {
    const int nb = ni * 16 + g * 4;
    const float4 bv = *(const float4*)(b2v + nb);
    acc2[ni][0] += bv.x + h1r[ni][0];
    acc2[ni][1] += bv.y + h1r[ni][1];
    acc2[ni][2] += bv.z + h1r[ni][2];
    acc2[ni][3] += bv.w + h1r[ni][3];
    #pragma unroll
    for (int r = 0; r < 4; ++r) {
      t1 += acc2[ni][r];
      t2 += acc2[ni][r] * acc2[ni][r];
    }
  }
  t1 += __shfl_xor(t1, 16); t1 += __shfl_xor(t1, 32);
  t2 += __shfl_xor(t2, 16); t2 += __shfl_xor(t2, 32);
  const float mu2 = t1 * (1.0f / 128.0f);
  const float rs2 = rsqrtf(fmaxf(t2 * (1.0f / 128.0f) - mu2 * mu2, 0.0f) + 1e-5f);

  if (ynp != nullptr) {
    // last layer: fused mask_norm — yn = normalize(x0 * sigmoid(h_final))
    float av[8][4];
    float ssum = 0.0f;
    #pragma unroll
    for (int ni = 0; ni < 8; ++ni) {
      const int nb = ni * 16 + g * 4;
      const float4 gv = *(const float4*)(lng2 + nb);
      const float4 bv = *(const float4*)(lnb2 + nb);
      const float4 xv = *(const float4*)(x0p + (size_t)m * DD + nb);
      const float hc0 = (acc2[ni][0] - mu2) * rs2 * gv.x + bv.x;
      const float hc1 = (acc2[ni][1] - mu2) * rs2 * gv.y + bv.y;
      const float hc2 = (acc2[ni][2] - mu2) * rs2 * gv.z + bv.z;
      const float hc3 = (acc2[ni][3] - mu2) * rs2 * gv.w + bv.w;
      av[ni][0] = xv.x / (1.0f + __expf(-hc0));
      av[ni][1] = xv.y / (1.0f + __expf(-hc1));
      av[ni][2] = xv.z / (1.0f + __expf(-hc2));
      av[ni][3] = xv.w / (1.0f + __expf(-hc3));
      #pragma unroll
      for (int r = 0; r < 4; ++r) ssum += av[ni][r] * av[ni][r];
    }
    ssum += __shfl_xor(ssum, 16);
    ssum += __shfl_xor(ssum, 32);
    const float inv = 1.0f / fmaxf(sqrtf(ssum), 1e-12f);
    #pragma unroll
    for (int ni = 0; ni < 8; ++ni) {
      const int nb = ni * 16 + g * 4;
      uint2 wb;
      wb.x = pack2(av[ni][0] * inv, av[ni][1] * inv);
      wb.y = pack2(av[ni][2] * inv, av[ni][3] * inv);
      *(uint2*)(ynp + (size_t)m * DD + nb) = wb;
    }
    return;
  }

  // layers 0..4: write hx fp32 + pack new-h bf16 into h1r, write Tb, phase C
  #pragma unroll
  for (int ni = 0; ni < 8; ++ni) {
    const int nb = ni * 16 + g * 4;
    const float4 gv = *(const float4*)(lng2 + nb);
    const float4 bv = *(const float4*)(lnb2 + nb);
    h1r[ni][0] = (acc2[ni][0] - mu2) * rs2 * gv.x + bv.x;
    h1r[ni][1] = (acc2[ni][1] - mu2) * rs2 * gv.y + bv.y;
    h1r[ni][2] = (acc2[ni][2] - mu2) * rs2 * gv.z + bv.z;
    h1r[ni][3] = (acc2[ni][3] - mu2) * rs2 * gv.w + bv.w;
    float4 wv;
    wv.x = h1r[ni][0]; wv.y = h1r[ni][1]; wv.z = h1r[ni][2]; wv.w = h1r[ni][3];
    *(float4*)(hx + (size_t)m * DD + nb) = wv;
  }

  // Tb (= W1base region): W1 buf1 reads finished at c=31 in-loop barrier; final
  // GEMM2 reads only W2base. Per-lane rows disjoint -> safe to write, then barrier.
  #pragma unroll
  for (int ni = 0; ni < 8; ++ni) {
    const int w16 = ni * 8 + 2 * g;
    const int slot = w16 >> 2, offs = w16 & 3;
    uint2 pk;
    pk.x = pack2(h1r[ni][0], h1r[ni][1]);
    pk.y = pack2(h1r[ni][2], h1r[ni][3]);
    *(uint2*)(&Tb[lr * 64 + ((slot ^ lkey) << 2) + offs]) = pk;
  }
  __syncthreads();

  #pragma unroll
  for (int kc = 0; kc < 4; ++kc) {
    union { bf16x8 v; uint4 u; } uu;
    uu.u = *(const uint4*)(&Tb[lr * 64 + (((kc * 4 + g) ^ lkey) << 2)]);
    hsf[kc] = uu.v;
  }
  __syncthreads();

  // ---- Phase C: next-layer QKV, 12 chunks of 32 n-rows (FFN GEMM1 machinery) ----
#define QKV_LOAD(c)                                                               \
  {                                                                               \
    const int nf0_ = (c) * 32;                                                    \
    rA0 = *(const uint4*)(Wqn + (size_t)(nf0_ + (t >> 4)) * DD + (t & 15) * 8);   \
    rA1 = *(const uint4*)(Wqn + (size_t)(nf0_ + 16 + (t >> 4)) * DD + (t & 15) * 8); \
  }

#define QKV_WRITE(bufA)                                                           \
  {                                                                               \
    uint32_t* W1p = W1base + (bufA) * 2048;                                       \
    const int rw0 = t >> 4, sl0 = t & 15;                                         \
    const int k0 = (rw0 & 3) | ((rw0 >> 1) & 12);                                 \
    *(uint4*)(&W1p[rw0 * 64 + ((sl0 ^ k0) << 2)]) = rA0;                          \
    const int rw1 = 16 + rw0;                                                     \
    const int k1 = (rw1 & 3) | ((rw1 >> 1) & 12);                                 \
    *(uint4*)(&W1p[rw1 * 64 + ((sl0 ^ k1) << 2)]) = rA1;                          \
  }

  QKV_LOAD(0);
  QKV_WRITE(0);
  __syncthreads();

  const int bb2 = m >> 9, sm = m & 511;
  for (int c = 0; c < 12; ++c) {
    const int bA = c & 1;
    if (c + 1 < 12) QKV_LOAD(c + 1);

    const uint32_t* W1p = W1base + bA * 2048;
    f32x4 s0 = zacc, s1 = zacc;
    #pragma unroll
    for (int kc = 0; kc < 4; ++kc) {
      union { bf16x8 v; uint4 u; } a0, a1;
      a0.u = *(const uint4*)(&W1p[pr0 * 64 + (((kc * 4 + g) ^ key0) << 2)]);
      a1.u = *(const uint4*)(&W1p[pr1 * 64 + (((kc * 4 + g) ^ key1) << 2)]);
      s0 = __builtin_amdgcn_mfma_f32_16x16x32_bf16(a0.v, hsf[kc], s0, 0, 0, 0);
      s1 = __builtin_amdgcn_mfma_f32_16x16x32_bf16(a1.v, hsf[kc], s1, 0, 0, 0);
    }

    // lane (g,p): s0[r] = qkv[m][n0q+r], s1[r] = qkv[m][n0q+4+r], n0q = c*32+8g
    const int n0q = c * 32 + 8 * g;
    const float4 b0 = *(const float4*)(bqn + n0q);
    const float4 b4 = *(const float4*)(bqn + n0q + 4);
    const int which = n0q >> 7, hh = (n0q >> 4) & 7, d0 = n0q & 15;
    short* base = qkvo + ((((size_t)(bb2 * 3 + which) * 8 + hh) * 512 + sm) * 16 + d0);
    uint2 w0, w1;
    w0.x = pack2(s0[0] + b0.x, s0[1] + b0.y);
    w0.y = pack2(s0[2] + b0.z, s0[3] + b0.w);
    w1.x = pack2(s1[0] + b4.x, s1[1] + b4.y);
    w1.y = pack2(s1[2] + b4.z, s1[3] + b4.w);
    *(uint2*)(base) = w0;
    *(uint2*)(base + 4) = w1;

    if (c + 1 < 12) QKV_WRITE(bA ^ 1);
    __syncthreads();
  }
}

// ---------------- MFMA flash attention v6 (z=2) ----------------
__global__ __launch_bounds__(512) void attn_mfma_kernel(const short* __restrict__ qkvp,
                                                        short* __restrict__ o_out) {
  const int h = blockIdx.x;
  const int b = blockIdx.y;
  const int z = blockIdx.z;
  const int t = threadIdx.x;
  const int wave = t >> 6;
  const int lane = t & 63;
  const int g = lane >> 4;
  const int p = lane & 15;

  __shared__ uint32_t Ks[512 * 8];
  __shared__ uint32_t Vs[16 * 256];

  const short* baseQ = qkvp + ((size_t)(b * 3 + 0) * 8 + h) * 8192;
  const short* baseK = qkvp + ((size_t)(b * 3 + 1) * 8 + h) * 8192;
  const short* baseV = qkvp + ((size_t)(b * 3 + 2) * 8 + h) * 8192;

  { // stage K
    const int row = t;
    const uint4 lo = *(const uint4*)(baseK + row * 16);
    const uint4 hi = *(const uint4*)(baseK + row * 16 + 8);
    const int f = ((row >> 3) & 1) << 2;
    *(uint4*)(Ks + row * 8 + f) = lo;
    *(uint4*)(Ks + row * 8 + (f ^ 4)) = hi;
  }
  { // stage V^T (swizzled scatter)
    const int k = t;
    union { uint4 u[2]; short s[16]; } vv;
    vv.u[0] = *(const uint4*)(baseV + k * 16);
    vv.u[1] = *(const uint4*)(baseV + k * 16 + 8);
    const int wk = k >> 1;
    #pragma unroll
    for (int d = 0; d < 16; ++d) {
      const int word = d * 256 + (wk ^ ((d & 7) << 2));
      ((short*)(Vs + word))[k & 1] = vv.s[d];
    }
  }
  __syncthreads();

  const bf16x8 zfrag = {0, 0, 0, 0, 0, 0, 0, 0};
  const f32x4 zacc = {0.f, 0.f, 0.f, 0.f};

  #pragma unroll
  for (int qi = 0; qi < 2; ++qi) {
    const int qt = z * 16 + wave + qi * 8;
    bf16x8 qf = zfrag;
    if (g < 2) {
      union { bf16x8 v; uint4 w; } qu;
      qu.w = *(const uint4*)(baseQ + (qt * 16 + p) * 16 + g * 8);
      qf = qu.v;
    }

    f32x4 o = zacc;
    float lsum = 0.0f;

    for (int kv = 0; kv < 16; ++kv) {
      bf16x8 ka = zfrag, kb = zfrag;
      if (g < 2) {
        const int r0 = kv * 32 + 8 * (p >> 2) + (p & 3);
        const int r1 = r0 + 4;
        union { bf16x8 v; uint4 w; } u;
        u.w = *(const uint4*)(Ks + r0 * 8 + ((4 * g) ^ (((r0 >> 3) & 1) << 2)));
        ka = u.v;
        u.w = *(const uint4*)(Ks + r1 * 8 + ((4 * g) ^ (((r1 >> 3) & 1) << 2)));
        kb = u.v;
      }
      union { bf16x8 v; uint4 w; } vu;
      vu.w = *(const uint4*)(Vs + p * 256 + ((kv * 16 + g * 4) ^ ((p & 7) << 2)));

      const f32x4 s0 = __builtin_amdgcn_mfma_f32_16x16x32_bf16(ka, qf, zacc, 0, 0, 0);
      const f32x4 s1 = __builtin_amdgcn_mfma_f32_16x16x32_bf16(kb, qf, zacc, 0, 0, 0);

      float sv0[4], sv1[4];
      #pragma unroll
      for (int r = 0; r < 4; ++r) {
        sv0[r] = __builtin_amdgcn_exp2f(s0[r]);
        sv1[r] = __builtin_amdgcn_exp2f(s1[r]);
      }
      #pragma unroll
      for (int r = 0; r < 4; ++r) lsum += sv0[r] + sv1[r];

      union { bf16x8 v; uint4 w; } pu;
      pu.w.x = pack2(sv0[0], sv0[1]);
      pu.w.y = pack2(sv0[2], sv0[3]);
      pu.w.z = pack2(sv1[0], sv1[1]);
      pu.w.w = pack2(sv1[2], sv1[3]);

      o = __builtin_amdgcn_mfma_f32_16x16x32_bf16(pu.v, vu.v, o, 0, 0, 0);
    }

    lsum += __shfl_xor(lsum, 16);
    lsum += __shfl_xor(lsum, 32);
    const float li = 1.0f / lsum;
    #pragma unroll
    for (int r = 0; r < 4; ++r) {
      const float inv = __shfl(li, 4 * g + r);
      o_out[((size_t)(b * SS + qt * 16 + 4 * g + r)) * DD + h * HDIM + p] =
          (short)(pack2(o[r] * inv, 0.0f) & 0xffff);
    }
  }
}

extern "C" void kernel_launch(void* const* d_in, const int* in_sizes, int n_in,
                              void* d_out, int out_size, void* d_ws, size_t ws_size,
                              hipStream_t stream) {
  const float* src  = (const float*)d_in[0];
  const float* Wqkv = (const float*)d_in[1];
  const float* bqkv = (const float*)d_in[2];
  const float* Wo   = (const float*)d_in[3];
  const float* bo   = (const float*)d_in[4];
  const float* ln1g = (const float*)d_in[5];
  const float* ln1b = (const float*)d_in[6];
  const float* W1   = (const float*)d_in[7];
  const float* b1   = (const float*)d_in[8];
  const float* W2   = (const float*)d_in[9];
  const float* b2   = (const float*)d_in[10];
  const float* ln2g = (const float*)d_in[11];
  const float* ln2b = (const float*)d_in[12];
  float* out = (float*)d_out;

  char* W = (char*)d_ws;
  const size_t MB = 1048576;
  float* x0  = (float*)(W);
  float* h   = (float*)(W + 16 * MB);
  short* hb  = (short*)(W + 32 * MB);
  short* qkvp = (short*)(W + 40 * MB);   // 24 MB head-major [b][3][h][s][16]
  short* att = (short*)(W + 128 * MB);
  short* xn  = (short*)(W + 136 * MB);
  short* yn  = (short*)(W + 144 * MB);
  short* wqB = (short*)(W + 152 * MB);
  short* woB = wqB + (size_t)NL * 384 * DD;
  short* w1B = woB + (size_t)NL * DD * DD;
  short* w2B = w1B + (size_t)NL * FFD * DD;
  float* bq2 = (float*)(w2B + (size_t)NL * DD * FFD);

  const dim3 blk(256);
  const int ROWS = BB * SS;

  cvt_qkv_kernel<<<(NL * 384 * 64 + 255) / 256, blk, 0, stream>>>(Wqkv, wqB);
  cvt_kernel<<<(NL * DD * DD / 2 + 255) / 256, blk, 0, stream>>>(Wo, woB, NL * DD * DD / 2);
  cvt_kernel<<<(NL * FFD * DD / 2 + 255) / 256, blk, 0, stream>>>(W1, w1B, NL * FFD * DD / 2);
  cvt_kernel<<<(NL * DD * FFD / 2 + 255) / 256, blk, 0, stream>>>(W2, w2B, NL * DD * FFD / 2);
  scale_bq_kernel<<<(NL * 384 + 255) / 256, blk, 0, stream>>>(bqkv, bq2);

  transpose_rn_kernel<<<ROWS / 4, blk, 0, stream>>>(src, x0, h, hb, xn);

  // layer 0 QKV from hb (transpose output)
  mgemm_qkv<<<dim3(3, ROWS / 128), blk, 0, stream>>>(hb, wqB, bq2, qkvp);

  for (int l = 0; l < NL; ++l) {
    attn_mfma_kernel<<<dim3(HH, BB, 2), dim3(512), 0, stream>>>(qkvp, att);
    const bool last = (l == NL - 1);
    wo_ffn_ln_kernel<<<dim3(ROWS / 64), blk, 0, stream>>>(
        att, woB + (size_t)l * DD * DD, bo + l * DD, ln1g + l * DD, ln1b + l * DD,
        w1B + (size_t)l * FFD * DD, b1 + l * FFD,
        w2B + (size_t)l * DD * FFD, b2 + l * DD,
        ln2g + l * DD, ln2b + l * DD, h,
        last ? nullptr : (wqB + (size_t)(l + 1) * 384 * DD),
        last ? nullptr : (bq2 + (l + 1) * 384),
        last ? nullptr : qkvp,
        last ? x0 : nullptr, last ? yn : nullptr);
  }

  cos2_kernel<<<dim3(4, 8, BB), blk, 0, stream>>>(xn, yn, out);
}

// Round 23
// 487.726 us; speedup vs baseline: 2.4273x; 1.0257x over previous
//
#include <hip/hip_runtime.h>
#include <cstdint>
#include <cstddef>

#define SS 512
#define BB 64
#define DD 128
#define HH 8
#define HDIM 16
#define FFD 1024
#define NL 6

typedef short bf16x8 __attribute__((ext_vector_type(8)));
typedef float f32x4 __attribute__((ext_vector_type(4)));

// hardware packed f32->bf16 (RNE), low16 = a, high16 = b
__device__ inline uint32_t pack2(float a, float b) {
  uint32_t r;
  asm("v_cvt_pk_bf16_f32 %0, %1, %2" : "=v"(r) : "v"(a), "v"(b));
  return r;
}

#define QSCALE 0.36067376022224085f  /* 0.25 * log2(e) */

// ---------------- merged weight-conversion prologue (1 launch, 5 sections) ----------------
// A: Wqkv (Q rows scaled by QSCALE)  B: Wo  C: W1  D: W2  (float2->bf16x2 units)
// E: bqkv scale (scalars). Section sizes are exact multiples of 256.
#define SECA (NL * 384 * 64)
#define SECB (NL * DD * 64)
#define SECC (NL * FFD * 64)
#define SECD (NL * DD * 64 * 8)
#define SECE (NL * 384)
__global__ __launch_bounds__(256) void cvt_all_kernel(const float* __restrict__ Wqkv,
                                                      const float* __restrict__ Wo,
                                                      const float* __restrict__ W1,
                                                      const float* __restrict__ W2,
                                                      const float* __restrict__ bqkv,
                                                      short* __restrict__ wqB,
                                                      short* __restrict__ woB,
                                                      short* __restrict__ w1B,
                                                      short* __restrict__ w2B,
                                                      float* __restrict__ bq2) {
  int i = blockIdx.x * 256 + threadIdx.x;
  if (i < SECA) {
    const int within = i % (384 * 64);
    const float sc = (within < 128 * 64) ? QSCALE : 1.0f;
    float2 v = ((const float2*)Wqkv)[i];
    ((uint32_t*)wqB)[i] = pack2(v.x * sc, v.y * sc);
    return;
  }
  i -= SECA;
  if (i < SECB) {
    float2 v = ((const float2*)Wo)[i];
    ((uint32_t*)woB)[i] = pack2(v.x, v.y);
    return;
  }
  i -= SECB;
  if (i < SECC) {
    float2 v = ((const float2*)W1)[i];
    ((uint32_t*)w1B)[i] = pack2(v.x, v.y);
    return;
  }
  i -= SECC;
  if (i < SECD) {
    float2 v = ((const float2*)W2)[i];
    ((uint32_t*)w2B)[i] = pack2(v.x, v.y);
    return;
  }
  i -= SECD;
  if (i < SECE) {
    const float sc = ((i % 384) < 128) ? QSCALE : 1.0f;
    bq2[i] = bqkv[i] * sc;
  }
}

// ---------------- transpose+rownorm: (S,B,D)->(B,S,D) x0/h fp32, hb bf16, xn bf16 ----------------
__global__ __launch_bounds__(256) void transpose_rn_kernel(const float* __restrict__ src,
                                                           float* __restrict__ x0,
                                                           float* __restrict__ h,
                                                           short* __restrict__ hb,
                                                           short* __restrict__ xn) {
  const int wave = threadIdx.x >> 6;
  const int lane = threadIdx.x & 63;
  const int row = blockIdx.x * 4 + wave;   // row = b*512 + s
  const int b = row >> 9;
  const int s = row & 511;
  const float2 v = ((const float2*)(src + ((size_t)s * BB + b) * DD))[lane];
  ((float2*)(x0 + (size_t)row * DD))[lane] = v;
  ((float2*)(h + (size_t)row * DD))[lane] = v;
  ((uint32_t*)hb)[(size_t)row * 64 + lane] = pack2(v.x, v.y);
  float ss = v.x * v.x + v.y * v.y;
  #pragma unroll
  for (int off = 1; off < 64; off <<= 1) ss += __shfl_xor(ss, off);
  const float r = rsqrtf(ss);
  ((uint32_t*)xn)[(size_t)row * 64 + lane] = pack2(v.x * r, v.y * r);
}

// ---------------- MFMA GEMM (QKV layer 0 only): C = A@B^T + bias, head-major out ----------------
__global__ __launch_bounds__(256) void mgemm_qkv(const short* __restrict__ Ab,
                                                 const short* __restrict__ Bw,
                                                 const float* __restrict__ bias,
                                                 short* __restrict__ Cb) {
  __shared__ uint32_t Xs[128 * 32];
  __shared__ uint32_t Wls[128 * 32];
  const int t = threadIdx.x;
  const int wave = t >> 6, lane = t & 63;
  const int g = lane >> 4, p = lane & 15;
  const int wr = wave >> 1, wc = wave & 1;
  const int m0 = blockIdx.y * 128, n0 = blockIdx.x * 128;
  const int K = DD;

  f32x4 acc[4][4];
  #pragma unroll
  for (int i = 0; i < 4; ++i)
    #pragma unroll
    for (int j = 0; j < 4; ++j) acc[i][j] = (f32x4){0.f, 0.f, 0.f, 0.f};

  for (int kt = 0; kt < K; kt += 64) {
    __syncthreads();
    #pragma unroll
    for (int i = 0; i < 4; ++i) {
      const int idx = t + i * 256;
      const int row = idx >> 3, kc = idx & 7;
      const uint4 w = *(const uint4*)(Ab + (size_t)(m0 + row) * K + kt + kc * 8);
      *(uint4*)(Xs + row * 32 + ((kc ^ (row & 7)) << 2)) = w;
      const uint4 u = *(const uint4*)(Bw + (size_t)(n0 + row) * K + kt + kc * 8);
      *(uint4*)(Wls + row * 32 + ((kc ^ (row & 7)) << 2)) = u;
    }
    __syncthreads();
    #pragma unroll
    for (int kc32 = 0; kc32 < 2; ++kc32) {
      bf16x8 xf[4], wf[4];
      #pragma unroll
      for (int mi = 0; mi < 4; ++mi) {
        const int row = wr * 64 + mi * 16 + p;
        union { bf16x8 v; uint4 w; } u;
        u.w = *(const uint4*)(Xs + row * 32 + (((kc32 * 4 + g) ^ (row & 7)) << 2));
        xf[mi] = u.v;
      }
      #pragma unroll
      for (int ni = 0; ni < 4; ++ni) {
        const int row = wc * 64 + ni * 16 + p;
        union { bf16x8 v; uint4 w; } u;
        u.w = *(const uint4*)(Wls + row * 32 + (((kc32 * 4 + g) ^ (row & 7)) << 2));
        wf[ni] = u.v;
      }
      #pragma unroll
      for (int mi = 0; mi < 4; ++mi)
        #pragma unroll
        for (int ni = 0; ni < 4; ++ni)
          acc[mi][ni] = __builtin_amdgcn_mfma_f32_16x16x32_bf16(wf[ni], xf[mi], acc[mi][ni], 0, 0, 0);
    }
  }

  #pragma unroll
  for (int mi = 0; mi < 4; ++mi) {
    const int m = m0 + wr * 64 + mi * 16 + p;
    #pragma unroll
    for (int ni = 0; ni < 4; ++ni) {
      const int nb = n0 + wc * 64 + ni * 16 + g * 4;
      const float4 bv = *(const float4*)(bias + nb);
      float c[4];
      c[0] = acc[mi][ni][0] + bv.x;
      c[1] = acc[mi][ni][1] + bv.y;
      c[2] = acc[mi][ni][2] + bv.z;
      c[3] = acc[mi][ni][3] + bv.w;
      const int bb2 = m >> 9, s = m & 511;
      const int which = nb >> 7, hh = (nb >> 4) & 7, d = nb & 15;
      uint2 w;
      w.x = pack2(c[0], c[1]);
      w.y = pack2(c[2], c[3]);
      *(uint2*)(Cb + ((((size_t)(bb2 * 3 + which) * 8 + hh) * 512 + s) * 16 + d)) = w;
    }
  }
}

// ---------------- Fused cosine-sim pair ----------------
__global__ __launch_bounds__(256) void cos2_kernel(const short* __restrict__ xn,
                                                   const short* __restrict__ yn,
                                                   float* __restrict__ out) {
  __shared__ uint32_t Js[128 * 64];  // 32 KB
  const int t = threadIdx.x;
  const int w = t >> 6, lane = t & 63;
  const int g = lane >> 4, p = lane & 15;
  const int j0 = blockIdx.x * 128;
  const int i0 = blockIdx.y * 64;
  const int b = blockIdx.z;
  const short* xb = xn + (size_t)b * SS * DD;
  const short* yb = yn + (size_t)b * SS * DD;
  const int i = i0 + w * 16 + p;

  // ---- pass 1: xn ----
  bf16x8 af[4];
  #pragma unroll
  for (int kc = 0; kc < 4; ++kc) {
    union { bf16x8 v; uint4 u; } uu;
    uu.u = *(const uint4*)(xb + (size_t)i * DD + kc * 32 + g * 8);
    af[kc] = uu.v;
  }
  #pragma unroll
  for (int q = 0; q < 8; ++q) {
    const int idx = q * 256 + t;
    const int row = idx >> 4, slot = idx & 15;
    const int key = (row & 3) | ((row >> 1) & 12);
    const uint4 u = *(const uint4*)(xb + (size_t)(j0 + row) * DD + slot * 8);
    *(uint4*)(&Js[row * 64 + ((slot ^ key) << 2)]) = u;
  }
  __syncthreads();

  f32x4 acc[8];
  #pragma unroll
  for (int q = 0; q < 8; ++q) acc[q] = (f32x4){0.f, 0.f, 0.f, 0.f};
  #pragma unroll
  for (int kc = 0; kc < 4; ++kc) {
    #pragma unroll
    for (int ni = 0; ni < 8; ++ni) {
      const int row = ni * 16 + p;
      const int key = (row & 3) | ((row >> 1) & 12);
      union { bf16x8 v; uint4 u; } jf;
      jf.u = *(const uint4*)(&Js[row * 64 + (((kc * 4 + g) ^ key) << 2)]);
      acc[ni] = __builtin_amdgcn_mfma_f32_16x16x32_bf16(jf.v, af[kc], acc[ni], 0, 0, 0);
    }
  }
  float prev[8][4];
  #pragma unroll
  for (int ni = 0; ni < 8; ++ni)
    #pragma unroll
    for (int r = 0; r < 4; ++r) prev[ni][r] = fmaxf(acc[ni][r], 1e-6f);
  __syncthreads();

  // ---- pass 2: yn ----
  #pragma unroll
  for (int kc = 0; kc < 4; ++kc) {
    union { bf16x8 v; uint4 u; } uu;
    uu.u = *(const uint4*)(yb + (size_t)i * DD + kc * 32 + g * 8);
    af[kc] = uu.v;
  }
  #pragma unroll
  for (int q = 0; q < 8; ++q) {
    const int idx = q * 256 + t;
    const int row = idx >> 4, slot = idx & 15;
    const int key = (row & 3) | ((row >> 1) & 12);
    const uint4 u = *(const uint4*)(yb + (size_t)(j0 + row) * DD + slot * 8);
    *(uint4*)(&Js[row * 64 + ((slot ^ key) << 2)]) = u;
  }
  __syncthreads();

  #pragma unroll
  for (int q = 0; q < 8; ++q) acc[q] = (f32x4){0.f, 0.f, 0.f, 0.f};
  #pragma unroll
  for (int kc = 0; kc < 4; ++kc) {
    #pragma unroll
    for (int ni = 0; ni < 8; ++ni) {
      const int row = ni * 16 + p;
      const int key = (row & 3) | ((row >> 1) & 12);
      union { bf16x8 v; uint4 u; } jf;
      jf.u = *(const uint4*)(&Js[row * 64 + (((kc * 4 + g) ^ key) << 2)]);
      acc[ni] = __builtin_amdgcn_mfma_f32_16x16x32_bf16(jf.v, af[kc], acc[ni], 0, 0, 0);
    }
  }

  float* ob = out + (size_t)b * SS * SS;
  #pragma unroll
  for (int ni = 0; ni < 8; ++ni) {
    const int j = j0 + ni * 16 + g * 4;
    float4 wv;
    float* pw = &wv.x;
    #pragma unroll
    for (int r = 0; r < 4; ++r) {
      const float v = fmaxf(acc[ni][r], 1e-6f);
      pw[r] = fminf(fmaxf(0.5f * (v + prev[ni][r]), 0.1f), 0.9f);
    }
    *(float4*)(ob + (size_t)i * SS + j) = wv;
  }
}

// ---------------- Fused Wo+LN1+FFN+LN2 + {phase C: next-layer QKV | mask_norm} ----------------
__global__ __launch_bounds__(256) void wo_ffn_ln_kernel(const short* __restrict__ att,
                                                        const short* __restrict__ Wob,
                                                        const float* __restrict__ bov,
                                                        const float* __restrict__ lng1,
                                                        const float* __restrict__ lnb1,
                                                        const short* __restrict__ W1b,
                                                        const float* __restrict__ b1v,
                                                        const short* __restrict__ W2b,
                                                        const float* __restrict__ b2v,
                                                        const float* __restrict__ lng2,
                                                        const float* __restrict__ lnb2,
                                                        float* __restrict__ hx,
                                                        const short* __restrict__ Wqn,
                                                        const float* __restrict__ bqn,
                                                        short* __restrict__ qkvo,
                                                        const float* __restrict__ x0p,
                                                        short* __restrict__ ynp) {
  __shared__ uint32_t S[10240];      // 40 KB union
  uint32_t* WoLS = S;                // phase A: 8192 words (32 KB)
  uint32_t* Tb   = S;                // transient: 4096 words (16 KB)
  uint32_t* W1base = S;              // 2 bufs x 2048 words
  uint32_t* W2base = S + 4096;       // 3 bufs x 2048 words
  const int t = threadIdx.x;
  const int w = t >> 6, lane = t & 63;
  const int g = lane >> 4, p = lane & 15;
  const int m0 = blockIdx.x * 64;
  const int m = m0 + w * 16 + p;
  const int lr = w * 16 + p;
  const int lkey = (lr & 3) | ((lr >> 1) & 12);

  // ---- Phase A: att rows in regs, Wo in LDS ----
  bf16x8 af[4];
  #pragma unroll
  for (int kc = 0; kc < 4; ++kc) {
    union { bf16x8 v; uint4 u; } uu;
    uu.u = *(const uint4*)(att + (size_t)m * DD + kc * 32 + g * 8);
    af[kc] = uu.v;
  }
  #pragma unroll
  for (int i = 0; i < 8; ++i) {
    const int idx = i * 256 + t;
    const int row = idx >> 4, slot = idx & 15;
    const int key = (row & 3) | ((row >> 1) & 12);
    const uint4 u = *(const uint4*)(Wob + (size_t)row * DD + slot * 8);
    *(uint4*)(&WoLS[row * 64 + ((slot ^ key) << 2)]) = u;
  }
  __syncthreads();

  f32x4 acc[8];
  #pragma unroll
  for (int i = 0; i < 8; ++i) acc[i] = (f32x4){0.f, 0.f, 0.f, 0.f};
  #pragma unroll
  for (int kc = 0; kc < 4; ++kc) {
    #pragma unroll
    for (int ni = 0; ni < 8; ++ni) {
      const int row = ni * 16 + p;
      const int key = (row & 3) | ((row >> 1) & 12);
      union { bf16x8 v; uint4 u; } wf;
      wf.u = *(const uint4*)(&WoLS[row * 64 + (((kc * 4 + g) ^ key) << 2)]);
      acc[ni] = __builtin_amdgcn_mfma_f32_16x16x32_bf16(wf.v, af[kc], acc[ni], 0, 0, 0);
    }
  }

  // LN1 (lane-local rows)
  float h1r[8][4];
  float s1r = 0.0f, s2r = 0.0f;
  #pragma unroll
  for (int ni = 0; ni < 8; ++ni) {
    const int nb = ni * 16 + g * 4;
    const float4 rv = *(const float4*)(hx + (size_t)m * DD + nb);
    const float4 bv = *(const float4*)(bov + nb);
    h1r[ni][0] = acc[ni][0] + bv.x + rv.x;
    h1r[ni][1] = acc[ni][1] + bv.y + rv.y;
    h1r[ni][2] = acc[ni][2] + bv.z + rv.z;
    h1r[ni][3] = acc[ni][3] + bv.w + rv.w;
    #pragma unroll
    for (int r = 0; r < 4; ++r) {
      s1r += h1r[ni][r];
      s2r += h1r[ni][r] * h1r[ni][r];
    }
  }
  s1r += __shfl_xor(s1r, 16); s1r += __shfl_xor(s1r, 32);
  s2r += __shfl_xor(s2r, 16); s2r += __shfl_xor(s2r, 32);
  {
    const float mu = s1r * (1.0f / 128.0f);
    const float rs = rsqrtf(fmaxf(s2r * (1.0f / 128.0f) - mu * mu, 0.0f) + 1e-5f);
    #pragma unroll
    for (int ni = 0; ni < 8; ++ni) {
      const int nb = ni * 16 + g * 4;
      const float4 gv = *(const float4*)(lng1 + nb);
      const float4 bv = *(const float4*)(lnb1 + nb);
      h1r[ni][0] = (h1r[ni][0] - mu) * rs * gv.x + bv.x;
      h1r[ni][1] = (h1r[ni][1] - mu) * rs * gv.y + bv.y;
      h1r[ni][2] = (h1r[ni][2] - mu) * rs * gv.z + bv.z;
      h1r[ni][3] = (h1r[ni][3] - mu) * rs * gv.w + bv.w;
    }
  }
  __syncthreads();  // all Wo reads done before Tb overwrites WoLS

  // write h1 (bf16) into Tb
  #pragma unroll
  for (int ni = 0; ni < 8; ++ni) {
    const int w16 = ni * 8 + 2 * g;
    const int slot = w16 >> 2, offs = w16 & 3;
    uint2 pk;
    pk.x = pack2(h1r[ni][0], h1r[ni][1]);
    pk.y = pack2(h1r[ni][2], h1r[ni][3]);
    *(uint2*)(&Tb[lr * 64 + ((slot ^ lkey) << 2) + offs]) = pk;
  }
  __syncthreads();

  // h1 B-frags from Tb (read ONCE; Tb dead after this barrier)
  bf16x8 hsf[4];
  #pragma unroll
  for (int kc = 0; kc < 4; ++kc) {
    union { bf16x8 v; uint4 u; } uu;
    uu.u = *(const uint4*)(&Tb[lr * 64 + (((kc * 4 + g) ^ lkey) << 2)]);
    hsf[kc] = uu.v;
  }
  __syncthreads();

  // ---- Phase B: ffn v3 ----
  uint4 rA0, rA1, rB0, rB1;

#define FFN_LOAD(c)                                                               \
  {                                                                               \
    const int nf0_ = (c) * 32;                                                    \
    rA0 = *(const uint4*)(W1b + (size_t)(nf0_ + (t >> 4)) * DD + (t & 15) * 8);   \
    rA1 = *(const uint4*)(W1b + (size_t)(nf0_ + 16 + (t >> 4)) * DD + (t & 15) * 8); \
    rB0 = *(const uint4*)(W2b + (size_t)(t >> 2) * FFD + nf0_ + (t & 3) * 8);     \
    rB1 = *(const uint4*)(W2b + (size_t)(64 + (t >> 2)) * FFD + nf0_ + (t & 3) * 8); \
  }

#define FFN_WRITE(bufA, bufB)                                                     \
  {                                                                               \
    uint32_t* W1p = W1base + (bufA) * 2048;                                       \
    uint32_t* W2p = W2base + (bufB) * 2048;                                       \
    const int rw0 = t >> 4, sl0 = t & 15;                                         \
    const int k0 = (rw0 & 3) | ((rw0 >> 1) & 12);                                 \
    *(uint4*)(&W1p[rw0 * 64 + ((sl0 ^ k0) << 2)]) = rA0;                          \
    const int rw1 = 16 + rw0;                                                     \
    const int k1 = (rw1 & 3) | ((rw1 >> 1) & 12);                                 \
    *(uint4*)(&W1p[rw1 * 64 + ((sl0 ^ k1) << 2)]) = rA1;                          \
    const int rw2 = t >> 2, sl2 = t & 3;                                          \
    *(uint4*)(&W2p[rw2 * 16 + ((sl2 ^ ((rw2 >> 1) & 3)) << 2)]) = rB0;            \
    const int rw3 = 64 + rw2;                                                     \
    *(uint4*)(&W2p[rw3 * 16 + ((sl2 ^ ((rw3 >> 1) & 3)) << 2)]) = rB1;            \
  }

  FFN_LOAD(0);
  FFN_WRITE(0, 0);
  __syncthreads();

  const int pr0 = 8 * (p >> 2) + (p & 3);
  const int pr1 = pr0 + 4;
  const int key0 = (pr0 & 3) | ((pr0 >> 1) & 12);
  const int key1 = (pr1 & 3) | ((pr1 >> 1) & 12);

  f32x4 acc2[8];
  #pragma unroll
  for (int i = 0; i < 8; ++i) acc2[i] = (f32x4){0.f, 0.f, 0.f, 0.f};
  const f32x4 zacc = {0.f, 0.f, 0.f, 0.f};

  bf16x8 pbv;
  int bPrev = 2, bCur = 0, bNext = 1;

  for (int c = 0; c < 32; ++c) {
    const int bA = c & 1;
    if (c + 1 < 32) FFN_LOAD(c + 1);

    const uint32_t* W1p = W1base + bA * 2048;
    f32x4 s0 = zacc, s1 = zacc;
    #pragma unroll
    for (int kc = 0; kc < 4; ++kc) {
      union { bf16x8 v; uint4 u; } a0, a1;
      a0.u = *(const uint4*)(&W1p[pr0 * 64 + (((kc * 4 + g) ^ key0) << 2)]);
      a1.u = *(const uint4*)(&W1p[pr1 * 64 + (((kc * 4 + g) ^ key1) << 2)]);
      s0 = __builtin_amdgcn_mfma_f32_16x16x32_bf16(a0.v, hsf[kc], s0, 0, 0, 0);
      s1 = __builtin_amdgcn_mfma_f32_16x16x32_bf16(a1.v, hsf[kc], s1, 0, 0, 0);
    }

    if (c > 0) {
      const uint32_t* W2p = W2base + bPrev * 2048;
      #pragma unroll
      for (int ni = 0; ni < 8; ++ni) {
        const int row = ni * 16 + p;
        union { bf16x8 v; uint4 u; } wf;
        wf.u = *(const uint4*)(&W2p[row * 16 + ((g ^ ((row >> 1) & 3)) << 2)]);
        acc2[ni] = __builtin_amdgcn_mfma_f32_16x16x32_bf16(wf.v, pbv, acc2[ni], 0, 0, 0);
      }
    }

    const int nf0 = c * 32;
    const float4 bb0 = *(const float4*)(b1v + nf0 + 8 * g);
    const float4 bb1 = *(const float4*)(b1v + nf0 + 8 * g + 4);
    union { bf16x8 v; uint4 u; } pb;
    pb.u.x = pack2(fmaxf(s0[0] + bb0.x, 0.0f), fmaxf(s0[1] + bb0.y, 0.0f));
    pb.u.y = pack2(fmaxf(s0[2] + bb0.z, 0.0f), fmaxf(s0[3] + bb0.w, 0.0f));
    pb.u.z = pack2(fmaxf(s1[0] + bb1.x, 0.0f), fmaxf(s1[1] + bb1.y, 0.0f));
    pb.u.w = pack2(fmaxf(s1[2] + bb1.z, 0.0f), fmaxf(s1[3] + bb1.w, 0.0f));
    pbv = pb.v;

    if (c + 1 < 32) FFN_WRITE(bA ^ 1, bNext);
    __syncthreads();

    bPrev = bCur; bCur = bNext; bNext = (bNext == 2) ? 0 : bNext + 1;
  }

  { // final GEMM2(31): chunk 31 staged into buf (1+30)%3 = 1
    const uint32_t* W2p = W2base + 1 * 2048;
    #pragma unroll
    for (int ni = 0; ni < 8; ++ni) {
      const int row = ni * 16 + p;
      union { bf16x8 v; uint4 u; } wf;
      wf.u = *(const uint4*)(&W2p[row * 16 + ((g ^ ((row >> 1) & 3)) << 2)]);
      acc2[ni] = __builtin_amdgcn_mfma_f32_16x16x32_bf16(wf.v, pbv, acc2[ni], 0, 0, 0);
    }
  }

  // LN2: residual = h1r (regs)
  float t1 = 0.0f, t2 = 0.0f;
  #pragma unroll
  for (int ni = 0; ni < 8; ++ni) {
    const int nb = ni * 16 + g * 4;
    const float4 bv = *(const float4*)(b2v + nb);
    acc2[ni][0] += bv.x + h1r[ni][0];
    acc2[ni][1] += bv.y + h1r[ni][1];
    acc2[ni][2] += bv.z + h1r[ni][2];
    acc2[ni][3] += bv.w + h1r[ni][3];
    #pragma unroll
    for (int r = 0; r < 4; ++r) {
      t1 += acc2[ni][r];
      t2 += acc2[ni][r] * acc2[ni][r];
    }
  }
  t1 += __shfl_xor(t1, 16); t1 += __shfl_xor(t1, 32);
  t2 += __shfl_xor(t2, 16); t2 += __shfl_xor(t2, 32);
  const float mu2 = t1 * (1.0f / 128.0f);
  const float rs2 = rsqrtf(fmaxf(t2 * (1.0f / 128.0f) - mu2 * mu2, 0.0f) + 1e-5f);

  if (ynp != nullptr) {
    // last layer: fused mask_norm — yn = normalize(x0 * sigmoid(h_final))
    float av[8][4];
    float ssum = 0.0f;
    #pragma unroll
    for (int ni = 0; ni < 8; ++ni) {
      const int nb = ni * 16 + g * 4;
      const float4 gv = *(const float4*)(lng2 + nb);
      const float4 bv = *(const float4*)(lnb2 + nb);
      const float4 xv = *(const float4*)(x0p + (size_t)m * DD + nb);
      const float hc0 = (acc2[ni][0] - mu2) * rs2 * gv.x + bv.x;
      const float hc1 = (acc2[ni][1] - mu2) * rs2 * gv.y + bv.y;
      const float hc2 = (acc2[ni][2] - mu2) * rs2 * gv.z + bv.z;
      const float hc3 = (acc2[ni][3] - mu2) * rs2 * gv.w + bv.w;
      av[ni][0] = xv.x / (1.0f + __expf(-hc0));
      av[ni][1] = xv.y / (1.0f + __expf(-hc1));
      av[ni][2] = xv.z / (1.0f + __expf(-hc2));
      av[ni][3] = xv.w / (1.0f + __expf(-hc3));
      #pragma unroll
      for (int r = 0; r < 4; ++r) ssum += av[ni][r] * av[ni][r];
    }
    ssum += __shfl_xor(ssum, 16);
    ssum += __shfl_xor(ssum, 32);
    const float inv = 1.0f / fmaxf(sqrtf(ssum), 1e-12f);
    #pragma unroll
    for (int ni = 0; ni < 8; ++ni) {
      const int nb = ni * 16 + g * 4;
      uint2 wb;
      wb.x = pack2(av[ni][0] * inv, av[ni][1] * inv);
      wb.y = pack2(av[ni][2] * inv, av[ni][3] * inv);
      *(uint2*)(ynp + (size_t)m * DD + nb) = wb;
    }
    return;
  }

  // layers 0..4: write hx fp32 + pack new-h bf16 into h1r, write Tb, phase C
  #pragma unroll
  for (int ni = 0; ni < 8; ++ni) {
    const int nb = ni * 16 + g * 4;
    const float4 gv = *(const float4*)(lng2 + nb);
    const float4 bv = *(const float4*)(lnb2 + nb);
    h1r[ni][0] = (acc2[ni][0] - mu2) * rs2 * gv.x + bv.x;
    h1r[ni][1] = (acc2[ni][1] - mu2) * rs2 * gv.y + bv.y;
    h1r[ni][2] = (acc2[ni][2] - mu2) * rs2 * gv.z + bv.z;
    h1r[ni][3] = (acc2[ni][3] - mu2) * rs2 * gv.w + bv.w;
    float4 wv;
    wv.x = h1r[ni][0]; wv.y = h1r[ni][1]; wv.z = h1r[ni][2]; wv.w = h1r[ni][3];
    *(float4*)(hx + (size_t)m * DD + nb) = wv;
  }

  // Tb (= W1base region): W1 buf1 reads finished at c=31 in-loop barrier; final
  // GEMM2 reads only W2base. Per-lane rows disjoint -> safe to write, then barrier.
  #pragma unroll
  for (int ni = 0; ni < 8; ++ni) {
    const int w16 = ni * 8 + 2 * g;
    const int slot = w16 >> 2, offs = w16 & 3;
    uint2 pk;
    pk.x = pack2(h1r[ni][0], h1r[ni][1]);
    pk.y = pack2(h1r[ni][2], h1r[ni][3]);
    *(uint2*)(&Tb[lr * 64 + ((slot ^ lkey) << 2) + offs]) = pk;
  }
  __syncthreads();

  #pragma unroll
  for (int kc = 0; kc < 4; ++kc) {
    union { bf16x8 v; uint4 u; } uu;
    uu.u = *(const uint4*)(&Tb[lr * 64 + (((kc * 4 + g) ^ lkey) << 2)]);
    hsf[kc] = uu.v;
  }
  __syncthreads();

  // ---- Phase C: next-layer QKV, 12 chunks of 32 n-rows (FFN GEMM1 machinery) ----
#define QKV_LOAD(c)                                                               \
  {                                                                               \
    const int nf0_ = (c) * 32;                                                    \
    rA0 = *(const uint4*)(Wqn + (size_t)(nf0_ + (t >> 4)) * DD + (t & 15) * 8);   \
    rA1 = *(const uint4*)(Wqn + (size_t)(nf0_ + 16 + (t >> 4)) * DD + (t & 15) * 8); \
  }

#define QKV_WRITE(bufA)                                                           \
  {                                                                               \
    uint32_t* W1p = W1base + (bufA) * 2048;                                       \
    const int rw0 = t >> 4, sl0 = t & 15;                                         \
    const int k0 = (rw0 & 3) | ((rw0 >> 1) & 12);                                 \
    *(uint4*)(&W1p[rw0 * 64 + ((sl0 ^ k0) << 2)]) = rA0;                          \
    const int rw1 = 16 + rw0;                                                     \
    const int k1 = (rw1 & 3) | ((rw1 >> 1) & 12);                                 \
    *(uint4*)(&W1p[rw1 * 64 + ((sl0 ^ k1) << 2)]) = rA1;                          \
  }

  QKV_LOAD(0);
  QKV_WRITE(0);
  __syncthreads();

  const int bb2 = m >> 9, sm = m & 511;
  for (int c = 0; c < 12; ++c) {
    const int bA = c & 1;
    if (c + 1 < 12) QKV_LOAD(c + 1);

    const uint32_t* W1p = W1base + bA * 2048;
    f32x4 s0 = zacc, s1 = zacc;
    #pragma unroll
    for (int kc = 0; kc < 4; ++kc) {
      union { bf16x8 v; uint4 u; } a0, a1;
      a0.u = *(const uint4*)(&W1p[pr0 * 64 + (((kc * 4 + g) ^ key0) << 2)]);
      a1.u = *(const uint4*)(&W1p[pr1 * 64 + (((kc * 4 + g) ^ key1) << 2)]);
      s0 = __builtin_amdgcn_mfma_f32_16x16x32_bf16(a0.v, hsf[kc], s0, 0, 0, 0);
      s1 = __builtin_amdgcn_mfma_f32_16x16x32_bf16(a1.v, hsf[kc], s1, 0, 0, 0);
    }

    // lane (g,p): s0[r] = qkv[m][n0q+r], s1[r] = qkv[m][n0q+4+r], n0q = c*32+8g
    const int n0q = c * 32 + 8 * g;
    const float4 b0 = *(const float4*)(bqn + n0q);
    const float4 b4 = *(const float4*)(bqn + n0q + 4);
    const int which = n0q >> 7, hh = (n0q >> 4) & 7, d0 = n0q & 15;
    short* base = qkvo + ((((size_t)(bb2 * 3 + which) * 8 + hh) * 512 + sm) * 16 + d0);
    uint2 w0, w1;
    w0.x = pack2(s0[0] + b0.x, s0[1] + b0.y);
    w0.y = pack2(s0[2] + b0.z, s0[3] + b0.w);
    w1.x = pack2(s1[0] + b4.x, s1[1] + b4.y);
    w1.y = pack2(s1[2] + b4.z, s1[3] + b4.w);
    *(uint2*)(base) = w0;
    *(uint2*)(base + 4) = w1;

    if (c + 1 < 12) QKV_WRITE(bA ^ 1);
    __syncthreads();
  }
}

// ---------------- MFMA flash attention v6 (z=2) ----------------
__global__ __launch_bounds__(512) void attn_mfma_kernel(const short* __restrict__ qkvp,
                                                        short* __restrict__ o_out) {
  const int h = blockIdx.x;
  const int b = blockIdx.y;
  const int z = blockIdx.z;
  const int t = threadIdx.x;
  const int wave = t >> 6;
  const int lane = t & 63;
  const int g = lane >> 4;
  const int p = lane & 15;

  __shared__ uint32_t Ks[512 * 8];
  __shared__ uint32_t Vs[16 * 256];

  const short* baseQ = qkvp + ((size_t)(b * 3 + 0) * 8 + h) * 8192;
  const short* baseK = qkvp + ((size_t)(b * 3 + 1) * 8 + h) * 8192;
  const short* baseV = qkvp + ((size_t)(b * 3 + 2) * 8 + h) * 8192;

  { // stage K
    const int row = t;
    const uint4 lo = *(const uint4*)(baseK + row * 16);
    const uint4 hi = *(const uint4*)(baseK + row * 16 + 8);
    const int f = ((row >> 3) & 1) << 2;
    *(uint4*)(Ks + row * 8 + f) = lo;
    *(uint4*)(Ks + row * 8 + (f ^ 4)) = hi;
  }
  { // stage V^T (swizzled scatter)
    const int k = t;
    union { uint4 u[2]; short s[16]; } vv;
    vv.u[0] = *(const uint4*)(baseV + k * 16);
    vv.u[1] = *(const uint4*)(baseV + k * 16 + 8);
    const int wk = k >> 1;
    #pragma unroll
    for (int d = 0; d < 16; ++d) {
      const int word = d * 256 + (wk ^ ((d & 7) << 2));
      ((short*)(Vs + word))[k & 1] = vv.s[d];
    }
  }
  __syncthreads();

  const bf16x8 zfrag = {0, 0, 0, 0, 0, 0, 0, 0};
  const f32x4 zacc = {0.f, 0.f, 0.f, 0.f};

  #pragma unroll
  for (int qi = 0; qi < 2; ++qi) {
    const int qt = z * 16 + wave + qi * 8;
    bf16x8 qf = zfrag;
    if (g < 2) {
      union { bf16x8 v; uint4 w; } qu;
      qu.w = *(const uint4*)(baseQ + (qt * 16 + p) * 16 + g * 8);
      qf = qu.v;
    }

    f32x4 o = zacc;
    float lsum = 0.0f;

    for (int kv = 0; kv < 16; ++kv) {
      bf16x8 ka = zfrag, kb = zfrag;
      if (g < 2) {
        const int r0 = kv * 32 + 8 * (p >> 2) + (p & 3);
        const int r1 = r0 + 4;
        union { bf16x8 v; uint4 w; } u;
        u.w = *(const uint4*)(Ks + r0 * 8 + ((4 * g) ^ (((r0 >> 3) & 1) << 2)));
        ka = u.v;
        u.w = *(const uint4*)(Ks + r1 * 8 + ((4 * g) ^ (((r1 >> 3) & 1) << 2)));
        kb = u.v;
      }
      union { bf16x8 v; uint4 w; } vu;
      vu.w = *(const uint4*)(Vs + p * 256 + ((kv * 16 + g * 4) ^ ((p & 7) << 2)));

      const f32x4 s0 = __builtin_amdgcn_mfma_f32_16x16x32_bf16(ka, qf, zacc, 0, 0, 0);
      const f32x4 s1 = __builtin_amdgcn_mfma_f32_16x16x32_bf16(kb, qf, zacc, 0, 0, 0);

      float sv0[4], sv1[4];
      #pragma unroll
      for (int r = 0; r < 4; ++r) {
        sv0[r] = __builtin_amdgcn_exp2f(s0[r]);
        sv1[r] = __builtin_amdgcn_exp2f(s1[r]);
      }
      #pragma unroll
      for (int r = 0; r < 4; ++r) lsum += sv0[r] + sv1[r];

      union { bf16x8 v; uint4 w; } pu;
      pu.w.x = pack2(sv0[0], sv0[1]);
      pu.w.y = pack2(sv0[2], sv0[3]);
      pu.w.z = pack2(sv1[0], sv1[1]);
      pu.w.w = pack2(sv1[2], sv1[3]);

      o = __builtin_amdgcn_mfma_f32_16x16x32_bf16(pu.v, vu.v, o, 0, 0, 0);
    }

    lsum += __shfl_xor(lsum, 16);
    lsum += __shfl_xor(lsum, 32);
    const float li = 1.0f / lsum;
    #pragma unroll
    for (int r = 0; r < 4; ++r) {
      const float inv = __shfl(li, 4 * g + r);
      o_out[((size_t)(b * SS + qt * 16 + 4 * g + r)) * DD + h * HDIM + p] =
          (short)(pack2(o[r] * inv, 0.0f) & 0xffff);
    }
  }
}

extern "C" void kernel_launch(void* const* d_in, const int* in_sizes, int n_in,
                              void* d_out, int out_size, void* d_ws, size_t ws_size,
                              hipStream_t stream) {
  const float* src  = (const float*)d_in[0];
  const float* Wqkv = (const float*)d_in[1];
  const float* bqkv = (const float*)d_in[2];
  const float* Wo   = (const float*)d_in[3];
  const float* bo   = (const float*)d_in[4];
  const float* ln1g = (const float*)d_in[5];
  const float* ln1b = (const float*)d_in[6];
  const float* W1   = (const float*)d_in[7];
  const float* b1   = (const float*)d_in[8];
  const float* W2   = (const float*)d_in[9];
  const float* b2   = (const float*)d_in[10];
  const float* ln2g = (const float*)d_in[11];
  const float* ln2b = (const float*)d_in[12];
  float* out = (float*)d_out;

  char* W = (char*)d_ws;
  const size_t MB = 1048576;
  float* x0  = (float*)(W);
  float* h   = (float*)(W + 16 * MB);
  short* hb  = (short*)(W + 32 * MB);
  short* qkvp = (short*)(W + 40 * MB);   // 24 MB head-major [b][3][h][s][16]
  short* att = (short*)(W + 128 * MB);
  short* xn  = (short*)(W + 136 * MB);
  short* yn  = (short*)(W + 144 * MB);
  short* wqB = (short*)(W + 152 * MB);
  short* woB = wqB + (size_t)NL * 384 * DD;
  short* w1B = woB + (size_t)NL * DD * DD;
  short* w2B = w1B + (size_t)NL * FFD * DD;
  float* bq2 = (float*)(w2B + (size_t)NL * DD * FFD);

  const dim3 blk(256);
  const int ROWS = BB * SS;

  // merged prologue: all weight converts + bias scale in one launch
  const int CVT_TOTAL = SECA + SECB + SECC + SECD + SECE;  // 985344 = 3849 * 256
  cvt_all_kernel<<<(CVT_TOTAL + 255) / 256, blk, 0, stream>>>(
      Wqkv, Wo, W1, W2, bqkv, wqB, woB, w1B, w2B, bq2);

  transpose_rn_kernel<<<ROWS / 4, blk, 0, stream>>>(src, x0, h, hb, xn);

  // layer 0 QKV from hb (transpose output)
  mgemm_qkv<<<dim3(3, ROWS / 128), blk, 0, stream>>>(hb, wqB, bq2, qkvp);

  for (int l = 0; l < NL; ++l) {
    attn_mfma_kernel<<<dim3(HH, BB, 2), dim3(512), 0, stream>>>(qkvp, att);
    const bool last = (l == NL - 1);
    wo_ffn_ln_kernel<<<dim3(ROWS / 64), blk, 0, stream>>>(
        att, woB + (size_t)l * DD * DD, bo + l * DD, ln1g + l * DD, ln1b + l * DD,
        w1B + (size_t)l * FFD * DD, b1 + l * FFD,
        w2B + (size_t)l * DD * FFD, b2 + l * DD,
        ln2g + l * DD, ln2b + l * DD, h,
        last ? nullptr : (wqB + (size_t)(l + 1) * 384 * DD),
        last ? nullptr : (bq2 + (l + 1) * 384),
        last ? nullptr : qkvp,
        last ? x0 : nullptr, last ? yn : nullptr);
  }

  cos2_kernel<<<dim3(4, 8, BB), blk, 0, stream>>>(xn, yn, out);
}

// Round 24
// 487.216 us; speedup vs baseline: 2.4298x; 1.0010x over previous
//
#include <hip/hip_runtime.h>
#include <cstdint>
#include <cstddef>

#define SS 512
#define BB 64
#define DD 128
#define HH 8
#define HDIM 16
#define FFD 1024
#define NL 6

typedef short bf16x8 __attribute__((ext_vector_type(8)));
typedef float f32x4 __attribute__((ext_vector_type(4)));

// hardware packed f32->bf16 (RNE), low16 = a, high16 = b
__device__ inline uint32_t pack2(float a, float b) {
  uint32_t r;
  asm("v_cvt_pk_bf16_f32 %0, %1, %2" : "=v"(r) : "v"(a), "v"(b));
  return r;
}

#define QSCALE 0.36067376022224085f  /* 0.25 * log2(e) */

// ---------------- merged prologue (1 launch, 6 sections) ----------------
// A: Wqkv (Q rows scaled)  B: Wo  C: W1  D: W2  E: bqkv scale
// F: transpose+rownorm (wave-per-row; section base is wave-aligned).
#define SECA (NL * 384 * 64)
#define SECB (NL * DD * 64)
#define SECC (NL * FFD * 64)
#define SECD (NL * DD * 64 * 8)
#define SECE (NL * 384)
#define SECF (BB * SS * 64)
__global__ __launch_bounds__(256) void prologue_kernel(const float* __restrict__ Wqkv,
                                                       const float* __restrict__ Wo,
                                                       const float* __restrict__ W1,
                                                       const float* __restrict__ W2,
                                                       const float* __restrict__ bqkv,
                                                       short* __restrict__ wqB,
                                                       short* __restrict__ woB,
                                                       short* __restrict__ w1B,
                                                       short* __restrict__ w2B,
                                                       float* __restrict__ bq2,
                                                       const float* __restrict__ src,
                                                       float* __restrict__ x0,
                                                       float* __restrict__ h,
                                                       short* __restrict__ hb,
                                                       short* __restrict__ xn) {
  int i = blockIdx.x * 256 + threadIdx.x;
  if (i < SECA) {
    const int within = i % (384 * 64);
    const float sc = (within < 128 * 64) ? QSCALE : 1.0f;
    float2 v = ((const float2*)Wqkv)[i];
    ((uint32_t*)wqB)[i] = pack2(v.x * sc, v.y * sc);
    return;
  }
  i -= SECA;
  if (i < SECB) {
    float2 v = ((const float2*)Wo)[i];
    ((uint32_t*)woB)[i] = pack2(v.x, v.y);
    return;
  }
  i -= SECB;
  if (i < SECC) {
    float2 v = ((const float2*)W1)[i];
    ((uint32_t*)w1B)[i] = pack2(v.x, v.y);
    return;
  }
  i -= SECC;
  if (i < SECD) {
    float2 v = ((const float2*)W2)[i];
    ((uint32_t*)w2B)[i] = pack2(v.x, v.y);
    return;
  }
  i -= SECD;
  if (i < SECE) {
    const float sc = ((i % 384) < 128) ? QSCALE : 1.0f;
    bq2[i] = bqkv[i] * sc;
    return;
  }
  i -= SECE;
  if (i < SECF) {
    // transpose+rownorm: row = i>>6, lane = i&63 (intra-wave: base offset
    // SECA+..+SECE = 985344 is a multiple of 64/256)
    const int row = i >> 6;
    const int lane = i & 63;
    const int b = row >> 9;
    const int s = row & 511;
    const float2 v = ((const float2*)(src + ((size_t)s * BB + b) * DD))[lane];
    ((float2*)(x0 + (size_t)row * DD))[lane] = v;
    ((float2*)(h + (size_t)row * DD))[lane] = v;
    ((uint32_t*)hb)[(size_t)row * 64 + lane] = pack2(v.x, v.y);
    float ss = v.x * v.x + v.y * v.y;
    #pragma unroll
    for (int off = 1; off < 64; off <<= 1) ss += __shfl_xor(ss, off);
    const float r = rsqrtf(ss);
    ((uint32_t*)xn)[(size_t)row * 64 + lane] = pack2(v.x * r, v.y * r);
  }
}

// ---------------- MFMA GEMM (QKV layer 0 only): C = A@B^T + bias, head-major out ----------------
__global__ __launch_bounds__(256) void mgemm_qkv(const short* __restrict__ Ab,
                                                 const short* __restrict__ Bw,
                                                 const float* __restrict__ bias,
                                                 short* __restrict__ Cb) {
  __shared__ uint32_t Xs[128 * 32];
  __shared__ uint32_t Wls[128 * 32];
  const int t = threadIdx.x;
  const int wave = t >> 6, lane = t & 63;
  const int g = lane >> 4, p = lane & 15;
  const int wr = wave >> 1, wc = wave & 1;
  const int m0 = blockIdx.y * 128, n0 = blockIdx.x * 128;
  const int K = DD;

  f32x4 acc[4][4];
  #pragma unroll
  for (int i = 0; i < 4; ++i)
    #pragma unroll
    for (int j = 0; j < 4; ++j) acc[i][j] = (f32x4){0.f, 0.f, 0.f, 0.f};

  for (int kt = 0; kt < K; kt += 64) {
    __syncthreads();
    #pragma unroll
    for (int i = 0; i < 4; ++i) {
      const int idx = t + i * 256;
      const int row = idx >> 3, kc = idx & 7;
      const uint4 w = *(const uint4*)(Ab + (size_t)(m0 + row) * K + kt + kc * 8);
      *(uint4*)(Xs + row * 32 + ((kc ^ (row & 7)) << 2)) = w;
      const uint4 u = *(const uint4*)(Bw + (size_t)(n0 + row) * K + kt + kc * 8);
      *(uint4*)(Wls + row * 32 + ((kc ^ (row & 7)) << 2)) = u;
    }
    __syncthreads();
    #pragma unroll
    for (int kc32 = 0; kc32 < 2; ++kc32) {
      bf16x8 xf[4], wf[4];
      #pragma unroll
      for (int mi = 0; mi < 4; ++mi) {
        const int row = wr * 64 + mi * 16 + p;
        union { bf16x8 v; uint4 w; } u;
        u.w = *(const uint4*)(Xs + row * 32 + (((kc32 * 4 + g) ^ (row & 7)) << 2));
        xf[mi] = u.v;
      }
      #pragma unroll
      for (int ni = 0; ni < 4; ++ni) {
        const int row = wc * 64 + ni * 16 + p;
        union { bf16x8 v; uint4 w; } u;
        u.w = *(const uint4*)(Wls + row * 32 + (((kc32 * 4 + g) ^ (row & 7)) << 2));
        wf[ni] = u.v;
      }
      #pragma unroll
      for (int mi = 0; mi < 4; ++mi)
        #pragma unroll
        for (int ni = 0; ni < 4; ++ni)
          acc[mi][ni] = __builtin_amdgcn_mfma_f32_16x16x32_bf16(wf[ni], xf[mi], acc[mi][ni], 0, 0, 0);
    }
  }

  #pragma unroll
  for (int mi = 0; mi < 4; ++mi) {
    const int m = m0 + wr * 64 + mi * 16 + p;
    #pragma unroll
    for (int ni = 0; ni < 4; ++ni) {
      const int nb = n0 + wc * 64 + ni * 16 + g * 4;
      const float4 bv = *(const float4*)(bias + nb);
      float c[4];
      c[0] = acc[mi][ni][0] + bv.x;
      c[1] = acc[mi][ni][1] + bv.y;
      c[2] = acc[mi][ni][2] + bv.z;
      c[3] = acc[mi][ni][3] + bv.w;
      const int bb2 = m >> 9, s = m & 511;
      const int which = nb >> 7, hh = (nb >> 4) & 7, d = nb & 15;
      uint2 w;
      w.x = pack2(c[0], c[1]);
      w.y = pack2(c[2], c[3]);
      *(uint2*)(Cb + ((((size_t)(bb2 * 3 + which) * 8 + hh) * 512 + s) * 16 + d)) = w;
    }
  }
}

// ---------------- Fused cosine-sim pair ----------------
__global__ __launch_bounds__(256) void cos2_kernel(const short* __restrict__ xn,
                                                   const short* __restrict__ yn,
                                                   float* __restrict__ out) {
  __shared__ uint32_t Js[128 * 64];  // 32 KB
  const int t = threadIdx.x;
  const int w = t >> 6, lane = t & 63;
  const int g = lane >> 4, p = lane & 15;
  const int j0 = blockIdx.x * 128;
  const int i0 = blockIdx.y * 64;
  const int b = blockIdx.z;
  const short* xb = xn + (size_t)b * SS * DD;
  const short* yb = yn + (size_t)b * SS * DD;
  const int i = i0 + w * 16 + p;

  // ---- pass 1: xn ----
  bf16x8 af[4];
  #pragma unroll
  for (int kc = 0; kc < 4; ++kc) {
    union { bf16x8 v; uint4 u; } uu;
    uu.u = *(const uint4*)(xb + (size_t)i * DD + kc * 32 + g * 8);
    af[kc] = uu.v;
  }
  #pragma unroll
  for (int q = 0; q < 8; ++q) {
    const int idx = q * 256 + t;
    const int row = idx >> 4, slot = idx & 15;
    const int key = (row & 3) | ((row >> 1) & 12);
    const uint4 u = *(const uint4*)(xb + (size_t)(j0 + row) * DD + slot * 8);
    *(uint4*)(&Js[row * 64 + ((slot ^ key) << 2)]) = u;
  }
  __syncthreads();

  f32x4 acc[8];
  #pragma unroll
  for (int q = 0; q < 8; ++q) acc[q] = (f32x4){0.f, 0.f, 0.f, 0.f};
  #pragma unroll
  for (int kc = 0; kc < 4; ++kc) {
    #pragma unroll
    for (int ni = 0; ni < 8; ++ni) {
      const int row = ni * 16 + p;
      const int key = (row & 3) | ((row >> 1) & 12);
      union { bf16x8 v; uint4 u; } jf;
      jf.u = *(const uint4*)(&Js[row * 64 + (((kc * 4 + g) ^ key) << 2)]);
      acc[ni] = __builtin_amdgcn_mfma_f32_16x16x32_bf16(jf.v, af[kc], acc[ni], 0, 0, 0);
    }
  }
  float prev[8][4];
  #pragma unroll
  for (int ni = 0; ni < 8; ++ni)
    #pragma unroll
    for (int r = 0; r < 4; ++r) prev[ni][r] = fmaxf(acc[ni][r], 1e-6f);
  __syncthreads();

  // ---- pass 2: yn ----
  #pragma unroll
  for (int kc = 0; kc < 4; ++kc) {
    union { bf16x8 v; uint4 u; } uu;
    uu.u = *(const uint4*)(yb + (size_t)i * DD + kc * 32 + g * 8);
    af[kc] = uu.v;
  }
  #pragma unroll
  for (int q = 0; q < 8; ++q) {
    const int idx = q * 256 + t;
    const int row = idx >> 4, slot = idx & 15;
    const int key = (row & 3) | ((row >> 1) & 12);
    const uint4 u = *(const uint4*)(yb + (size_t)(j0 + row) * DD + slot * 8);
    *(uint4*)(&Js[row * 64 + ((slot ^ key) << 2)]) = u;
  }
  __syncthreads();

  #pragma unroll
  for (int q = 0; q < 8; ++q) acc[q] = (f32x4){0.f, 0.f, 0.f, 0.f};
  #pragma unroll
  for (int kc = 0; kc < 4; ++kc) {
    #pragma unroll
    for (int ni = 0; ni < 8; ++ni) {
      const int row = ni * 16 + p;
      const int key = (row & 3) | ((row >> 1) & 12);
      union { bf16x8 v; uint4 u; } jf;
      jf.u = *(const uint4*)(&Js[row * 64 + (((kc * 4 + g) ^ key) << 2)]);
      acc[ni] = __builtin_amdgcn_mfma_f32_16x16x32_bf16(jf.v, af[kc], acc[ni], 0, 0, 0);
    }
  }

  float* ob = out + (size_t)b * SS * SS;
  #pragma unroll
  for (int ni = 0; ni < 8; ++ni) {
    const int j = j0 + ni * 16 + g * 4;
    float4 wv;
    float* pw = &wv.x;
    #pragma unroll
    for (int r = 0; r < 4; ++r) {
      const float v = fmaxf(acc[ni][r], 1e-6f);
      pw[r] = fminf(fmaxf(0.5f * (v + prev[ni][r]), 0.1f), 0.9f);
    }
    *(float4*)(ob + (size_t)i * SS + j) = wv;
  }
}

// ---------------- Fused Wo+LN1+FFN+LN2 + {phase C: next-layer QKV | mask_norm} ----------------
__global__ __launch_bounds__(256) void wo_ffn_ln_kernel(const short* __restrict__ att,
                                                        const short* __restrict__ Wob,
                                                        const float* __restrict__ bov,
                                                        const float* __restrict__ lng1,
                                                        const float* __restrict__ lnb1,
                                                        const short* __restrict__ W1b,
                                                        const float* __restrict__ b1v,
                                                        const short* __restrict__ W2b,
                                                        const float* __restrict__ b2v,
                                                        const float* __restrict__ lng2,
                                                        const float* __restrict__ lnb2,
                                                        float* __restrict__ hx,
                                                        const short* __restrict__ Wqn,
                                                        const float* __restrict__ bqn,
                                                        short* __restrict__ qkvo,
                                                        const float* __restrict__ x0p,
                                                        short* __restrict__ ynp) {
  __shared__ uint32_t S[10240];      // 40 KB union
  uint32_t* WoLS = S;                // phase A: 8192 words (32 KB)
  uint32_t* Tb   = S;                // transient: 4096 words (16 KB)
  uint32_t* W1base = S;              // 2 bufs x 2048 words
  uint32_t* W2base = S + 4096;       // 3 bufs x 2048 words
  const int t = threadIdx.x;
  const int w = t >> 6, lane = t & 63;
  const int g = lane >> 4, p = lane & 15;
  const int m0 = blockIdx.x * 64;
  const int m = m0 + w * 16 + p;
  const int lr = w * 16 + p;
  const int lkey = (lr & 3) | ((lr >> 1) & 12);

  // ---- Phase A: att rows in regs, Wo in LDS ----
  bf16x8 af[4];
  #pragma unroll
  for (int kc = 0; kc < 4; ++kc) {
    union { bf16x8 v; uint4 u; } uu;
    uu.u = *(const uint4*)(att + (size_t)m * DD + kc * 32 + g * 8);
    af[kc] = uu.v;
  }
  #pragma unroll
  for (int i = 0; i < 8; ++i) {
    const int idx = i * 256 + t;
    const int row = idx >> 4, slot = idx & 15;
    const int key = (row & 3) | ((row >> 1) & 12);
    const uint4 u = *(const uint4*)(Wob + (size_t)row * DD + slot * 8);
    *(uint4*)(&WoLS[row * 64 + ((slot ^ key) << 2)]) = u;
  }
  __syncthreads();

  f32x4 acc[8];
  #pragma unroll
  for (int i = 0; i < 8; ++i) acc[i] = (f32x4){0.f, 0.f, 0.f, 0.f};
  #pragma unroll
  for (int kc = 0; kc < 4; ++kc) {
    #pragma unroll
    for (int ni = 0; ni < 8; ++ni) {
      const int row = ni * 16 + p;
      const int key = (row & 3) | ((row >> 1) & 12);
      union { bf16x8 v; uint4 u; } wf;
      wf.u = *(const uint4*)(&WoLS[row * 64 + (((kc * 4 + g) ^ key) << 2)]);
      acc[ni] = __builtin_amdgcn_mfma_f32_16x16x32_bf16(wf.v, af[kc], acc[ni], 0, 0, 0);
    }
  }

  // LN1 (lane-local rows)
  float h1r[8][4];
  float s1r = 0.0f, s2r = 0.0f;
  #pragma unroll
  for (int ni = 0; ni < 8; ++ni) {
    const int nb = ni * 16 + g * 4;
    const float4 rv = *(const float4*)(hx + (size_t)m * DD + nb);
    const float4 bv = *(const float4*)(bov + nb);
    h1r[ni][0] = acc[ni][0] + bv.x + rv.x;
    h1r[ni][1] = acc[ni][1] + bv.y + rv.y;
    h1r[ni][2] = acc[ni][2] + bv.z + rv.z;
    h1r[ni][3] = acc[ni][3] + bv.w + rv.w;
    #pragma unroll
    for (int r = 0; r < 4; ++r) {
      s1r += h1r[ni][r];
      s2r += h1r[ni][r] * h1r[ni][r];
    }
  }
  s1r += __shfl_xor(s1r, 16); s1r += __shfl_xor(s1r, 32);
  s2r += __shfl_xor(s2r, 16); s2r += __shfl_xor(s2r, 32);
  {
    const float mu = s1r * (1.0f / 128.0f);
    const float rs = rsqrtf(fmaxf(s2r * (1.0f / 128.0f) - mu * mu, 0.0f) + 1e-5f);
    #pragma unroll
    for (int ni = 0; ni < 8; ++ni) {
      const int nb = ni * 16 + g * 4;
      const float4 gv = *(const float4*)(lng1 + nb);
      const float4 bv = *(const float4*)(lnb1 + nb);
      h1r[ni][0] = (h1r[ni][0] - mu) * rs * gv.x + bv.x;
      h1r[ni][1] = (h1r[ni][1] - mu) * rs * gv.y + bv.y;
      h1r[ni][2] = (h1r[ni][2] - mu) * rs * gv.z + bv.z;
      h1r[ni][3] = (h1r[ni][3] - mu) * rs * gv.w + bv.w;
    }
  }
  __syncthreads();  // all Wo reads done before Tb overwrites WoLS

  // write h1 (bf16) into Tb
  #pragma unroll
  for (int ni = 0; ni < 8; ++ni) {
    const int w16 = ni * 8 + 2 * g;
    const int slot = w16 >> 2, offs = w16 & 3;
    uint2 pk;
    pk.x = pack2(h1r[ni][0], h1r[ni][1]);
    pk.y = pack2(h1r[ni][2], h1r[ni][3]);
    *(uint2*)(&Tb[lr * 64 + ((slot ^ lkey) << 2) + offs]) = pk;
  }
  __syncthreads();

  // h1 B-frags from Tb (read ONCE; Tb dead after this barrier)
  bf16x8 hsf[4];
  #pragma unroll
  for (int kc = 0; kc < 4; ++kc) {
    union { bf16x8 v; uint4 u; } uu;
    uu.u = *(const uint4*)(&Tb[lr * 64 + (((kc * 4 + g) ^ lkey) << 2)]);
    hsf[kc] = uu.v;
  }
  __syncthreads();

  // ---- Phase B: ffn v3 ----
  uint4 rA0, rA1, rB0, rB1;

#define FFN_LOAD(c)                                                               \
  {                                                                               \
    const int nf0_ = (c) * 32;                                                    \
    rA0 = *(const uint4*)(W1b + (size_t)(nf0_ + (t >> 4)) * DD + (t & 15) * 8);   \
    rA1 = *(const uint4*)(W1b + (size_t)(nf0_ + 16 + (t >> 4)) * DD + (t & 15) * 8); \
    rB0 = *(const uint4*)(W2b + (size_t)(t >> 2) * FFD + nf0_ + (t & 3) * 8);     \
    rB1 = *(const uint4*)(W2b + (size_t)(64 + (t >> 2)) * FFD + nf0_ + (t & 3) * 8); \
  }

#define FFN_WRITE(bufA, bufB)                                                     \
  {                                                                               \
    uint32_t* W1p = W1base + (bufA) * 2048;                                       \
    uint32_t* W2p = W2base + (bufB) * 2048;                                       \
    const int rw0 = t >> 4, sl0 = t & 15;                                         \
    const int k0 = (rw0 & 3) | ((rw0 >> 1) & 12);                                 \
    *(uint4*)(&W1p[rw0 * 64 + ((sl0 ^ k0) << 2)]) = rA0;                          \
    const int rw1 = 16 + rw0;                                                     \
    const int k1 = (rw1 & 3) | ((rw1 >> 1) & 12);                                 \
    *(uint4*)(&W1p[rw1 * 64 + ((sl0 ^ k1) << 2)]) = rA1;                          \
    const int rw2 = t >> 2, sl2 = t & 3;                                          \
    *(uint4*)(&W2p[rw2 * 16 + ((sl2 ^ ((rw2 >> 1) & 3)) << 2)]) = rB0;            \
    const int rw3 = 64 + rw2;                                                     \
    *(uint4*)(&W2p[rw3 * 16 + ((sl2 ^ ((rw3 >> 1) & 3)) << 2)]) = rB1;            \
  }

  FFN_LOAD(0);
  FFN_WRITE(0, 0);
  __syncthreads();

  const int pr0 = 8 * (p >> 2) + (p & 3);
  const int pr1 = pr0 + 4;
  const int key0 = (pr0 & 3) | ((pr0 >> 1) & 12);
  const int key1 = (pr1 & 3) | ((pr1 >> 1) & 12);

  f32x4 acc2[8];
  #pragma unroll
  for (int i = 0; i < 8; ++i) acc2[i] = (f32x4){0.f, 0.f, 0.f, 0.f};
  const f32x4 zacc = {0.f, 0.f, 0.f, 0.f};

  bf16x8 pbv;
  int bPrev = 2, bCur = 0, bNext = 1;

  for (int c = 0; c < 32; ++c) {
    const int bA = c & 1;
    if (c + 1 < 32) FFN_LOAD(c + 1);

    const uint32_t* W1p = W1base + bA * 2048;
    f32x4 s0 = zacc, s1 = zacc;
    #pragma unroll
    for (int kc = 0; kc < 4; ++kc) {
      union { bf16x8 v; uint4 u; } a0, a1;
      a0.u = *(const uint4*)(&W1p[pr0 * 64 + (((kc * 4 + g) ^ key0) << 2)]);
      a1.u = *(const uint4*)(&W1p[pr1 * 64 + (((kc * 4 + g) ^ key1) << 2)]);
      s0 = __builtin_amdgcn_mfma_f32_16x16x32_bf16(a0.v, hsf[kc], s0, 0, 0, 0);
      s1 = __builtin_amdgcn_mfma_f32_16x16x32_bf16(a1.v, hsf[kc], s1, 0, 0, 0);
    }

    if (c > 0) {
      const uint32_t* W2p = W2base + bPrev * 2048;
      #pragma unroll
      for (int ni = 0; ni < 8; ++ni) {
        const int row = ni * 16 + p;
        union { bf16x8 v; uint4 u; } wf;
        wf.u = *(const uint4*)(&W2p[row * 16 + ((g ^ ((row >> 1) & 3)) << 2)]);
        acc2[ni] = __builtin_amdgcn_mfma_f32_16x16x32_bf16(wf.v, pbv, acc2[ni], 0, 0, 0);
      }
    }

    const int nf0 = c * 32;
    const float4 bb0 = *(const float4*)(b1v + nf0 + 8 * g);
    const float4 bb1 = *(const float4*)(b1v + nf0 + 8 * g + 4);
    union { bf16x8 v; uint4 u; } pb;
    pb.u.x = pack2(fmaxf(s0[0] + bb0.x, 0.0f), fmaxf(s0[1] + bb0.y, 0.0f));
    pb.u.y = pack2(fmaxf(s0[2] + bb0.z, 0.0f), fmaxf(s0[3] + bb0.w, 0.0f));
    pb.u.z = pack2(fmaxf(s1[0] + bb1.x, 0.0f), fmaxf(s1[1] + bb1.y, 0.0f));
    pb.u.w = pack2(fmaxf(s1[2] + bb1.z, 0.0f), fmaxf(s1[3] + bb1.w, 0.0f));
    pbv = pb.v;

    if (c + 1 < 32) FFN_WRITE(bA ^ 1, bNext);
    __syncthreads();

    bPrev = bCur; bCur = bNext; bNext = (bNext == 2) ? 0 : bNext + 1;
  }

  { // final GEMM2(31): chunk 31 staged into buf (1+30)%3 = 1
    const uint32_t* W2p = W2base + 1 * 2048;
    #pragma unroll
    for (int ni = 0; ni < 8; ++ni) {
      const int row = ni * 16 + p;
      union { bf16x8 v; uint4 u; } wf;
      wf.u = *(const uint4*)(&W2p[row * 16 + ((g ^ ((row >> 1) & 3)) << 2)]);
      acc2[ni] = __builtin_amdgcn_mfma_f32_16x16x32_bf16(wf.v, pbv, acc2[ni], 0, 0, 0);
    }
  }

  // LN2: residual = h1r (regs)
  float t1 = 0.0f, t2 = 0.0f;
  #pragma unroll
  for (int ni = 0; ni < 8; ++ni) {
    const int nb = ni * 16 + g * 4;
    const float4 bv = *(const float4*)(b2v + nb);
    acc2[ni][0] += bv.x + h1r[ni][0];
    acc2[ni][1] += bv.y + h1r[ni][1];
    acc2[ni][2] += bv.z + h1r[ni][2];
    acc2[ni][3] += bv.w + h1r[ni][3];
    #pragma unroll
    for (int r = 0; r < 4; ++r) {
      t1 += acc2[ni][r];
      t2 += acc2[ni][r] * acc2[ni][r];
    }
  }
  t1 += __shfl_xor(t1, 16); t1 += __shfl_xor(t1, 32);
  t2 += __shfl_xor(t2, 16); t2 += __shfl_xor(t2, 32);
  const float mu2 = t1 * (1.0f / 128.0f);
  const float rs2 = rsqrtf(fmaxf(t2 * (1.0f / 128.0f) - mu2 * mu2, 0.0f) + 1e-5f);

  if (ynp != nullptr) {
    // last layer: fused mask_norm — yn = normalize(x0 * sigmoid(h_final))
    float av[8][4];
    float ssum = 0.0f;
    #pragma unroll
    for (int ni = 0; ni < 8; ++ni) {
      const int nb = ni * 16 + g * 4;
      const float4 gv = *(const float4*)(lng2 + nb);
      const float4 bv = *(const float4*)(lnb2 + nb);
      const float4 xv = *(const float4*)(x0p + (size_t)m * DD + nb);
      const float hc0 = (acc2[ni][0] - mu2) * rs2 * gv.x + bv.x;
      const float hc1 = (acc2[ni][1] - mu2) * rs2 * gv.y + bv.y;
      const float hc2 = (acc2[ni][2] - mu2) * rs2 * gv.z + bv.z;
      const float hc3 = (acc2[ni][3] - mu2) * rs2 * gv.w + bv.w;
      av[ni][0] = xv.x / (1.0f + __expf(-hc0));
      av[ni][1] = xv.y / (1.0f + __expf(-hc1));
      av[ni][2] = xv.z / (1.0f + __expf(-hc2));
      av[ni][3] = xv.w / (1.0f + __expf(-hc3));
      #pragma unroll
      for (int r = 0; r < 4; ++r) ssum += av[ni][r] * av[ni][r];
    }
    ssum += __shfl_xor(ssum, 16);
    ssum += __shfl_xor(ssum, 32);
    const float inv = 1.0f / fmaxf(sqrtf(ssum), 1e-12f);
    #pragma unroll
    for (int ni = 0; ni < 8; ++ni) {
      const int nb = ni * 16 + g * 4;
      uint2 wb;
      wb.x = pack2(av[ni][0] * inv, av[ni][1] * inv);
      wb.y = pack2(av[ni][2] * inv, av[ni][3] * inv);
      *(uint2*)(ynp + (size_t)m * DD + nb) = wb;
    }
    return;
  }

  // layers 0..4: write hx fp32 + pack new-h bf16 into h1r, write Tb, phase C
  #pragma unroll
  for (int ni = 0; ni < 8; ++ni) {
    const int nb = ni * 16 + g * 4;
    const float4 gv = *(const float4*)(lng2 + nb);
    const float4 bv = *(const float4*)(lnb2 + nb);
    h1r[ni][0] = (acc2[ni][0] - mu2) * rs2 * gv.x + bv.x;
    h1r[ni][1] = (acc2[ni][1] - mu2) * rs2 * gv.y + bv.y;
    h1r[ni][2] = (acc2[ni][2] - mu2) * rs2 * gv.z + bv.z;
    h1r[ni][3] = (acc2[ni][3] - mu2) * rs2 * gv.w + bv.w;
    float4 wv;
    wv.x = h1r[ni][0]; wv.y = h1r[ni][1]; wv.z = h1r[ni][2]; wv.w = h1r[ni][3];
    *(float4*)(hx + (size_t)m * DD + nb) = wv;
  }

  // Tb (= W1base region): W1 buf1 reads finished at c=31 in-loop barrier; final
  // GEMM2 reads only W2base. Per-lane rows disjoint -> safe to write, then barrier.
  #pragma unroll
  for (int ni = 0; ni < 8; ++ni) {
    const int w16 = ni * 8 + 2 * g;
    const int slot = w16 >> 2, offs = w16 & 3;
    uint2 pk;
    pk.x = pack2(h1r[ni][0], h1r[ni][1]);
    pk.y = pack2(h1r[ni][2], h1r[ni][3]);
    *(uint2*)(&Tb[lr * 64 + ((slot ^ lkey) << 2) + offs]) = pk;
  }
  __syncthreads();

  #pragma unroll
  for (int kc = 0; kc < 4; ++kc) {
    union { bf16x8 v; uint4 u; } uu;
    uu.u = *(const uint4*)(&Tb[lr * 64 + (((kc * 4 + g) ^ lkey) << 2)]);
    hsf[kc] = uu.v;
  }
  __syncthreads();

  // ---- Phase C: next-layer QKV, 12 chunks of 32 n-rows (FFN GEMM1 machinery) ----
#define QKV_LOAD(c)                                                               \
  {                                                                               \
    const int nf0_ = (c) * 32;                                                    \
    rA0 = *(const uint4*)(Wqn + (size_t)(nf0_ + (t >> 4)) * DD + (t & 15) * 8);   \
    rA1 = *(const uint4*)(Wqn + (size_t)(nf0_ + 16 + (t >> 4)) * DD + (t & 15) * 8); \
  }

#define QKV_WRITE(bufA)                                                           \
  {                                                                               \
    uint32_t* W1p = W1base + (bufA) * 2048;                                       \
    const int rw0 = t >> 4, sl0 = t & 15;                                         \
    const int k0 = (rw0 & 3) | ((rw0 >> 1) & 12);                                 \
    *(uint4*)(&W1p[rw0 * 64 + ((sl0 ^ k0) << 2)]) = rA0;                          \
    const int rw1 = 16 + rw0;                                                     \
    const int k1 = (rw1 & 3) | ((rw1 >> 1) & 12);                                 \
    *(uint4*)(&W1p[rw1 * 64 + ((sl0 ^ k1) << 2)]) = rA1;                          \
  }

  QKV_LOAD(0);
  QKV_WRITE(0);
  __syncthreads();

  const int bb2 = m >> 9, sm = m & 511;
  for (int c = 0; c < 12; ++c) {
    const int bA = c & 1;
    if (c + 1 < 12) QKV_LOAD(c + 1);

    const uint32_t* W1p = W1base + bA * 2048;
    f32x4 s0 = zacc, s1 = zacc;
    #pragma unroll
    for (int kc = 0; kc < 4; ++kc) {
      union { bf16x8 v; uint4 u; } a0, a1;
      a0.u = *(const uint4*)(&W1p[pr0 * 64 + (((kc * 4 + g) ^ key0) << 2)]);
      a1.u = *(const uint4*)(&W1p[pr1 * 64 + (((kc * 4 + g) ^ key1) << 2)]);
      s0 = __builtin_amdgcn_mfma_f32_16x16x32_bf16(a0.v, hsf[kc], s0, 0, 0, 0);
      s1 = __builtin_amdgcn_mfma_f32_16x16x32_bf16(a1.v, hsf[kc], s1, 0, 0, 0);
    }

    // lane (g,p): s0[r] = qkv[m][n0q+r], s1[r] = qkv[m][n0q+4+r], n0q = c*32+8g
    const int n0q = c * 32 + 8 * g;
    const float4 b0 = *(const float4*)(bqn + n0q);
    const float4 b4 = *(const float4*)(bqn + n0q + 4);
    const int which = n0q >> 7, hh = (n0q >> 4) & 7, d0 = n0q & 15;
    short* base = qkvo + ((((size_t)(bb2 * 3 + which) * 8 + hh) * 512 + sm) * 16 + d0);
    uint2 w0, w1;
    w0.x = pack2(s0[0] + b0.x, s0[1] + b0.y);
    w0.y = pack2(s0[2] + b0.z, s0[3] + b0.w);
    w1.x = pack2(s1[0] + b4.x, s1[1] + b4.y);
    w1.y = pack2(s1[2] + b4.z, s1[3] + b4.w);
    *(uint2*)(base) = w0;
    *(uint2*)(base + 4) = w1;

    if (c + 1 < 12) QKV_WRITE(bA ^ 1);
    __syncthreads();
  }
}

// ---------------- MFMA flash attention v6 (z=2) ----------------
__global__ __launch_bounds__(512) void attn_mfma_kernel(const short* __restrict__ qkvp,
                                                        short* __restrict__ o_out) {
  const int h = blockIdx.x;
  const int b = blockIdx.y;
  const int z = blockIdx.z;
  const int t = threadIdx.x;
  const int wave = t >> 6;
  const int lane = t & 63;
  const int g = lane >> 4;
  const int p = lane & 15;

  __shared__ uint32_t Ks[512 * 8];
  __shared__ uint32_t Vs[16 * 256];

  const short* baseQ = qkvp + ((size_t)(b * 3 + 0) * 8 + h) * 8192;
  const short* baseK = qkvp + ((size_t)(b * 3 + 1) * 8 + h) * 8192;
  const short* baseV = qkvp + ((size_t)(b * 3 + 2) * 8 + h) * 8192;

  { // stage K
    const int row = t;
    const uint4 lo = *(const uint4*)(baseK + row * 16);
    const uint4 hi = *(const uint4*)(baseK + row * 16 + 8);
    const int f = ((row >> 3) & 1) << 2;
    *(uint4*)(Ks + row * 8 + f) = lo;
    *(uint4*)(Ks + row * 8 + (f ^ 4)) = hi;
  }
  { // stage V^T (swizzled scatter)
    const int k = t;
    union { uint4 u[2]; short s[16]; } vv;
    vv.u[0] = *(const uint4*)(baseV + k * 16);
    vv.u[1] = *(const uint4*)(baseV + k * 16 + 8);
    const int wk = k >> 1;
    #pragma unroll
    for (int d = 0; d < 16; ++d) {
      const int word = d * 256 + (wk ^ ((d & 7) << 2));
      ((short*)(Vs + word))[k & 1] = vv.s[d];
    }
  }
  __syncthreads();

  const bf16x8 zfrag = {0, 0, 0, 0, 0, 0, 0, 0};
  const f32x4 zacc = {0.f, 0.f, 0.f, 0.f};

  #pragma unroll
  for (int qi = 0; qi < 2; ++qi) {
    const int qt = z * 16 + wave + qi * 8;
    bf16x8 qf = zfrag;
    if (g < 2) {
      union { bf16x8 v; uint4 w; } qu;
      qu.w = *(const uint4*)(baseQ + (qt * 16 + p) * 16 + g * 8);
      qf = qu.v;
    }

    f32x4 o = zacc;
    float lsum = 0.0f;

    for (int kv = 0; kv < 16; ++kv) {
      bf16x8 ka = zfrag, kb = zfrag;
      if (g < 2) {
        const int r0 = kv * 32 + 8 * (p >> 2) + (p & 3);
        const int r1 = r0 + 4;
        union { bf16x8 v; uint4 w; } u;
        u.w = *(const uint4*)(Ks + r0 * 8 + ((4 * g) ^ (((r0 >> 3) & 1) << 2)));
        ka = u.v;
        u.w = *(const uint4*)(Ks + r1 * 8 + ((4 * g) ^ (((r1 >> 3) & 1) << 2)));
        kb = u.v;
      }
      union { bf16x8 v; uint4 w; } vu;
      vu.w = *(const uint4*)(Vs + p * 256 + ((kv * 16 + g * 4) ^ ((p & 7) << 2)));

      const f32x4 s0 = __builtin_amdgcn_mfma_f32_16x16x32_bf16(ka, qf, zacc, 0, 0, 0);
      const f32x4 s1 = __builtin_amdgcn_mfma_f32_16x16x32_bf16(kb, qf, zacc, 0, 0, 0);

      float sv0[4], sv1[4];
      #pragma unroll
      for (int r = 0; r < 4; ++r) {
        sv0[r] = __builtin_amdgcn_exp2f(s0[r]);
        sv1[r] = __builtin_amdgcn_exp2f(s1[r]);
      }
      #pragma unroll
      for (int r = 0; r < 4; ++r) lsum += sv0[r] + sv1[r];

      union { bf16x8 v; uint4 w; } pu;
      pu.w.x = pack2(sv0[0], sv0[1]);
      pu.w.y = pack2(sv0[2], sv0[3]);
      pu.w.z = pack2(sv1[0], sv1[1]);
      pu.w.w = pack2(sv1[2], sv1[3]);

      o = __builtin_amdgcn_mfma_f32_16x16x32_bf16(pu.v, vu.v, o, 0, 0, 0);
    }

    lsum += __shfl_xor(lsum, 16);
    lsum += __shfl_xor(lsum, 32);
    const float li = 1.0f / lsum;
    #pragma unroll
    for (int r = 0; r < 4; ++r) {
      const float inv = __shfl(li, 4 * g + r);
      o_out[((size_t)(b * SS + qt * 16 + 4 * g + r)) * DD + h * HDIM + p] =
          (short)(pack2(o[r] * inv, 0.0f) & 0xffff);
    }
  }
}

extern "C" void kernel_launch(void* const* d_in, const int* in_sizes, int n_in,
                              void* d_out, int out_size, void* d_ws, size_t ws_size,
                              hipStream_t stream) {
  const float* src  = (const float*)d_in[0];
  const float* Wqkv = (const float*)d_in[1];
  const float* bqkv = (const float*)d_in[2];
  const float* Wo   = (const float*)d_in[3];
  const float* bo   = (const float*)d_in[4];
  const float* ln1g = (const float*)d_in[5];
  const float* ln1b = (const float*)d_in[6];
  const float* W1   = (const float*)d_in[7];
  const float* b1   = (const float*)d_in[8];
  const float* W2   = (const float*)d_in[9];
  const float* b2   = (const float*)d_in[10];
  const float* ln2g = (const float*)d_in[11];
  const float* ln2b = (const float*)d_in[12];
  float* out = (float*)d_out;

  char* W = (char*)d_ws;
  const size_t MB = 1048576;
  float* x0  = (float*)(W);
  float* h   = (float*)(W + 16 * MB);
  short* hb  = (short*)(W + 32 * MB);
  short* qkvp = (short*)(W + 40 * MB);   // 24 MB head-major [b][3][h][s][16]
  short* att = (short*)(W + 128 * MB);
  short* xn  = (short*)(W + 136 * MB);
  short* yn  = (short*)(W + 144 * MB);
  short* wqB = (short*)(W + 152 * MB);
  short* woB = wqB + (size_t)NL * 384 * DD;
  short* w1B = woB + (size_t)NL * DD * DD;
  short* w2B = w1B + (size_t)NL * FFD * DD;
  float* bq2 = (float*)(w2B + (size_t)NL * DD * FFD);

  const dim3 blk(256);
  const int ROWS = BB * SS;

  // merged prologue: weight converts + bias scale + transpose/rownorm, one launch
  const int PRO_TOTAL = SECA + SECB + SECC + SECD + SECE + SECF;
  prologue_kernel<<<(PRO_TOTAL + 255) / 256, blk, 0, stream>>>(
      Wqkv, Wo, W1, W2, bqkv, wqB, woB, w1B, w2B, bq2, src, x0, h, hb, xn);

  // layer 0 QKV from hb (transpose output)
  mgemm_qkv<<<dim3(3, ROWS / 128), blk, 0, stream>>>(hb, wqB, bq2, qkvp);

  for (int l = 0; l < NL; ++l) {
    attn_mfma_kernel<<<dim3(HH, BB, 2), dim3(512), 0, stream>>>(qkvp, att);
    const bool last = (l == NL - 1);
    wo_ffn_ln_kernel<<<dim3(ROWS / 64), blk, 0, stream>>>(
        att, woB + (size_t)l * DD * DD, bo + l * DD, ln1g + l * DD, ln1b + l * DD,
        w1B + (size_t)l * FFD * DD, b1 + l * FFD,
        w2B + (size_t)l * DD * FFD, b2 + l * DD,
        ln2g + l * DD, ln2b + l * DD, h,
        last ? nullptr : (wqB + (size_t)(l + 1) * 384 * DD),
        last ? nullptr : (bq2 + (l + 1) * 384),
        last ? nullptr : qkvp,
        last ? x0 : nullptr, last ? yn : nullptr);
  }

  cos2_kernel<<<dim3(4, 8, BB), blk, 0, stream>>>(xn, yn, out);
}